// Round 4
// baseline (493.575 us; speedup 1.0000x reference)
//
#include <hip/hip_runtime.h>
#include <math.h>

#define HC 128
#define NSLOPE 0.2f

__device__ __forceinline__ float lrelu(float v){ return v > 0.f ? v : NSLOPE * v; }

// bf16 round-to-nearest-even pack / unpack
__device__ __forceinline__ unsigned short f2bf(float f){
    unsigned int b = __float_as_uint(f);
    b += 0x7FFFu + ((b >> 16) & 1u);
    return (unsigned short)(b >> 16);
}
__device__ __forceinline__ float bf_lo(unsigned int v){ return __uint_as_float(v << 16); }
__device__ __forceinline__ float bf_hi(unsigned int v){ return __uint_as_float(v & 0xFFFF0000u); }

// ----------------- CSR build (dst-sorted) -----------------
__global__ void count_kernel(const int* __restrict__ ei, int* __restrict__ cnt, int E){
    int e = blockIdx.x * blockDim.x + threadIdx.x;
    if (e < E) atomicAdd(&cnt[ei[E + e]], 1);
}

// S1: per-block (1024 nodes) partial sums
__global__ __launch_bounds__(256) void scan_part_kernel(
        const int* __restrict__ deg, int* __restrict__ bsum, int n)
{
    int t = threadIdx.x, lane = t & 63, wid = t >> 6;
    int base = blockIdx.x * 1024 + t * 4;
    int s = 0;
    #pragma unroll
    for (int j = 0; j < 4; ++j){ int i = base + j; if (i < n) s += deg[i]; }
    #pragma unroll
    for (int o = 1; o < 64; o <<= 1) s += __shfl_xor(s, o);
    __shared__ int red[4];
    if (lane == 0) red[wid] = s;
    __syncthreads();
    if (t == 0) bsum[blockIdx.x] = red[0] + red[1] + red[2] + red[3];
}

// S2: 1 wave scans the (<=64) block sums; writes exclusive offsets + rowptr[n]=total
__global__ __launch_bounds__(64) void scan_top_kernel(
        const int* __restrict__ bsum, int* __restrict__ boff, int* __restrict__ rowptr,
        int nb, int n)
{
    int t = threadIdx.x;
    int v = (t < nb) ? bsum[t] : 0;
    int incl = v;
    #pragma unroll
    for (int o = 1; o < 64; o <<= 1){ int u = __shfl_up(incl, o); if (t >= o) incl += u; }
    if (t < nb) boff[t] = incl - v;
    if (t == 63) rowptr[n] = incl;
}

// S3: per-block exclusive scan with global offset -> rowptr[0..n-1]
__global__ __launch_bounds__(256) void scan_fin_kernel(
        const int* __restrict__ deg, const int* __restrict__ boff,
        int* __restrict__ rowptr, int n)
{
    int t = threadIdx.x, lane = t & 63, wid = t >> 6;
    int base = blockIdx.x * 1024 + t * 4;
    int d[4]; int s = 0;
    #pragma unroll
    for (int j = 0; j < 4; ++j){ int i = base + j; d[j] = (i < n) ? deg[i] : 0; s += d[j]; }
    int incl = s;
    #pragma unroll
    for (int o = 1; o < 64; o <<= 1){ int u = __shfl_up(incl, o); if (lane >= o) incl += u; }
    __shared__ int wsum[4];
    if (lane == 63) wsum[wid] = incl;
    __syncthreads();
    int off = boff[blockIdx.x] + (incl - s);
    for (int w = 0; w < wid; ++w) off += wsum[w];
    #pragma unroll
    for (int j = 0; j < 4; ++j){
        int i = base + j;
        if (i < n) rowptr[i] = off;
        off += d[j];
    }
}

__global__ void scatter_kernel(const int* __restrict__ ei, const int* __restrict__ rowptr,
                               int* __restrict__ cursor, int* __restrict__ colsrc, int E){
    int e = blockIdx.x * blockDim.x + threadIdx.x;
    if (e < E){
        int d = ei[E + e];
        int pos = rowptr[d] + atomicAdd(&cursor[d], 1);
        colsrc[pos] = ei[e];
    }
}

// ----------------- node encoder stage 1: hid = relu(x@w1+b1), K=32 -----------------
__global__ __launch_bounds__(256) void enc1_kernel(
        const float* __restrict__ x, const float* __restrict__ w1, const float* __restrict__ b1,
        float* __restrict__ hid, int n)
{
    __shared__ float As[32][132];
    __shared__ float Bs[32][128];
    int t = threadIdx.x;
    int m0 = blockIdx.x * 128;
    int tm = t >> 4, tn = t & 15;

    #pragma unroll
    for (int i = 0; i < 4; ++i){
        int f = i * 256 + t;
        int row = f >> 3, kq = f & 7;
        int gr = m0 + row; if (gr > n - 1) gr = n - 1;
        float4 v = *(const float4*)(x + (size_t)gr * 32 + kq * 4);
        As[kq*4+0][row] = v.x; As[kq*4+1][row] = v.y; As[kq*4+2][row] = v.z; As[kq*4+3][row] = v.w;
    }
    #pragma unroll
    for (int i = 0; i < 4; ++i){
        int f = i * 256 + t;
        int kk = f >> 5, nq = f & 31;
        *(float4*)&Bs[kk][nq*4] = *(const float4*)(w1 + (size_t)kk * 128 + nq * 4);
    }
    __syncthreads();

    float acc[8][8];
    #pragma unroll
    for (int i = 0; i < 8; ++i)
        #pragma unroll
        for (int j = 0; j < 8; ++j) acc[i][j] = 0.f;

    #pragma unroll 4
    for (int k = 0; k < 32; ++k){
        float a[8], b[8];
        *(float4*)&a[0] = *(float4*)&As[k][tm*8];
        *(float4*)&a[4] = *(float4*)&As[k][tm*8+4];
        *(float4*)&b[0] = *(float4*)&Bs[k][tn*8];
        *(float4*)&b[4] = *(float4*)&Bs[k][tn*8+4];
        #pragma unroll
        for (int i = 0; i < 8; ++i)
            #pragma unroll
            for (int j = 0; j < 8; ++j) acc[i][j] = fmaf(a[i], b[j], acc[i][j]);
    }

    float bb[8];
    *(float4*)&bb[0] = *(const float4*)(b1 + tn*8);
    *(float4*)&bb[4] = *(const float4*)(b1 + tn*8 + 4);
    #pragma unroll
    for (int i = 0; i < 8; ++i){
        int node = m0 + tm*8 + i;
        if (node < n){
            float o[8];
            #pragma unroll
            for (int j = 0; j < 8; ++j) o[j] = fmaxf(acc[i][j] + bb[j], 0.f);
            *(float4*)(hid + (size_t)node*HC + tn*8)     = *(float4*)&o[0];
            *(float4*)(hid + (size_t)node*HC + tn*8 + 4) = *(float4*)&o[4];
        }
    }
}

// ----------------- main GEMM: C = A@W (+bias); ATT: bf16 C + fused att dots -----------------
template<bool ATT>
__global__ __launch_bounds__(256) void gemm_main_kernel(
        const float* __restrict__ A, const float* __restrict__ W, const float* __restrict__ bias,
        const float* __restrict__ att_s, const float* __restrict__ att_d,
        float* __restrict__ C, unsigned short* __restrict__ Cb,
        float* __restrict__ asrc, float* __restrict__ adst, int n)
{
    __shared__ float As[32][132];
    __shared__ float Bs[32][128];
    int t = threadIdx.x;
    int m0 = blockIdx.x * 128;
    int tm = t >> 4, tn = t & 15;

    float acc[8][8];
    #pragma unroll
    for (int i = 0; i < 8; ++i)
        #pragma unroll
        for (int j = 0; j < 8; ++j) acc[i][j] = 0.f;

    for (int kc = 0; kc < 4; ++kc){
        int k0 = kc * 32;
        #pragma unroll
        for (int i = 0; i < 4; ++i){
            int f = i * 256 + t;
            int row = f >> 3, kq = f & 7;
            int gr = m0 + row; if (gr > n - 1) gr = n - 1;
            float4 v = *(const float4*)(A + (size_t)gr * HC + k0 + kq * 4);
            As[kq*4+0][row] = v.x; As[kq*4+1][row] = v.y; As[kq*4+2][row] = v.z; As[kq*4+3][row] = v.w;
        }
        #pragma unroll
        for (int i = 0; i < 4; ++i){
            int f = i * 256 + t;
            int kk = f >> 5, nq = f & 31;
            *(float4*)&Bs[kk][nq*4] = *(const float4*)(W + (size_t)(k0 + kk) * 128 + nq * 4);
        }
        __syncthreads();
        #pragma unroll 4
        for (int k = 0; k < 32; ++k){
            float a[8], b[8];
            *(float4*)&a[0] = *(float4*)&As[k][tm*8];
            *(float4*)&a[4] = *(float4*)&As[k][tm*8+4];
            *(float4*)&b[0] = *(float4*)&Bs[k][tn*8];
            *(float4*)&b[4] = *(float4*)&Bs[k][tn*8+4];
            #pragma unroll
            for (int i = 0; i < 8; ++i)
                #pragma unroll
                for (int j = 0; j < 8; ++j) acc[i][j] = fmaf(a[i], b[j], acc[i][j]);
        }
        __syncthreads();
    }

    if (!ATT){
        float bb[8];
        *(float4*)&bb[0] = *(const float4*)(bias + tn*8);
        *(float4*)&bb[4] = *(const float4*)(bias + tn*8 + 4);
        #pragma unroll
        for (int i = 0; i < 8; ++i){
            int node = m0 + tm*8 + i;
            if (node < n){
                float o[8];
                #pragma unroll
                for (int j = 0; j < 8; ++j) o[j] = acc[i][j] + bb[j];
                *(float4*)(C + (size_t)node*HC + tn*8)     = *(float4*)&o[0];
                *(float4*)(C + (size_t)node*HC + tn*8 + 4) = *(float4*)&o[4];
            }
        }
    } else {
        #pragma unroll
        for (int i = 0; i < 8; ++i){
            int node = m0 + tm*8 + i;
            if (node < n){
                uint4 pk;
                pk.x = (unsigned int)f2bf(acc[i][0]) | ((unsigned int)f2bf(acc[i][1]) << 16);
                pk.y = (unsigned int)f2bf(acc[i][2]) | ((unsigned int)f2bf(acc[i][3]) << 16);
                pk.z = (unsigned int)f2bf(acc[i][4]) | ((unsigned int)f2bf(acc[i][5]) << 16);
                pk.w = (unsigned int)f2bf(acc[i][6]) | ((unsigned int)f2bf(acc[i][7]) << 16);
                *(uint4*)(Cb + (size_t)node*HC + tn*8) = pk;
            }
        }
        float ats[8], atd[8];
        *(float4*)&ats[0] = *(const float4*)(att_s + tn*8);
        *(float4*)&ats[4] = *(const float4*)(att_s + tn*8 + 4);
        *(float4*)&atd[0] = *(const float4*)(att_d + tn*8);
        *(float4*)&atd[4] = *(const float4*)(att_d + tn*8 + 4);
        #pragma unroll
        for (int i = 0; i < 8; ++i){
            float sa = 0.f, sd = 0.f;
            #pragma unroll
            for (int j = 0; j < 8; ++j){
                sa = fmaf(acc[i][j], ats[j], sa);
                sd = fmaf(acc[i][j], atd[j], sd);
            }
            sa += __shfl_xor(sa, 1); sa += __shfl_xor(sa, 2); sa += __shfl_xor(sa, 4);
            sd += __shfl_xor(sd, 1); sd += __shfl_xor(sd, 2); sd += __shfl_xor(sd, 4);
            int node = m0 + tm*8 + i;
            if ((tn == 0 || tn == 8) && node < n){
                int head = tn >> 3;
                asrc[(size_t)node*2 + head] = sa;
                adst[(size_t)node*2 + head] = sd;
            }
        }
    }
}

// ----------------- aggregation: 4 nodes/block (1 wave each), h' in bf16 -----------------
__global__ __launch_bounds__(256) void aggregate_kernel(
        const unsigned short* __restrict__ h1b, const float* __restrict__ asrc, const float* __restrict__ adst,
        const int* __restrict__ rowptr, const int* __restrict__ colsrc,
        const float* __restrict__ bias, float* __restrict__ hout, int n)
{
    int i = blockIdx.x * 4 + (threadIdx.x >> 6);
    if (i >= n) return;
    int t = threadIdx.x & 63;         // 64 lanes, 2 channels each (one uint of 2 bf16)
    int head = t >> 5;
    float ad = adst[(size_t)i*2 + head];
    float ex = __expf(lrelu(asrc[(size_t)i*2 + head] + ad));   // self loop
    unsigned int hv = ((const unsigned int*)(h1b + (size_t)i * HC))[t];
    float acc0 = ex * bf_lo(hv), acc1 = ex * bf_hi(hv), D = ex;
    int e  = rowptr[i];
    int e1 = rowptr[i + 1];
    for (; e + 2 <= e1; e += 2){       // 2-way unroll: overlap dependent gather chains
        int s0 = colsrc[e], s1 = colsrc[e + 1];
        float a0 = asrc[(size_t)s0*2 + head];
        float a1 = asrc[(size_t)s1*2 + head];
        unsigned int v0 = ((const unsigned int*)(h1b + (size_t)s0 * HC))[t];
        unsigned int v1 = ((const unsigned int*)(h1b + (size_t)s1 * HC))[t];
        float ex0 = __expf(lrelu(a0 + ad));
        float ex1 = __expf(lrelu(a1 + ad));
        acc0 = fmaf(ex0, bf_lo(v0), acc0);
        acc1 = fmaf(ex0, bf_hi(v0), acc1);
        acc0 = fmaf(ex1, bf_lo(v1), acc0);
        acc1 = fmaf(ex1, bf_hi(v1), acc1);
        D += ex0 + ex1;
    }
    if (e < e1){
        int s = colsrc[e];
        float exx = __expf(lrelu(asrc[(size_t)s*2 + head] + ad));
        unsigned int v = ((const unsigned int*)(h1b + (size_t)s * HC))[t];
        acc0 = fmaf(exx, bf_lo(v), acc0);
        acc1 = fmaf(exx, bf_hi(v), acc1);
        D += exx;
    }
    float rD = 1.0f / D;
    float o0 = fmaxf(acc0 * rD + bias[2*t],     0.f);
    float o1 = fmaxf(acc1 * rD + bias[2*t + 1], 0.f);
    ((float2*)(hout + (size_t)i * HC))[t] = make_float2(o0, o1);
}

// ----------------- graph mean: two-level reduction, float4 per thread -----------------
__global__ __launch_bounds__(256) void mean_kernel(const float* __restrict__ h, float* __restrict__ g, int n){
    int t = threadIdx.x;
    int cq = t & 31;                   // channel quad: channels cq*4 .. cq*4+3
    int rl = t >> 5;                   // row lane 0..7
    float4 acc = make_float4(0.f, 0.f, 0.f, 0.f);
    for (int i = blockIdx.x * 8 + rl; i < n; i += gridDim.x * 8){
        float4 v = *(const float4*)(h + (size_t)i * HC + cq * 4);
        acc.x += v.x; acc.y += v.y; acc.z += v.z; acc.w += v.w;
    }
    __shared__ float4 red[256];
    red[t] = acc;
    __syncthreads();
    if (t < 128){
        float4 o = red[t + 128];
        red[t].x += o.x; red[t].y += o.y; red[t].z += o.z; red[t].w += o.w;
    }
    __syncthreads();
    if (t < 64){
        float4 o = red[t + 64];
        red[t].x += o.x; red[t].y += o.y; red[t].z += o.z; red[t].w += o.w;
    }
    __syncthreads();
    if (t < 32){
        float4 a = red[t], b = red[t + 32];
        atomicAdd(&g[t*4+0], a.x + b.x);
        atomicAdd(&g[t*4+1], a.y + b.y);
        atomicAdd(&g[t*4+2], a.z + b.z);
        atomicAdd(&g[t*4+3], a.w + b.w);
    }
}

// ----------------- vuln head: sigmoid(relu(h@wv1+bv1)@wv2+bv2), tiled -----------------
__global__ __launch_bounds__(256) void vuln_fused_kernel(
        const float* __restrict__ h, const float* __restrict__ wv1, const float* __restrict__ bv1,
        const float* __restrict__ wv2, const float* __restrict__ bv2,
        float* __restrict__ out, int n)
{
    __shared__ float As[32][132];
    __shared__ float Bs[32][64];
    int t = threadIdx.x;
    int m0 = blockIdx.x * 128;
    int tm = t >> 4, tn = t & 15;

    float acc[8][4];
    #pragma unroll
    for (int i = 0; i < 8; ++i)
        #pragma unroll
        for (int j = 0; j < 4; ++j) acc[i][j] = 0.f;

    for (int kc = 0; kc < 4; ++kc){
        int k0 = kc * 32;
        #pragma unroll
        for (int i = 0; i < 4; ++i){
            int f = i * 256 + t;
            int row = f >> 3, kq = f & 7;
            int gr = m0 + row; if (gr > n - 1) gr = n - 1;
            float4 v = *(const float4*)(h + (size_t)gr * HC + k0 + kq * 4);
            As[kq*4+0][row] = v.x; As[kq*4+1][row] = v.y; As[kq*4+2][row] = v.z; As[kq*4+3][row] = v.w;
        }
        #pragma unroll
        for (int i = 0; i < 2; ++i){
            int f = i * 256 + t;
            int kk = f >> 4, nq = f & 15;
            *(float4*)&Bs[kk][nq*4] = *(const float4*)(wv1 + (size_t)(k0 + kk) * 64 + nq * 4);
        }
        __syncthreads();
        #pragma unroll 4
        for (int k = 0; k < 32; ++k){
            float a[8], b[4];
            *(float4*)&a[0] = *(float4*)&As[k][tm*8];
            *(float4*)&a[4] = *(float4*)&As[k][tm*8+4];
            *(float4*)&b[0] = *(float4*)&Bs[k][tn*4];
            #pragma unroll
            for (int i = 0; i < 8; ++i)
                #pragma unroll
                for (int j = 0; j < 4; ++j) acc[i][j] = fmaf(a[i], b[j], acc[i][j]);
        }
        __syncthreads();
    }

    float bb[4], wv[4];
    *(float4*)&bb[0] = *(const float4*)(bv1 + tn*4);
    *(float4*)&wv[0] = *(const float4*)(wv2 + tn*4);
    float bv2v = bv2[0];
    #pragma unroll
    for (int i = 0; i < 8; ++i){
        float v = 0.f;
        #pragma unroll
        for (int j = 0; j < 4; ++j) v = fmaf(fmaxf(acc[i][j] + bb[j], 0.f), wv[j], v);
        v += __shfl_xor(v, 1); v += __shfl_xor(v, 2);
        v += __shfl_xor(v, 4); v += __shfl_xor(v, 8);
        int node = m0 + tm*8 + i;
        if (tn == 0 && node < n)
            out[1 + node] = 1.0f / (1.0f + __expf(-(v + bv2v)));
    }
}

// ----------------- path head (1 block) -----------------
__global__ __launch_bounds__(128) void path_kernel(
        const float* __restrict__ h, const float* __restrict__ g,
        const float* __restrict__ wp1, const float* __restrict__ bp1,
        const float* __restrict__ wp2, const float* __restrict__ bp2,
        const float* __restrict__ wp3, const float* __restrict__ bp3,
        float* __restrict__ out, int n)
{
    __shared__ float pc[256];
    __shared__ float p1[HC];
    __shared__ float p2[64];
    int t = threadIdx.x;              // 128
    pc[t]       = h[t];               // h[0,:]
    pc[128 + t] = g[t] * (1.0f / (float)n);
    __syncthreads();
    float a = bp1[t];
    for (int k = 0; k < 256; ++k) a = fmaf(pc[k], wp1[k * HC + t], a);
    p1[t] = fmaxf(a, 0.f);
    __syncthreads();
    if (t < 64){
        float a2 = bp2[t];
        for (int k = 0; k < HC; ++k) a2 = fmaf(p1[k], wp2[k * 64 + t], a2);
        p2[t] = fmaxf(a2, 0.f);
    }
    __syncthreads();
    if (t == 0){
        float a3 = bp3[0];
        for (int k = 0; k < 64; ++k) a3 = fmaf(p2[k], wp3[k], a3);
        out[0] = 1.0f / (1.0f + __expf(-a3));
        out[1 + n] = 0.f;             // esc = 0
    }
}

extern "C" void kernel_launch(void* const* d_in, const int* in_sizes, int n_in,
                              void* d_out, int out_size, void* d_ws, size_t ws_size,
                              hipStream_t stream)
{
    const float* x    = (const float*)d_in[0];
    const int*   ei   = (const int*)d_in[1];
    const float* w_n1 = (const float*)d_in[3];
    const float* b_n1 = (const float*)d_in[4];
    const float* w_n2 = (const float*)d_in[5];
    const float* b_n2 = (const float*)d_in[6];
    const float* conv_w = (const float*)d_in[9];
    const float* att_s  = (const float*)d_in[10];
    const float* att_d  = (const float*)d_in[11];
    const float* conv_b = (const float*)d_in[12];
    const float* wp1 = (const float*)d_in[13];
    const float* bp1 = (const float*)d_in[14];
    const float* wp2 = (const float*)d_in[15];
    const float* bp2 = (const float*)d_in[16];
    const float* wp3 = (const float*)d_in[17];
    const float* bp3 = (const float*)d_in[18];
    const float* wv1 = (const float*)d_in[19];
    const float* bv1 = (const float*)d_in[20];
    const float* wv2 = (const float*)d_in[21];
    const float* bv2 = (const float*)d_in[22];

    const int N = in_sizes[0] / 32;
    const int E = in_sizes[1] / 2;
    float* out = (float*)d_out;

    char* ws = (char*)d_ws;
    size_t off = 0;
    auto take = [&](size_t bytes) -> char* {
        char* p = ws + off;
        off += (bytes + 255) & ~(size_t)255;
        return p;
    };
    float* hA    = (float*)take((size_t)N * HC * 4);
    float* hB    = (float*)take((size_t)N * HC * 4);   // f32 hid OR bf16 h' (reused)
    float* asrc  = (float*)take((size_t)N * 2 * 4);
    float* adst  = (float*)take((size_t)N * 2 * 4);
    int*   rowptr= (int*)take((size_t)(N + 1) * 4);
    int*   cursor= (int*)take((size_t)N * 4);
    int*   colsrc= (int*)take((size_t)E * 4);
    float* g     = (float*)take(HC * 4);
    int nb = (N + 1023) / 1024;
    int*   bsum  = (int*)take((size_t)((nb + 63) & ~63) * 4);
    int*   boff  = (int*)take((size_t)((nb + 63) & ~63) * 4);
    unsigned short* hBb = (unsigned short*)hB;

    // --- CSR build (dst-sorted; reused across the 3 layers) ---
    hipMemsetAsync(cursor, 0, (size_t)N * 4, stream);
    count_kernel<<<(E + 255) / 256, 256, 0, stream>>>(ei, cursor, E);
    scan_part_kernel<<<nb, 256, 0, stream>>>(cursor, bsum, N);
    scan_top_kernel<<<1, 64, 0, stream>>>(bsum, boff, rowptr, nb, N);
    scan_fin_kernel<<<nb, 256, 0, stream>>>(cursor, boff, rowptr, N);
    hipMemsetAsync(cursor, 0, (size_t)N * 4, stream);
    scatter_kernel<<<(E + 255) / 256, 256, 0, stream>>>(ei, rowptr, cursor, colsrc, E);

    int nblk = (N + 127) / 128;
    // node encoder: hid (hB f32) = relu(x@w1+b1); hA = hid@w2 + b2
    enc1_kernel<<<nblk, 256, 0, stream>>>(x, w_n1, b_n1, hB, N);
    gemm_main_kernel<false><<<nblk, 256, 0, stream>>>(
        hB, w_n2, b_n2, nullptr, nullptr, hA, nullptr, nullptr, nullptr, N);

    for (int l = 0; l < 3; ++l){
        gemm_main_kernel<true><<<nblk, 256, 0, stream>>>(
            hA, conv_w + (size_t)l * HC * HC, nullptr,
            att_s + (size_t)l * HC, att_d + (size_t)l * HC,
            nullptr, hBb, asrc, adst, N);
        aggregate_kernel<<<(N + 3) / 4, 256, 0, stream>>>(
            hBb, asrc, adst, rowptr, colsrc, conv_b + (size_t)l * HC, hA, N);
    }

    hipMemsetAsync(g, 0, HC * 4, stream);
    mean_kernel<<<512, 256, 0, stream>>>(hA, g, N);
    vuln_fused_kernel<<<nblk, 256, 0, stream>>>(hA, wv1, bv1, wv2, bv2, out, N);
    path_kernel<<<1, 128, 0, stream>>>(hA, g, wp1, bp1, wp2, bp2, wp3, bp3, out, N);
}

// Round 5
// 474.209 us; speedup vs baseline: 1.0408x; 1.0408x over previous
//
#include <hip/hip_runtime.h>
#include <math.h>

#define HC 128
#define NSLOPE 0.2f

__device__ __forceinline__ float lrelu(float v){ return v > 0.f ? v : NSLOPE * v; }

// bf16 round-to-nearest-even pack / unpack
__device__ __forceinline__ unsigned short f2bf(float f){
    unsigned int b = __float_as_uint(f);
    b += 0x7FFFu + ((b >> 16) & 1u);
    return (unsigned short)(b >> 16);
}
__device__ __forceinline__ float bf_lo(unsigned int v){ return __uint_as_float(v << 16); }
__device__ __forceinline__ float bf_hi(unsigned int v){ return __uint_as_float(v & 0xFFFF0000u); }

// ----------------- CSR build (dst-sorted) -----------------
__global__ void count_kernel(const int* __restrict__ ei, int* __restrict__ cnt, int E){
    int e = blockIdx.x * blockDim.x + threadIdx.x;
    if (e < E) atomicAdd(&cnt[ei[E + e]], 1);
}

// S1: per-block (1024 nodes) partial sums
__global__ __launch_bounds__(256) void scan_part_kernel(
        const int* __restrict__ deg, int* __restrict__ bsum, int n)
{
    int t = threadIdx.x, lane = t & 63, wid = t >> 6;
    int base = blockIdx.x * 1024 + t * 4;
    int s = 0;
    #pragma unroll
    for (int j = 0; j < 4; ++j){ int i = base + j; if (i < n) s += deg[i]; }
    #pragma unroll
    for (int o = 1; o < 64; o <<= 1) s += __shfl_xor(s, o);
    __shared__ int red[4];
    if (lane == 0) red[wid] = s;
    __syncthreads();
    if (t == 0) bsum[blockIdx.x] = red[0] + red[1] + red[2] + red[3];
}

// S2: 1 wave scans the (<=64) block sums; writes exclusive offsets + rowptr[n]=total
__global__ __launch_bounds__(64) void scan_top_kernel(
        const int* __restrict__ bsum, int* __restrict__ boff, int* __restrict__ rowptr,
        int nb, int n)
{
    int t = threadIdx.x;
    int v = (t < nb) ? bsum[t] : 0;
    int incl = v;
    #pragma unroll
    for (int o = 1; o < 64; o <<= 1){ int u = __shfl_up(incl, o); if (t >= o) incl += u; }
    if (t < nb) boff[t] = incl - v;
    if (t == 63) rowptr[n] = incl;
}

// S3: per-block exclusive scan with global offset -> rowptr[0..n-1]
__global__ __launch_bounds__(256) void scan_fin_kernel(
        const int* __restrict__ deg, const int* __restrict__ boff,
        int* __restrict__ rowptr, int n)
{
    int t = threadIdx.x, lane = t & 63, wid = t >> 6;
    int base = blockIdx.x * 1024 + t * 4;
    int d[4]; int s = 0;
    #pragma unroll
    for (int j = 0; j < 4; ++j){ int i = base + j; d[j] = (i < n) ? deg[i] : 0; s += d[j]; }
    int incl = s;
    #pragma unroll
    for (int o = 1; o < 64; o <<= 1){ int u = __shfl_up(incl, o); if (lane >= o) incl += u; }
    __shared__ int wsum[4];
    if (lane == 63) wsum[wid] = incl;
    __syncthreads();
    int off = boff[blockIdx.x] + (incl - s);
    for (int w = 0; w < wid; ++w) off += wsum[w];
    #pragma unroll
    for (int j = 0; j < 4; ++j){
        int i = base + j;
        if (i < n) rowptr[i] = off;
        off += d[j];
    }
}

__global__ void scatter_kernel(const int* __restrict__ ei, const int* __restrict__ rowptr,
                               int* __restrict__ cursor, int* __restrict__ colsrc,
                               int* __restrict__ dstc, int E){
    int e = blockIdx.x * blockDim.x + threadIdx.x;
    if (e < E){
        int d = ei[E + e];
        int pos = rowptr[d] + atomicAdd(&cursor[d], 1);
        colsrc[pos] = ei[e];
        dstc[pos] = d;
    }
}

// ----------------- per-edge coefficient: exf[e][h] = exp(lrelu(asrc[s]+adst[d])) -----------------
__global__ __launch_bounds__(256) void edge_ex_kernel(
        const int* __restrict__ colsrc, const int* __restrict__ dstc,
        const float* __restrict__ asrc, const float* __restrict__ adst,
        float* __restrict__ exf, int E)
{
    int e = blockIdx.x * blockDim.x + threadIdx.x;
    if (e < E){
        int s = colsrc[e], d = dstc[e];
        float2 as = *(const float2*)(asrc + (size_t)s * 2);
        float2 ad = *(const float2*)(adst + (size_t)d * 2);
        float e0 = __expf(lrelu(as.x + ad.x));
        float e1 = __expf(lrelu(as.y + ad.y));
        *(float2*)(exf + (size_t)e * 2) = make_float2(e0, e1);
    }
}

// ----------------- node encoder stage 1: hid = relu(x@w1+b1), K=32 -----------------
__global__ __launch_bounds__(256) void enc1_kernel(
        const float* __restrict__ x, const float* __restrict__ w1, const float* __restrict__ b1,
        float* __restrict__ hid, int n)
{
    __shared__ float As[32][132];
    __shared__ float Bs[32][128];
    int t = threadIdx.x;
    int m0 = blockIdx.x * 128;
    int tm = t >> 4, tn = t & 15;

    #pragma unroll
    for (int i = 0; i < 4; ++i){
        int f = i * 256 + t;
        int row = f >> 3, kq = f & 7;
        int gr = m0 + row; if (gr > n - 1) gr = n - 1;
        float4 v = *(const float4*)(x + (size_t)gr * 32 + kq * 4);
        As[kq*4+0][row] = v.x; As[kq*4+1][row] = v.y; As[kq*4+2][row] = v.z; As[kq*4+3][row] = v.w;
    }
    #pragma unroll
    for (int i = 0; i < 4; ++i){
        int f = i * 256 + t;
        int kk = f >> 5, nq = f & 31;
        *(float4*)&Bs[kk][nq*4] = *(const float4*)(w1 + (size_t)kk * 128 + nq * 4);
    }
    __syncthreads();

    float acc[8][8];
    #pragma unroll
    for (int i = 0; i < 8; ++i)
        #pragma unroll
        for (int j = 0; j < 8; ++j) acc[i][j] = 0.f;

    #pragma unroll 4
    for (int k = 0; k < 32; ++k){
        float a[8], b[8];
        *(float4*)&a[0] = *(float4*)&As[k][tm*8];
        *(float4*)&a[4] = *(float4*)&As[k][tm*8+4];
        *(float4*)&b[0] = *(float4*)&Bs[k][tn*8];
        *(float4*)&b[4] = *(float4*)&Bs[k][tn*8+4];
        #pragma unroll
        for (int i = 0; i < 8; ++i)
            #pragma unroll
            for (int j = 0; j < 8; ++j) acc[i][j] = fmaf(a[i], b[j], acc[i][j]);
    }

    float bb[8];
    *(float4*)&bb[0] = *(const float4*)(b1 + tn*8);
    *(float4*)&bb[4] = *(const float4*)(b1 + tn*8 + 4);
    #pragma unroll
    for (int i = 0; i < 8; ++i){
        int node = m0 + tm*8 + i;
        if (node < n){
            float o[8];
            #pragma unroll
            for (int j = 0; j < 8; ++j) o[j] = fmaxf(acc[i][j] + bb[j], 0.f);
            *(float4*)(hid + (size_t)node*HC + tn*8)     = *(float4*)&o[0];
            *(float4*)(hid + (size_t)node*HC + tn*8 + 4) = *(float4*)&o[4];
        }
    }
}

// ----------------- main GEMM: C = A@W (+bias); ATT: bf16 C + fused att dots -----------------
template<bool ATT>
__global__ __launch_bounds__(256) void gemm_main_kernel(
        const float* __restrict__ A, const float* __restrict__ W, const float* __restrict__ bias,
        const float* __restrict__ att_s, const float* __restrict__ att_d,
        float* __restrict__ C, unsigned short* __restrict__ Cb,
        float* __restrict__ asrc, float* __restrict__ adst, int n)
{
    __shared__ float As[32][132];
    __shared__ float Bs[32][128];
    int t = threadIdx.x;
    int m0 = blockIdx.x * 128;
    int tm = t >> 4, tn = t & 15;

    float acc[8][8];
    #pragma unroll
    for (int i = 0; i < 8; ++i)
        #pragma unroll
        for (int j = 0; j < 8; ++j) acc[i][j] = 0.f;

    for (int kc = 0; kc < 4; ++kc){
        int k0 = kc * 32;
        #pragma unroll
        for (int i = 0; i < 4; ++i){
            int f = i * 256 + t;
            int row = f >> 3, kq = f & 7;
            int gr = m0 + row; if (gr > n - 1) gr = n - 1;
            float4 v = *(const float4*)(A + (size_t)gr * HC + k0 + kq * 4);
            As[kq*4+0][row] = v.x; As[kq*4+1][row] = v.y; As[kq*4+2][row] = v.z; As[kq*4+3][row] = v.w;
        }
        #pragma unroll
        for (int i = 0; i < 4; ++i){
            int f = i * 256 + t;
            int kk = f >> 5, nq = f & 31;
            *(float4*)&Bs[kk][nq*4] = *(const float4*)(W + (size_t)(k0 + kk) * 128 + nq * 4);
        }
        __syncthreads();
        #pragma unroll 4
        for (int k = 0; k < 32; ++k){
            float a[8], b[8];
            *(float4*)&a[0] = *(float4*)&As[k][tm*8];
            *(float4*)&a[4] = *(float4*)&As[k][tm*8+4];
            *(float4*)&b[0] = *(float4*)&Bs[k][tn*8];
            *(float4*)&b[4] = *(float4*)&Bs[k][tn*8+4];
            #pragma unroll
            for (int i = 0; i < 8; ++i)
                #pragma unroll
                for (int j = 0; j < 8; ++j) acc[i][j] = fmaf(a[i], b[j], acc[i][j]);
        }
        __syncthreads();
    }

    if (!ATT){
        float bb[8];
        *(float4*)&bb[0] = *(const float4*)(bias + tn*8);
        *(float4*)&bb[4] = *(const float4*)(bias + tn*8 + 4);
        #pragma unroll
        for (int i = 0; i < 8; ++i){
            int node = m0 + tm*8 + i;
            if (node < n){
                float o[8];
                #pragma unroll
                for (int j = 0; j < 8; ++j) o[j] = acc[i][j] + bb[j];
                *(float4*)(C + (size_t)node*HC + tn*8)     = *(float4*)&o[0];
                *(float4*)(C + (size_t)node*HC + tn*8 + 4) = *(float4*)&o[4];
            }
        }
    } else {
        #pragma unroll
        for (int i = 0; i < 8; ++i){
            int node = m0 + tm*8 + i;
            if (node < n){
                uint4 pk;
                pk.x = (unsigned int)f2bf(acc[i][0]) | ((unsigned int)f2bf(acc[i][1]) << 16);
                pk.y = (unsigned int)f2bf(acc[i][2]) | ((unsigned int)f2bf(acc[i][3]) << 16);
                pk.z = (unsigned int)f2bf(acc[i][4]) | ((unsigned int)f2bf(acc[i][5]) << 16);
                pk.w = (unsigned int)f2bf(acc[i][6]) | ((unsigned int)f2bf(acc[i][7]) << 16);
                *(uint4*)(Cb + (size_t)node*HC + tn*8) = pk;
            }
        }
        float ats[8], atd[8];
        *(float4*)&ats[0] = *(const float4*)(att_s + tn*8);
        *(float4*)&ats[4] = *(const float4*)(att_s + tn*8 + 4);
        *(float4*)&atd[0] = *(const float4*)(att_d + tn*8);
        *(float4*)&atd[4] = *(const float4*)(att_d + tn*8 + 4);
        #pragma unroll
        for (int i = 0; i < 8; ++i){
            float sa = 0.f, sd = 0.f;
            #pragma unroll
            for (int j = 0; j < 8; ++j){
                sa = fmaf(acc[i][j], ats[j], sa);
                sd = fmaf(acc[i][j], atd[j], sd);
            }
            sa += __shfl_xor(sa, 1); sa += __shfl_xor(sa, 2); sa += __shfl_xor(sa, 4);
            sd += __shfl_xor(sd, 1); sd += __shfl_xor(sd, 2); sd += __shfl_xor(sd, 4);
            int node = m0 + tm*8 + i;
            if ((tn == 0 || tn == 8) && node < n){
                int head = tn >> 3;
                asrc[(size_t)node*2 + head] = sa;
                adst[(size_t)node*2 + head] = sd;
            }
        }
    }
}

// ----------------- aggregation: 1 wave/node; coef precomputed in exf -----------------
__global__ __launch_bounds__(64) void aggregate_kernel(
        const unsigned short* __restrict__ h1b, const float* __restrict__ asrc, const float* __restrict__ adst,
        const int* __restrict__ rowptr, const int* __restrict__ colsrc, const float* __restrict__ exf,
        const float* __restrict__ bias, float* __restrict__ hout, int n)
{
    int i = blockIdx.x;
    if (i >= n) return;
    int t = threadIdx.x;              // 64 lanes, 2 channels each (one uint of 2 bf16)
    int head = t >> 5;
    // self loop (GATConv add_self_loops=True)
    float ad = adst[(size_t)i*2 + head];
    float ex = __expf(lrelu(asrc[(size_t)i*2 + head] + ad));
    unsigned int hv = ((const unsigned int*)(h1b + (size_t)i * HC))[t];
    float acc0 = ex * bf_lo(hv), acc1 = ex * bf_hi(hv), D = ex;
    int e  = rowptr[i];
    int e1 = rowptr[i + 1];
    for (; e + 2 <= e1; e += 2){       // 2-way unroll: overlap gather chains
        int s0 = colsrc[e], s1 = colsrc[e + 1];
        float ex0 = exf[(size_t)e*2 + head];
        float ex1 = exf[(size_t)(e+1)*2 + head];
        unsigned int v0 = ((const unsigned int*)(h1b + (size_t)s0 * HC))[t];
        unsigned int v1 = ((const unsigned int*)(h1b + (size_t)s1 * HC))[t];
        acc0 = fmaf(ex0, bf_lo(v0), acc0);
        acc1 = fmaf(ex0, bf_hi(v0), acc1);
        acc0 = fmaf(ex1, bf_lo(v1), acc0);
        acc1 = fmaf(ex1, bf_hi(v1), acc1);
        D += ex0 + ex1;
    }
    if (e < e1){
        int s = colsrc[e];
        float exx = exf[(size_t)e*2 + head];
        unsigned int v = ((const unsigned int*)(h1b + (size_t)s * HC))[t];
        acc0 = fmaf(exx, bf_lo(v), acc0);
        acc1 = fmaf(exx, bf_hi(v), acc1);
        D += exx;
    }
    float rD = 1.0f / D;
    float o0 = fmaxf(acc0 * rD + bias[2*t],     0.f);
    float o1 = fmaxf(acc1 * rD + bias[2*t + 1], 0.f);
    ((float2*)(hout + (size_t)i * HC))[t] = make_float2(o0, o1);
}

// ----------------- graph mean: two-level reduction, float4 per thread -----------------
__global__ __launch_bounds__(256) void mean_kernel(const float* __restrict__ h, float* __restrict__ g, int n){
    int t = threadIdx.x;
    int cq = t & 31;                   // channel quad: channels cq*4 .. cq*4+3
    int rl = t >> 5;                   // row lane 0..7
    float4 acc = make_float4(0.f, 0.f, 0.f, 0.f);
    for (int i = blockIdx.x * 8 + rl; i < n; i += gridDim.x * 8){
        float4 v = *(const float4*)(h + (size_t)i * HC + cq * 4);
        acc.x += v.x; acc.y += v.y; acc.z += v.z; acc.w += v.w;
    }
    __shared__ float4 red[256];
    red[t] = acc;
    __syncthreads();
    if (t < 128){
        float4 o = red[t + 128];
        red[t].x += o.x; red[t].y += o.y; red[t].z += o.z; red[t].w += o.w;
    }
    __syncthreads();
    if (t < 64){
        float4 o = red[t + 64];
        red[t].x += o.x; red[t].y += o.y; red[t].z += o.z; red[t].w += o.w;
    }
    __syncthreads();
    if (t < 32){
        float4 a = red[t], b = red[t + 32];
        atomicAdd(&g[t*4+0], a.x + b.x);
        atomicAdd(&g[t*4+1], a.y + b.y);
        atomicAdd(&g[t*4+2], a.z + b.z);
        atomicAdd(&g[t*4+3], a.w + b.w);
    }
}

// ----------------- vuln head: sigmoid(relu(h@wv1+bv1)@wv2+bv2), tiled -----------------
__global__ __launch_bounds__(256) void vuln_fused_kernel(
        const float* __restrict__ h, const float* __restrict__ wv1, const float* __restrict__ bv1,
        const float* __restrict__ wv2, const float* __restrict__ bv2,
        float* __restrict__ out, int n)
{
    __shared__ float As[32][132];
    __shared__ float Bs[32][64];
    int t = threadIdx.x;
    int m0 = blockIdx.x * 128;
    int tm = t >> 4, tn = t & 15;

    float acc[8][4];
    #pragma unroll
    for (int i = 0; i < 8; ++i)
        #pragma unroll
        for (int j = 0; j < 4; ++j) acc[i][j] = 0.f;

    for (int kc = 0; kc < 4; ++kc){
        int k0 = kc * 32;
        #pragma unroll
        for (int i = 0; i < 4; ++i){
            int f = i * 256 + t;
            int row = f >> 3, kq = f & 7;
            int gr = m0 + row; if (gr > n - 1) gr = n - 1;
            float4 v = *(const float4*)(h + (size_t)gr * HC + k0 + kq * 4);
            As[kq*4+0][row] = v.x; As[kq*4+1][row] = v.y; As[kq*4+2][row] = v.z; As[kq*4+3][row] = v.w;
        }
        #pragma unroll
        for (int i = 0; i < 2; ++i){
            int f = i * 256 + t;
            int kk = f >> 4, nq = f & 15;
            *(float4*)&Bs[kk][nq*4] = *(const float4*)(wv1 + (size_t)(k0 + kk) * 64 + nq * 4);
        }
        __syncthreads();
        #pragma unroll 4
        for (int k = 0; k < 32; ++k){
            float a[8], b[4];
            *(float4*)&a[0] = *(float4*)&As[k][tm*8];
            *(float4*)&a[4] = *(float4*)&As[k][tm*8+4];
            *(float4*)&b[0] = *(float4*)&Bs[k][tn*4];
            #pragma unroll
            for (int i = 0; i < 8; ++i)
                #pragma unroll
                for (int j = 0; j < 4; ++j) acc[i][j] = fmaf(a[i], b[j], acc[i][j]);
        }
        __syncthreads();
    }

    float bb[4], wv[4];
    *(float4*)&bb[0] = *(const float4*)(bv1 + tn*4);
    *(float4*)&wv[0] = *(const float4*)(wv2 + tn*4);
    float bv2v = bv2[0];
    #pragma unroll
    for (int i = 0; i < 8; ++i){
        float v = 0.f;
        #pragma unroll
        for (int j = 0; j < 4; ++j) v = fmaf(fmaxf(acc[i][j] + bb[j], 0.f), wv[j], v);
        v += __shfl_xor(v, 1); v += __shfl_xor(v, 2);
        v += __shfl_xor(v, 4); v += __shfl_xor(v, 8);
        int node = m0 + tm*8 + i;
        if (tn == 0 && node < n)
            out[1 + node] = 1.0f / (1.0f + __expf(-(v + bv2v)));
    }
}

// ----------------- path head (1 block) -----------------
__global__ __launch_bounds__(128) void path_kernel(
        const float* __restrict__ h, const float* __restrict__ g,
        const float* __restrict__ wp1, const float* __restrict__ bp1,
        const float* __restrict__ wp2, const float* __restrict__ bp2,
        const float* __restrict__ wp3, const float* __restrict__ bp3,
        float* __restrict__ out, int n)
{
    __shared__ float pc[256];
    __shared__ float p1[HC];
    __shared__ float p2[64];
    int t = threadIdx.x;              // 128
    pc[t]       = h[t];               // h[0,:]
    pc[128 + t] = g[t] * (1.0f / (float)n);
    __syncthreads();
    float a = bp1[t];
    for (int k = 0; k < 256; ++k) a = fmaf(pc[k], wp1[k * HC + t], a);
    p1[t] = fmaxf(a, 0.f);
    __syncthreads();
    if (t < 64){
        float a2 = bp2[t];
        for (int k = 0; k < HC; ++k) a2 = fmaf(p1[k], wp2[k * 64 + t], a2);
        p2[t] = fmaxf(a2, 0.f);
    }
    __syncthreads();
    if (t == 0){
        float a3 = bp3[0];
        for (int k = 0; k < 64; ++k) a3 = fmaf(p2[k], wp3[k], a3);
        out[0] = 1.0f / (1.0f + __expf(-a3));
        out[1 + n] = 0.f;             // esc = 0
    }
}

extern "C" void kernel_launch(void* const* d_in, const int* in_sizes, int n_in,
                              void* d_out, int out_size, void* d_ws, size_t ws_size,
                              hipStream_t stream)
{
    const float* x    = (const float*)d_in[0];
    const int*   ei   = (const int*)d_in[1];
    const float* w_n1 = (const float*)d_in[3];
    const float* b_n1 = (const float*)d_in[4];
    const float* w_n2 = (const float*)d_in[5];
    const float* b_n2 = (const float*)d_in[6];
    const float* conv_w = (const float*)d_in[9];
    const float* att_s  = (const float*)d_in[10];
    const float* att_d  = (const float*)d_in[11];
    const float* conv_b = (const float*)d_in[12];
    const float* wp1 = (const float*)d_in[13];
    const float* bp1 = (const float*)d_in[14];
    const float* wp2 = (const float*)d_in[15];
    const float* bp2 = (const float*)d_in[16];
    const float* wp3 = (const float*)d_in[17];
    const float* bp3 = (const float*)d_in[18];
    const float* wv1 = (const float*)d_in[19];
    const float* bv1 = (const float*)d_in[20];
    const float* wv2 = (const float*)d_in[21];
    const float* bv2 = (const float*)d_in[22];

    const int N = in_sizes[0] / 32;
    const int E = in_sizes[1] / 2;
    float* out = (float*)d_out;

    char* ws = (char*)d_ws;
    size_t off = 0;
    auto take = [&](size_t bytes) -> char* {
        char* p = ws + off;
        off += (bytes + 255) & ~(size_t)255;
        return p;
    };
    float* hA    = (float*)take((size_t)N * HC * 4);
    float* hB    = (float*)take((size_t)N * HC * 4);   // f32 hid OR bf16 h' (reused)
    float* asrc  = (float*)take((size_t)N * 2 * 4);
    float* adst  = (float*)take((size_t)N * 2 * 4);
    int*   rowptr= (int*)take((size_t)(N + 1) * 4);
    int*   cursor= (int*)take((size_t)N * 4);
    int*   colsrc= (int*)take((size_t)E * 4);
    int*   dstc  = (int*)take((size_t)E * 4);
    float* exf   = (float*)take((size_t)E * 2 * 4);
    float* g     = (float*)take(HC * 4);
    int nb = (N + 1023) / 1024;
    int*   bsum  = (int*)take((size_t)((nb + 63) & ~63) * 4);
    int*   boff  = (int*)take((size_t)((nb + 63) & ~63) * 4);
    unsigned short* hBb = (unsigned short*)hB;

    // --- CSR build (dst-sorted; reused across the 3 layers) ---
    hipMemsetAsync(cursor, 0, (size_t)N * 4, stream);
    count_kernel<<<(E + 255) / 256, 256, 0, stream>>>(ei, cursor, E);
    scan_part_kernel<<<nb, 256, 0, stream>>>(cursor, bsum, N);
    scan_top_kernel<<<1, 64, 0, stream>>>(bsum, boff, rowptr, nb, N);
    scan_fin_kernel<<<nb, 256, 0, stream>>>(cursor, boff, rowptr, N);
    hipMemsetAsync(cursor, 0, (size_t)N * 4, stream);
    scatter_kernel<<<(E + 255) / 256, 256, 0, stream>>>(ei, rowptr, cursor, colsrc, dstc, E);

    int nblk = (N + 127) / 128;
    // node encoder: hid (hB f32) = relu(x@w1+b1); hA = hid@w2 + b2
    enc1_kernel<<<nblk, 256, 0, stream>>>(x, w_n1, b_n1, hB, N);
    gemm_main_kernel<false><<<nblk, 256, 0, stream>>>(
        hB, w_n2, b_n2, nullptr, nullptr, hA, nullptr, nullptr, nullptr, N);

    for (int l = 0; l < 3; ++l){
        gemm_main_kernel<true><<<nblk, 256, 0, stream>>>(
            hA, conv_w + (size_t)l * HC * HC, nullptr,
            att_s + (size_t)l * HC, att_d + (size_t)l * HC,
            nullptr, hBb, asrc, adst, N);
        edge_ex_kernel<<<(E + 255) / 256, 256, 0, stream>>>(
            colsrc, dstc, asrc, adst, exf, E);
        aggregate_kernel<<<N, 64, 0, stream>>>(
            hBb, asrc, adst, rowptr, colsrc, exf, conv_b + (size_t)l * HC, hA, N);
    }

    hipMemsetAsync(g, 0, HC * 4, stream);
    mean_kernel<<<512, 256, 0, stream>>>(hA, g, N);
    vuln_fused_kernel<<<nblk, 256, 0, stream>>>(hA, wv1, bv1, wv2, bv2, out, N);
    path_kernel<<<1, 128, 0, stream>>>(hA, g, wp1, bp1, wp2, bp2, wp3, bp3, out, N);
}

// Round 6
// 448.110 us; speedup vs baseline: 1.1015x; 1.0582x over previous
//
#include <hip/hip_runtime.h>
#include <math.h>

#define HC 128
#define NSLOPE 0.2f

__device__ __forceinline__ float lrelu(float v){ return v > 0.f ? v : NSLOPE * v; }

// bf16 round-to-nearest-even pack / unpack
__device__ __forceinline__ unsigned short f2bf(float f){
    unsigned int b = __float_as_uint(f);
    b += 0x7FFFu + ((b >> 16) & 1u);
    return (unsigned short)(b >> 16);
}
__device__ __forceinline__ float bf_lo(unsigned int v){ return __uint_as_float(v << 16); }
__device__ __forceinline__ float bf_hi(unsigned int v){ return __uint_as_float(v & 0xFFFF0000u); }

// ----------------- CSR build (dst-sorted) -----------------
__global__ void count_kernel(const int* __restrict__ ei, int* __restrict__ cnt, int E){
    int e = blockIdx.x * blockDim.x + threadIdx.x;
    if (e < E) atomicAdd(&cnt[ei[E + e]], 1);
}

// S1: per-block (1024 nodes) partial sums
__global__ __launch_bounds__(256) void scan_part_kernel(
        const int* __restrict__ deg, int* __restrict__ bsum, int n)
{
    int t = threadIdx.x, lane = t & 63, wid = t >> 6;
    int base = blockIdx.x * 1024 + t * 4;
    int s = 0;
    #pragma unroll
    for (int j = 0; j < 4; ++j){ int i = base + j; if (i < n) s += deg[i]; }
    #pragma unroll
    for (int o = 1; o < 64; o <<= 1) s += __shfl_xor(s, o);
    __shared__ int red[4];
    if (lane == 0) red[wid] = s;
    __syncthreads();
    if (t == 0) bsum[blockIdx.x] = red[0] + red[1] + red[2] + red[3];
}

// S2: 1 wave scans the (<=64) block sums; writes exclusive offsets + rowptr[n]=total
__global__ __launch_bounds__(64) void scan_top_kernel(
        const int* __restrict__ bsum, int* __restrict__ boff, int* __restrict__ rowptr,
        int nb, int n)
{
    int t = threadIdx.x;
    int v = (t < nb) ? bsum[t] : 0;
    int incl = v;
    #pragma unroll
    for (int o = 1; o < 64; o <<= 1){ int u = __shfl_up(incl, o); if (t >= o) incl += u; }
    if (t < nb) boff[t] = incl - v;
    if (t == 63) rowptr[n] = incl;
}

// S3: per-block exclusive scan with global offset -> rowptr[0..n-1]
__global__ __launch_bounds__(256) void scan_fin_kernel(
        const int* __restrict__ deg, const int* __restrict__ boff,
        int* __restrict__ rowptr, int n)
{
    int t = threadIdx.x, lane = t & 63, wid = t >> 6;
    int base = blockIdx.x * 1024 + t * 4;
    int d[4]; int s = 0;
    #pragma unroll
    for (int j = 0; j < 4; ++j){ int i = base + j; d[j] = (i < n) ? deg[i] : 0; s += d[j]; }
    int incl = s;
    #pragma unroll
    for (int o = 1; o < 64; o <<= 1){ int u = __shfl_up(incl, o); if (lane >= o) incl += u; }
    __shared__ int wsum[4];
    if (lane == 63) wsum[wid] = incl;
    __syncthreads();
    int off = boff[blockIdx.x] + (incl - s);
    for (int w = 0; w < wid; ++w) off += wsum[w];
    #pragma unroll
    for (int j = 0; j < 4; ++j){
        int i = base + j;
        if (i < n) rowptr[i] = off;
        off += d[j];
    }
}

__global__ void scatter_kernel(const int* __restrict__ ei, const int* __restrict__ rowptr,
                               int* __restrict__ cursor, int* __restrict__ colsrc, int E){
    int e = blockIdx.x * blockDim.x + threadIdx.x;
    if (e < E){
        int d = ei[E + e];
        int pos = rowptr[d] + atomicAdd(&cursor[d], 1);
        colsrc[pos] = ei[e];
    }
}

// ----------------- node encoder stage 1: hid = relu(x@w1+b1), K=32 -----------------
__global__ __launch_bounds__(256) void enc1_kernel(
        const float* __restrict__ x, const float* __restrict__ w1, const float* __restrict__ b1,
        float* __restrict__ hid, int n)
{
    __shared__ float As[32][132];
    __shared__ float Bs[32][128];
    int t = threadIdx.x;
    int m0 = blockIdx.x * 128;
    int tm = t >> 4, tn = t & 15;

    #pragma unroll
    for (int i = 0; i < 4; ++i){
        int f = i * 256 + t;
        int row = f >> 3, kq = f & 7;
        int gr = m0 + row; if (gr > n - 1) gr = n - 1;
        float4 v = *(const float4*)(x + (size_t)gr * 32 + kq * 4);
        As[kq*4+0][row] = v.x; As[kq*4+1][row] = v.y; As[kq*4+2][row] = v.z; As[kq*4+3][row] = v.w;
    }
    #pragma unroll
    for (int i = 0; i < 4; ++i){
        int f = i * 256 + t;
        int kk = f >> 5, nq = f & 31;
        *(float4*)&Bs[kk][nq*4] = *(const float4*)(w1 + (size_t)kk * 128 + nq * 4);
    }
    __syncthreads();

    float acc[8][8];
    #pragma unroll
    for (int i = 0; i < 8; ++i)
        #pragma unroll
        for (int j = 0; j < 8; ++j) acc[i][j] = 0.f;

    #pragma unroll 4
    for (int k = 0; k < 32; ++k){
        float a[8], b[8];
        *(float4*)&a[0] = *(float4*)&As[k][tm*8];
        *(float4*)&a[4] = *(float4*)&As[k][tm*8+4];
        *(float4*)&b[0] = *(float4*)&Bs[k][tn*8];
        *(float4*)&b[4] = *(float4*)&Bs[k][tn*8+4];
        #pragma unroll
        for (int i = 0; i < 8; ++i)
            #pragma unroll
            for (int j = 0; j < 8; ++j) acc[i][j] = fmaf(a[i], b[j], acc[i][j]);
    }

    float bb[8];
    *(float4*)&bb[0] = *(const float4*)(b1 + tn*8);
    *(float4*)&bb[4] = *(const float4*)(b1 + tn*8 + 4);
    #pragma unroll
    for (int i = 0; i < 8; ++i){
        int node = m0 + tm*8 + i;
        if (node < n){
            float o[8];
            #pragma unroll
            for (int j = 0; j < 8; ++j) o[j] = fmaxf(acc[i][j] + bb[j], 0.f);
            *(float4*)(hid + (size_t)node*HC + tn*8)     = *(float4*)&o[0];
            *(float4*)(hid + (size_t)node*HC + tn*8 + 4) = *(float4*)&o[4];
        }
    }
}

// ----------------- main GEMM: C = A@W (+bias); ATT: bf16 C + fused att dots -----------------
template<bool ATT>
__global__ __launch_bounds__(256) void gemm_main_kernel(
        const float* __restrict__ A, const float* __restrict__ W, const float* __restrict__ bias,
        const float* __restrict__ att_s, const float* __restrict__ att_d,
        float* __restrict__ C, unsigned short* __restrict__ Cb,
        float* __restrict__ asrc, float* __restrict__ adst, int n)
{
    __shared__ float As[32][132];
    __shared__ float Bs[32][128];
    int t = threadIdx.x;
    int m0 = blockIdx.x * 128;
    int tm = t >> 4, tn = t & 15;

    float acc[8][8];
    #pragma unroll
    for (int i = 0; i < 8; ++i)
        #pragma unroll
        for (int j = 0; j < 8; ++j) acc[i][j] = 0.f;

    for (int kc = 0; kc < 4; ++kc){
        int k0 = kc * 32;
        #pragma unroll
        for (int i = 0; i < 4; ++i){
            int f = i * 256 + t;
            int row = f >> 3, kq = f & 7;
            int gr = m0 + row; if (gr > n - 1) gr = n - 1;
            float4 v = *(const float4*)(A + (size_t)gr * HC + k0 + kq * 4);
            As[kq*4+0][row] = v.x; As[kq*4+1][row] = v.y; As[kq*4+2][row] = v.z; As[kq*4+3][row] = v.w;
        }
        #pragma unroll
        for (int i = 0; i < 4; ++i){
            int f = i * 256 + t;
            int kk = f >> 5, nq = f & 31;
            *(float4*)&Bs[kk][nq*4] = *(const float4*)(W + (size_t)(k0 + kk) * 128 + nq * 4);
        }
        __syncthreads();
        #pragma unroll 4
        for (int k = 0; k < 32; ++k){
            float a[8], b[8];
            *(float4*)&a[0] = *(float4*)&As[k][tm*8];
            *(float4*)&a[4] = *(float4*)&As[k][tm*8+4];
            *(float4*)&b[0] = *(float4*)&Bs[k][tn*8];
            *(float4*)&b[4] = *(float4*)&Bs[k][tn*8+4];
            #pragma unroll
            for (int i = 0; i < 8; ++i)
                #pragma unroll
                for (int j = 0; j < 8; ++j) acc[i][j] = fmaf(a[i], b[j], acc[i][j]);
        }
        __syncthreads();
    }

    if (!ATT){
        float bb[8];
        *(float4*)&bb[0] = *(const float4*)(bias + tn*8);
        *(float4*)&bb[4] = *(const float4*)(bias + tn*8 + 4);
        #pragma unroll
        for (int i = 0; i < 8; ++i){
            int node = m0 + tm*8 + i;
            if (node < n){
                float o[8];
                #pragma unroll
                for (int j = 0; j < 8; ++j) o[j] = acc[i][j] + bb[j];
                *(float4*)(C + (size_t)node*HC + tn*8)     = *(float4*)&o[0];
                *(float4*)(C + (size_t)node*HC + tn*8 + 4) = *(float4*)&o[4];
            }
        }
    } else {
        #pragma unroll
        for (int i = 0; i < 8; ++i){
            int node = m0 + tm*8 + i;
            if (node < n){
                uint4 pk;
                pk.x = (unsigned int)f2bf(acc[i][0]) | ((unsigned int)f2bf(acc[i][1]) << 16);
                pk.y = (unsigned int)f2bf(acc[i][2]) | ((unsigned int)f2bf(acc[i][3]) << 16);
                pk.z = (unsigned int)f2bf(acc[i][4]) | ((unsigned int)f2bf(acc[i][5]) << 16);
                pk.w = (unsigned int)f2bf(acc[i][6]) | ((unsigned int)f2bf(acc[i][7]) << 16);
                *(uint4*)(Cb + (size_t)node*HC + tn*8) = pk;
            }
        }
        float ats[8], atd[8];
        *(float4*)&ats[0] = *(const float4*)(att_s + tn*8);
        *(float4*)&ats[4] = *(const float4*)(att_s + tn*8 + 4);
        *(float4*)&atd[0] = *(const float4*)(att_d + tn*8);
        *(float4*)&atd[4] = *(const float4*)(att_d + tn*8 + 4);
        #pragma unroll
        for (int i = 0; i < 8; ++i){
            float sa = 0.f, sd = 0.f;
            #pragma unroll
            for (int j = 0; j < 8; ++j){
                sa = fmaf(acc[i][j], ats[j], sa);
                sd = fmaf(acc[i][j], atd[j], sd);
            }
            sa += __shfl_xor(sa, 1); sa += __shfl_xor(sa, 2); sa += __shfl_xor(sa, 4);
            sd += __shfl_xor(sd, 1); sd += __shfl_xor(sd, 2); sd += __shfl_xor(sd, 4);
            int node = m0 + tm*8 + i;
            if ((tn == 0 || tn == 8) && node < n){
                int head = tn >> 3;
                asrc[(size_t)node*2 + head] = sa;
                adst[(size_t)node*2 + head] = sd;
            }
        }
    }
}

// ----------------- aggregation: 1 wave/node; exp computed once/edge in-wave -----------------
// 64-edge chunks: phase A (lane l = edge e+l) computes exp(lrelu(asrc[s]+adst[i])) for
// both heads; phase B broadcasts (s, ex0, ex1) via shfl and gathers h' rows.
__global__ __launch_bounds__(64) void aggregate_kernel(
        const unsigned short* __restrict__ h1b, const float* __restrict__ asrc, const float* __restrict__ adst,
        const int* __restrict__ rowptr, const int* __restrict__ colsrc,
        const float* __restrict__ bias, float* __restrict__ hout, int n)
{
    int i = blockIdx.x;
    if (i >= n) return;
    int t = threadIdx.x;              // 64 lanes, 2 channels each (one uint of 2 bf16)
    int head = t >> 5;
    float2 adv = *(const float2*)(adst + (size_t)i * 2);
    float2 asv = *(const float2*)(asrc + (size_t)i * 2);
    float ads = head ? adv.y : adv.x;
    // self loop (GATConv add_self_loops=True)
    float exs = __expf(lrelu((head ? asv.y : asv.x) + ads));
    unsigned int hv = ((const unsigned int*)(h1b + (size_t)i * HC))[t];
    float acc0 = exs * bf_lo(hv), acc1 = exs * bf_hi(hv), D = exs;

    int e  = rowptr[i];
    int e1 = rowptr[i + 1];
    while (e < e1){
        int m = e1 - e; if (m > 64) m = 64;
        int   sl  = 0;
        float ex0 = 0.f, ex1 = 0.f;
        if (t < m){
            sl = colsrc[e + t];                       // coalesced
            float2 as = *(const float2*)(asrc + (size_t)sl * 2);
            ex0 = __expf(lrelu(as.x + adv.x));
            ex1 = __expf(lrelu(as.y + adv.y));
        }
        int j = 0;
        for (; j + 2 <= m; j += 2){
            int   sa  = __shfl(sl,  j),     sb  = __shfl(sl,  j + 1);
            float ea0 = __shfl(ex0, j),     eb0 = __shfl(ex0, j + 1);
            float ea1 = __shfl(ex1, j),     eb1 = __shfl(ex1, j + 1);
            unsigned int va = ((const unsigned int*)(h1b + (size_t)sa * HC))[t];
            unsigned int vb = ((const unsigned int*)(h1b + (size_t)sb * HC))[t];
            float ea = head ? ea1 : ea0;
            float eb = head ? eb1 : eb0;
            acc0 = fmaf(ea, bf_lo(va), acc0);
            acc1 = fmaf(ea, bf_hi(va), acc1);
            acc0 = fmaf(eb, bf_lo(vb), acc0);
            acc1 = fmaf(eb, bf_hi(vb), acc1);
            D += ea + eb;
        }
        if (j < m){
            int   sa  = __shfl(sl,  j);
            float ea0 = __shfl(ex0, j);
            float ea1 = __shfl(ex1, j);
            unsigned int va = ((const unsigned int*)(h1b + (size_t)sa * HC))[t];
            float ea = head ? ea1 : ea0;
            acc0 = fmaf(ea, bf_lo(va), acc0);
            acc1 = fmaf(ea, bf_hi(va), acc1);
            D += ea;
        }
        e += m;
    }
    float rD = 1.0f / D;
    float o0 = fmaxf(acc0 * rD + bias[2*t],     0.f);
    float o1 = fmaxf(acc1 * rD + bias[2*t + 1], 0.f);
    ((float2*)(hout + (size_t)i * HC))[t] = make_float2(o0, o1);
}

// ----------------- graph mean: two-level reduction, float4 per thread -----------------
__global__ __launch_bounds__(256) void mean_kernel(const float* __restrict__ h, float* __restrict__ g, int n){
    int t = threadIdx.x;
    int cq = t & 31;                   // channel quad: channels cq*4 .. cq*4+3
    int rl = t >> 5;                   // row lane 0..7
    float4 acc = make_float4(0.f, 0.f, 0.f, 0.f);
    for (int i = blockIdx.x * 8 + rl; i < n; i += gridDim.x * 8){
        float4 v = *(const float4*)(h + (size_t)i * HC + cq * 4);
        acc.x += v.x; acc.y += v.y; acc.z += v.z; acc.w += v.w;
    }
    __shared__ float4 red[256];
    red[t] = acc;
    __syncthreads();
    if (t < 128){
        float4 o = red[t + 128];
        red[t].x += o.x; red[t].y += o.y; red[t].z += o.z; red[t].w += o.w;
    }
    __syncthreads();
    if (t < 64){
        float4 o = red[t + 64];
        red[t].x += o.x; red[t].y += o.y; red[t].z += o.z; red[t].w += o.w;
    }
    __syncthreads();
    if (t < 32){
        float4 a = red[t], b = red[t + 32];
        atomicAdd(&g[t*4+0], a.x + b.x);
        atomicAdd(&g[t*4+1], a.y + b.y);
        atomicAdd(&g[t*4+2], a.z + b.z);
        atomicAdd(&g[t*4+3], a.w + b.w);
    }
}

// ----------------- vuln head: sigmoid(relu(h@wv1+bv1)@wv2+bv2), tiled -----------------
__global__ __launch_bounds__(256) void vuln_fused_kernel(
        const float* __restrict__ h, const float* __restrict__ wv1, const float* __restrict__ bv1,
        const float* __restrict__ wv2, const float* __restrict__ bv2,
        float* __restrict__ out, int n)
{
    __shared__ float As[32][132];
    __shared__ float Bs[32][64];
    int t = threadIdx.x;
    int m0 = blockIdx.x * 128;
    int tm = t >> 4, tn = t & 15;

    float acc[8][4];
    #pragma unroll
    for (int i = 0; i < 8; ++i)
        #pragma unroll
        for (int j = 0; j < 4; ++j) acc[i][j] = 0.f;

    for (int kc = 0; kc < 4; ++kc){
        int k0 = kc * 32;
        #pragma unroll
        for (int i = 0; i < 4; ++i){
            int f = i * 256 + t;
            int row = f >> 3, kq = f & 7;
            int gr = m0 + row; if (gr > n - 1) gr = n - 1;
            float4 v = *(const float4*)(h + (size_t)gr * HC + k0 + kq * 4);
            As[kq*4+0][row] = v.x; As[kq*4+1][row] = v.y; As[kq*4+2][row] = v.z; As[kq*4+3][row] = v.w;
        }
        #pragma unroll
        for (int i = 0; i < 2; ++i){
            int f = i * 256 + t;
            int kk = f >> 4, nq = f & 15;
            *(float4*)&Bs[kk][nq*4] = *(const float4*)(wv1 + (size_t)(k0 + kk) * 64 + nq * 4);
        }
        __syncthreads();
        #pragma unroll 4
        for (int k = 0; k < 32; ++k){
            float a[8], b[4];
            *(float4*)&a[0] = *(float4*)&As[k][tm*8];
            *(float4*)&a[4] = *(float4*)&As[k][tm*8+4];
            *(float4*)&b[0] = *(float4*)&Bs[k][tn*4];
            #pragma unroll
            for (int i = 0; i < 8; ++i)
                #pragma unroll
                for (int j = 0; j < 4; ++j) acc[i][j] = fmaf(a[i], b[j], acc[i][j]);
        }
        __syncthreads();
    }

    float bb[4], wv[4];
    *(float4*)&bb[0] = *(const float4*)(bv1 + tn*4);
    *(float4*)&wv[0] = *(const float4*)(wv2 + tn*4);
    float bv2v = bv2[0];
    #pragma unroll
    for (int i = 0; i < 8; ++i){
        float v = 0.f;
        #pragma unroll
        for (int j = 0; j < 4; ++j) v = fmaf(fmaxf(acc[i][j] + bb[j], 0.f), wv[j], v);
        v += __shfl_xor(v, 1); v += __shfl_xor(v, 2);
        v += __shfl_xor(v, 4); v += __shfl_xor(v, 8);
        int node = m0 + tm*8 + i;
        if (tn == 0 && node < n)
            out[1 + node] = 1.0f / (1.0f + __expf(-(v + bv2v)));
    }
}

// ----------------- path head (1 block) -----------------
__global__ __launch_bounds__(128) void path_kernel(
        const float* __restrict__ h, const float* __restrict__ g,
        const float* __restrict__ wp1, const float* __restrict__ bp1,
        const float* __restrict__ wp2, const float* __restrict__ bp2,
        const float* __restrict__ wp3, const float* __restrict__ bp3,
        float* __restrict__ out, int n)
{
    __shared__ float pc[256];
    __shared__ float p1[HC];
    __shared__ float p2[64];
    int t = threadIdx.x;              // 128
    pc[t]       = h[t];               // h[0,:]
    pc[128 + t] = g[t] * (1.0f / (float)n);
    __syncthreads();
    float a = bp1[t];
    for (int k = 0; k < 256; ++k) a = fmaf(pc[k], wp1[k * HC + t], a);
    p1[t] = fmaxf(a, 0.f);
    __syncthreads();
    if (t < 64){
        float a2 = bp2[t];
        for (int k = 0; k < HC; ++k) a2 = fmaf(p1[k], wp2[k * 64 + t], a2);
        p2[t] = fmaxf(a2, 0.f);
    }
    __syncthreads();
    if (t == 0){
        float a3 = bp3[0];
        for (int k = 0; k < 64; ++k) a3 = fmaf(p2[k], wp3[k], a3);
        out[0] = 1.0f / (1.0f + __expf(-a3));
        out[1 + n] = 0.f;             // esc = 0
    }
}

extern "C" void kernel_launch(void* const* d_in, const int* in_sizes, int n_in,
                              void* d_out, int out_size, void* d_ws, size_t ws_size,
                              hipStream_t stream)
{
    const float* x    = (const float*)d_in[0];
    const int*   ei   = (const int*)d_in[1];
    const float* w_n1 = (const float*)d_in[3];
    const float* b_n1 = (const float*)d_in[4];
    const float* w_n2 = (const float*)d_in[5];
    const float* b_n2 = (const float*)d_in[6];
    const float* conv_w = (const float*)d_in[9];
    const float* att_s  = (const float*)d_in[10];
    const float* att_d  = (const float*)d_in[11];
    const float* conv_b = (const float*)d_in[12];
    const float* wp1 = (const float*)d_in[13];
    const float* bp1 = (const float*)d_in[14];
    const float* wp2 = (const float*)d_in[15];
    const float* bp2 = (const float*)d_in[16];
    const float* wp3 = (const float*)d_in[17];
    const float* bp3 = (const float*)d_in[18];
    const float* wv1 = (const float*)d_in[19];
    const float* bv1 = (const float*)d_in[20];
    const float* wv2 = (const float*)d_in[21];
    const float* bv2 = (const float*)d_in[22];

    const int N = in_sizes[0] / 32;
    const int E = in_sizes[1] / 2;
    float* out = (float*)d_out;

    char* ws = (char*)d_ws;
    size_t off = 0;
    auto take = [&](size_t bytes) -> char* {
        char* p = ws + off;
        off += (bytes + 255) & ~(size_t)255;
        return p;
    };
    float* hA    = (float*)take((size_t)N * HC * 4);
    float* hB    = (float*)take((size_t)N * HC * 4);   // f32 hid OR bf16 h' (reused)
    float* asrc  = (float*)take((size_t)N * 2 * 4);
    float* adst  = (float*)take((size_t)N * 2 * 4);
    int*   rowptr= (int*)take((size_t)(N + 1) * 4);
    int*   cursor= (int*)take((size_t)N * 4);
    int*   colsrc= (int*)take((size_t)E * 4);
    float* g     = (float*)take(HC * 4);
    int nb = (N + 1023) / 1024;
    int*   bsum  = (int*)take((size_t)((nb + 63) & ~63) * 4);
    int*   boff  = (int*)take((size_t)((nb + 63) & ~63) * 4);
    unsigned short* hBb = (unsigned short*)hB;

    // --- CSR build (dst-sorted; reused across the 3 layers) ---
    hipMemsetAsync(cursor, 0, (size_t)N * 4, stream);
    count_kernel<<<(E + 255) / 256, 256, 0, stream>>>(ei, cursor, E);
    scan_part_kernel<<<nb, 256, 0, stream>>>(cursor, bsum, N);
    scan_top_kernel<<<1, 64, 0, stream>>>(bsum, boff, rowptr, nb, N);
    scan_fin_kernel<<<nb, 256, 0, stream>>>(cursor, boff, rowptr, N);
    hipMemsetAsync(cursor, 0, (size_t)N * 4, stream);
    scatter_kernel<<<(E + 255) / 256, 256, 0, stream>>>(ei, rowptr, cursor, colsrc, E);

    int nblk = (N + 127) / 128;
    // node encoder: hid (hB f32) = relu(x@w1+b1); hA = hid@w2 + b2
    enc1_kernel<<<nblk, 256, 0, stream>>>(x, w_n1, b_n1, hB, N);
    gemm_main_kernel<false><<<nblk, 256, 0, stream>>>(
        hB, w_n2, b_n2, nullptr, nullptr, hA, nullptr, nullptr, nullptr, N);

    for (int l = 0; l < 3; ++l){
        gemm_main_kernel<true><<<nblk, 256, 0, stream>>>(
            hA, conv_w + (size_t)l * HC * HC, nullptr,
            att_s + (size_t)l * HC, att_d + (size_t)l * HC,
            nullptr, hBb, asrc, adst, N);
        aggregate_kernel<<<N, 64, 0, stream>>>(
            hBb, asrc, adst, rowptr, colsrc, conv_b + (size_t)l * HC, hA, N);
    }

    hipMemsetAsync(g, 0, HC * 4, stream);
    mean_kernel<<<512, 256, 0, stream>>>(hA, g, N);
    vuln_fused_kernel<<<nblk, 256, 0, stream>>>(hA, wv1, bv1, wv2, bv2, out, N);
    path_kernel<<<1, 128, 0, stream>>>(hA, g, wp1, bp1, wp2, bp2, wp3, bp3, out, N);
}

// Round 7
// 421.170 us; speedup vs baseline: 1.1719x; 1.0640x over previous
//
#include <hip/hip_runtime.h>
#include <math.h>

#define HC 128
#define NSLOPE 0.2f

__device__ __forceinline__ float lrelu(float v){ return v > 0.f ? v : NSLOPE * v; }

// bf16 round-to-nearest-even pack / unpack
__device__ __forceinline__ unsigned short f2bf(float f){
    unsigned int b = __float_as_uint(f);
    b += 0x7FFFu + ((b >> 16) & 1u);
    return (unsigned short)(b >> 16);
}
__device__ __forceinline__ float bf_lo(unsigned int v){ return __uint_as_float(v << 16); }
__device__ __forceinline__ float bf_hi(unsigned int v){ return __uint_as_float(v & 0xFFFF0000u); }

// ----------------- CSR build (dst-sorted) -----------------
__global__ void count_kernel(const int* __restrict__ ei, int* __restrict__ cnt, int E){
    int e = blockIdx.x * blockDim.x + threadIdx.x;
    if (e < E) atomicAdd(&cnt[ei[E + e]], 1);
}

// S1: per-block (1024 nodes) partial sums
__global__ __launch_bounds__(256) void scan_part_kernel(
        const int* __restrict__ deg, int* __restrict__ bsum, int n)
{
    int t = threadIdx.x, lane = t & 63, wid = t >> 6;
    int base = blockIdx.x * 1024 + t * 4;
    int s = 0;
    #pragma unroll
    for (int j = 0; j < 4; ++j){ int i = base + j; if (i < n) s += deg[i]; }
    #pragma unroll
    for (int o = 1; o < 64; o <<= 1) s += __shfl_xor(s, o);
    __shared__ int red[4];
    if (lane == 0) red[wid] = s;
    __syncthreads();
    if (t == 0) bsum[blockIdx.x] = red[0] + red[1] + red[2] + red[3];
}

// S2: 1 wave scans the (<=64) block sums; writes exclusive offsets + rowptr[n]=total
__global__ __launch_bounds__(64) void scan_top_kernel(
        const int* __restrict__ bsum, int* __restrict__ boff, int* __restrict__ rowptr,
        int nb, int n)
{
    int t = threadIdx.x;
    int v = (t < nb) ? bsum[t] : 0;
    int incl = v;
    #pragma unroll
    for (int o = 1; o < 64; o <<= 1){ int u = __shfl_up(incl, o); if (t >= o) incl += u; }
    if (t < nb) boff[t] = incl - v;
    if (t == 63) rowptr[n] = incl;
}

// S3: per-block exclusive scan with global offset -> rowptr[0..n-1]
__global__ __launch_bounds__(256) void scan_fin_kernel(
        const int* __restrict__ deg, const int* __restrict__ boff,
        int* __restrict__ rowptr, int n)
{
    int t = threadIdx.x, lane = t & 63, wid = t >> 6;
    int base = blockIdx.x * 1024 + t * 4;
    int d[4]; int s = 0;
    #pragma unroll
    for (int j = 0; j < 4; ++j){ int i = base + j; d[j] = (i < n) ? deg[i] : 0; s += d[j]; }
    int incl = s;
    #pragma unroll
    for (int o = 1; o < 64; o <<= 1){ int u = __shfl_up(incl, o); if (lane >= o) incl += u; }
    __shared__ int wsum[4];
    if (lane == 63) wsum[wid] = incl;
    __syncthreads();
    int off = boff[blockIdx.x] + (incl - s);
    for (int w = 0; w < wid; ++w) off += wsum[w];
    #pragma unroll
    for (int j = 0; j < 4; ++j){
        int i = base + j;
        if (i < n) rowptr[i] = off;
        off += d[j];
    }
}

__global__ void scatter_kernel(const int* __restrict__ ei, const int* __restrict__ rowptr,
                               int* __restrict__ cursor, int* __restrict__ colsrc, int E){
    int e = blockIdx.x * blockDim.x + threadIdx.x;
    if (e < E){
        int d = ei[E + e];
        int pos = rowptr[d] + atomicAdd(&cursor[d], 1);
        colsrc[pos] = ei[e];
    }
}

// ----------------- node encoder stage 1: hid = relu(x@w1+b1), K=32 -----------------
__global__ __launch_bounds__(256) void enc1_kernel(
        const float* __restrict__ x, const float* __restrict__ w1, const float* __restrict__ b1,
        float* __restrict__ hid, int n)
{
    __shared__ float As[32][132];
    __shared__ float Bs[32][128];
    int t = threadIdx.x;
    int m0 = blockIdx.x * 128;
    int tm = t >> 4, tn = t & 15;

    #pragma unroll
    for (int i = 0; i < 4; ++i){
        int f = i * 256 + t;
        int row = f >> 3, kq = f & 7;
        int gr = m0 + row; if (gr > n - 1) gr = n - 1;
        float4 v = *(const float4*)(x + (size_t)gr * 32 + kq * 4);
        As[kq*4+0][row] = v.x; As[kq*4+1][row] = v.y; As[kq*4+2][row] = v.z; As[kq*4+3][row] = v.w;
    }
    #pragma unroll
    for (int i = 0; i < 4; ++i){
        int f = i * 256 + t;
        int kk = f >> 5, nq = f & 31;
        *(float4*)&Bs[kk][nq*4] = *(const float4*)(w1 + (size_t)kk * 128 + nq * 4);
    }
    __syncthreads();

    float acc[8][8];
    #pragma unroll
    for (int i = 0; i < 8; ++i)
        #pragma unroll
        for (int j = 0; j < 8; ++j) acc[i][j] = 0.f;

    #pragma unroll 4
    for (int k = 0; k < 32; ++k){
        float a[8], b[8];
        *(float4*)&a[0] = *(float4*)&As[k][tm*8];
        *(float4*)&a[4] = *(float4*)&As[k][tm*8+4];
        *(float4*)&b[0] = *(float4*)&Bs[k][tn*8];
        *(float4*)&b[4] = *(float4*)&Bs[k][tn*8+4];
        #pragma unroll
        for (int i = 0; i < 8; ++i)
            #pragma unroll
            for (int j = 0; j < 8; ++j) acc[i][j] = fmaf(a[i], b[j], acc[i][j]);
    }

    float bb[8];
    *(float4*)&bb[0] = *(const float4*)(b1 + tn*8);
    *(float4*)&bb[4] = *(const float4*)(b1 + tn*8 + 4);
    #pragma unroll
    for (int i = 0; i < 8; ++i){
        int node = m0 + tm*8 + i;
        if (node < n){
            float o[8];
            #pragma unroll
            for (int j = 0; j < 8; ++j) o[j] = fmaxf(acc[i][j] + bb[j], 0.f);
            *(float4*)(hid + (size_t)node*HC + tn*8)     = *(float4*)&o[0];
            *(float4*)(hid + (size_t)node*HC + tn*8 + 4) = *(float4*)&o[4];
        }
    }
}

// ----------------- main GEMM: C = A@W (+bias); ATT: bf16 C + fused att dots -----------------
template<bool ATT>
__global__ __launch_bounds__(256) void gemm_main_kernel(
        const float* __restrict__ A, const float* __restrict__ W, const float* __restrict__ bias,
        const float* __restrict__ att_s, const float* __restrict__ att_d,
        float* __restrict__ C, unsigned short* __restrict__ Cb,
        float* __restrict__ asrc, float* __restrict__ adst, int n)
{
    __shared__ float As[32][132];
    __shared__ float Bs[32][128];
    int t = threadIdx.x;
    int m0 = blockIdx.x * 128;
    int tm = t >> 4, tn = t & 15;

    float acc[8][8];
    #pragma unroll
    for (int i = 0; i < 8; ++i)
        #pragma unroll
        for (int j = 0; j < 8; ++j) acc[i][j] = 0.f;

    for (int kc = 0; kc < 4; ++kc){
        int k0 = kc * 32;
        #pragma unroll
        for (int i = 0; i < 4; ++i){
            int f = i * 256 + t;
            int row = f >> 3, kq = f & 7;
            int gr = m0 + row; if (gr > n - 1) gr = n - 1;
            float4 v = *(const float4*)(A + (size_t)gr * HC + k0 + kq * 4);
            As[kq*4+0][row] = v.x; As[kq*4+1][row] = v.y; As[kq*4+2][row] = v.z; As[kq*4+3][row] = v.w;
        }
        #pragma unroll
        for (int i = 0; i < 4; ++i){
            int f = i * 256 + t;
            int kk = f >> 5, nq = f & 31;
            *(float4*)&Bs[kk][nq*4] = *(const float4*)(W + (size_t)(k0 + kk) * 128 + nq * 4);
        }
        __syncthreads();
        #pragma unroll 4
        for (int k = 0; k < 32; ++k){
            float a[8], b[8];
            *(float4*)&a[0] = *(float4*)&As[k][tm*8];
            *(float4*)&a[4] = *(float4*)&As[k][tm*8+4];
            *(float4*)&b[0] = *(float4*)&Bs[k][tn*8];
            *(float4*)&b[4] = *(float4*)&Bs[k][tn*8+4];
            #pragma unroll
            for (int i = 0; i < 8; ++i)
                #pragma unroll
                for (int j = 0; j < 8; ++j) acc[i][j] = fmaf(a[i], b[j], acc[i][j]);
        }
        __syncthreads();
    }

    if (!ATT){
        float bb[8];
        *(float4*)&bb[0] = *(const float4*)(bias + tn*8);
        *(float4*)&bb[4] = *(const float4*)(bias + tn*8 + 4);
        #pragma unroll
        for (int i = 0; i < 8; ++i){
            int node = m0 + tm*8 + i;
            if (node < n){
                float o[8];
                #pragma unroll
                for (int j = 0; j < 8; ++j) o[j] = acc[i][j] + bb[j];
                *(float4*)(C + (size_t)node*HC + tn*8)     = *(float4*)&o[0];
                *(float4*)(C + (size_t)node*HC + tn*8 + 4) = *(float4*)&o[4];
            }
        }
    } else {
        #pragma unroll
        for (int i = 0; i < 8; ++i){
            int node = m0 + tm*8 + i;
            if (node < n){
                uint4 pk;
                pk.x = (unsigned int)f2bf(acc[i][0]) | ((unsigned int)f2bf(acc[i][1]) << 16);
                pk.y = (unsigned int)f2bf(acc[i][2]) | ((unsigned int)f2bf(acc[i][3]) << 16);
                pk.z = (unsigned int)f2bf(acc[i][4]) | ((unsigned int)f2bf(acc[i][5]) << 16);
                pk.w = (unsigned int)f2bf(acc[i][6]) | ((unsigned int)f2bf(acc[i][7]) << 16);
                *(uint4*)(Cb + (size_t)node*HC + tn*8) = pk;
            }
        }
        float ats[8], atd[8];
        *(float4*)&ats[0] = *(const float4*)(att_s + tn*8);
        *(float4*)&ats[4] = *(const float4*)(att_s + tn*8 + 4);
        *(float4*)&atd[0] = *(const float4*)(att_d + tn*8);
        *(float4*)&atd[4] = *(const float4*)(att_d + tn*8 + 4);
        #pragma unroll
        for (int i = 0; i < 8; ++i){
            float sa = 0.f, sd = 0.f;
            #pragma unroll
            for (int j = 0; j < 8; ++j){
                sa = fmaf(acc[i][j], ats[j], sa);
                sd = fmaf(acc[i][j], atd[j], sd);
            }
            sa += __shfl_xor(sa, 1); sa += __shfl_xor(sa, 2); sa += __shfl_xor(sa, 4);
            sd += __shfl_xor(sd, 1); sd += __shfl_xor(sd, 2); sd += __shfl_xor(sd, 4);
            int node = m0 + tm*8 + i;
            if ((tn == 0 || tn == 8) && node < n){
                int head = tn >> 3;
                asrc[(size_t)node*2 + head] = sa;
                adst[(size_t)node*2 + head] = sd;
            }
        }
    }
}

// ----------------- aggregation: 1 wave/node; exp computed once/edge in-wave -----------------
__global__ __launch_bounds__(64) void aggregate_kernel(
        const unsigned short* __restrict__ h1b, const float* __restrict__ asrc, const float* __restrict__ adst,
        const int* __restrict__ rowptr, const int* __restrict__ colsrc,
        const float* __restrict__ bias, float* __restrict__ hout, int n)
{
    int i = blockIdx.x;
    if (i >= n) return;
    int t = threadIdx.x;              // 64 lanes, 2 channels each (one uint of 2 bf16)
    int head = t >> 5;
    float2 adv = *(const float2*)(adst + (size_t)i * 2);
    float2 asv = *(const float2*)(asrc + (size_t)i * 2);
    float ads = head ? adv.y : adv.x;
    // self loop (GATConv add_self_loops=True)
    float exs = __expf(lrelu((head ? asv.y : asv.x) + ads));
    unsigned int hv = ((const unsigned int*)(h1b + (size_t)i * HC))[t];
    float acc0 = exs * bf_lo(hv), acc1 = exs * bf_hi(hv), D = exs;

    int e  = rowptr[i];
    int e1 = rowptr[i + 1];
    while (e < e1){
        int m = e1 - e; if (m > 64) m = 64;
        int   sl  = 0;
        float ex0 = 0.f, ex1 = 0.f;
        if (t < m){
            sl = colsrc[e + t];                       // coalesced
            float2 as = *(const float2*)(asrc + (size_t)sl * 2);
            ex0 = __expf(lrelu(as.x + adv.x));
            ex1 = __expf(lrelu(as.y + adv.y));
        }
        int j = 0;
        for (; j + 2 <= m; j += 2){
            int   sa  = __shfl(sl,  j),     sb  = __shfl(sl,  j + 1);
            float ea0 = __shfl(ex0, j),     eb0 = __shfl(ex0, j + 1);
            float ea1 = __shfl(ex1, j),     eb1 = __shfl(ex1, j + 1);
            unsigned int va = ((const unsigned int*)(h1b + (size_t)sa * HC))[t];
            unsigned int vb = ((const unsigned int*)(h1b + (size_t)sb * HC))[t];
            float ea = head ? ea1 : ea0;
            float eb = head ? eb1 : eb0;
            acc0 = fmaf(ea, bf_lo(va), acc0);
            acc1 = fmaf(ea, bf_hi(va), acc1);
            acc0 = fmaf(eb, bf_lo(vb), acc0);
            acc1 = fmaf(eb, bf_hi(vb), acc1);
            D += ea + eb;
        }
        if (j < m){
            int   sa  = __shfl(sl,  j);
            float ea0 = __shfl(ex0, j);
            float ea1 = __shfl(ex1, j);
            unsigned int va = ((const unsigned int*)(h1b + (size_t)sa * HC))[t];
            float ea = head ? ea1 : ea0;
            acc0 = fmaf(ea, bf_lo(va), acc0);
            acc1 = fmaf(ea, bf_hi(va), acc1);
            D += ea;
        }
        e += m;
    }
    float rD = 1.0f / D;
    float o0 = fmaxf(acc0 * rD + bias[2*t],     0.f);
    float o1 = fmaxf(acc1 * rD + bias[2*t + 1], 0.f);
    ((float2*)(hout + (size_t)i * HC))[t] = make_float2(o0, o1);
}

// ----------------- graph mean: two-stage, NO global atomics -----------------
// stage 1: 64 blocks, each writes its 128-channel partial sum
__global__ __launch_bounds__(256) void mean_part_kernel(
        const float* __restrict__ h, float* __restrict__ partial, int n)
{
    int t = threadIdx.x;
    int cq = t & 31;                   // channel quad: channels cq*4 .. cq*4+3
    int rl = t >> 5;                   // row lane 0..7
    float4 acc = make_float4(0.f, 0.f, 0.f, 0.f);
    for (int i = blockIdx.x * 8 + rl; i < n; i += gridDim.x * 8){
        float4 v = *(const float4*)(h + (size_t)i * HC + cq * 4);
        acc.x += v.x; acc.y += v.y; acc.z += v.z; acc.w += v.w;
    }
    __shared__ float4 red[256];
    red[t] = acc;
    __syncthreads();
    if (t < 128){
        float4 o = red[t + 128];
        red[t].x += o.x; red[t].y += o.y; red[t].z += o.z; red[t].w += o.w;
    }
    __syncthreads();
    if (t < 64){
        float4 o = red[t + 64];
        red[t].x += o.x; red[t].y += o.y; red[t].z += o.z; red[t].w += o.w;
    }
    __syncthreads();
    if (t < 32){
        float4 a = red[t], b = red[t + 32];
        float4 s = make_float4(a.x + b.x, a.y + b.y, a.z + b.z, a.w + b.w);
        *(float4*)(partial + (size_t)blockIdx.x * HC + t * 4) = s;
    }
}

// stage 2: 1 block reduces nb x 128 partials -> g (sum; path_kernel divides by n)
__global__ __launch_bounds__(256) void mean_fin_kernel(
        const float* __restrict__ partial, float* __restrict__ g, int nb)
{
    int t = threadIdx.x;
    int cq = t & 31, b0 = t >> 5;      // 8-way over blocks
    float4 acc = make_float4(0.f, 0.f, 0.f, 0.f);
    for (int b = b0; b < nb; b += 8){
        float4 v = *(const float4*)(partial + (size_t)b * HC + cq * 4);
        acc.x += v.x; acc.y += v.y; acc.z += v.z; acc.w += v.w;
    }
    __shared__ float4 red[256];
    red[t] = acc;
    __syncthreads();
    if (t < 128){
        float4 o = red[t + 128];
        red[t].x += o.x; red[t].y += o.y; red[t].z += o.z; red[t].w += o.w;
    }
    __syncthreads();
    if (t < 64){
        float4 o = red[t + 64];
        red[t].x += o.x; red[t].y += o.y; red[t].z += o.z; red[t].w += o.w;
    }
    __syncthreads();
    if (t < 32){
        float4 a = red[t], b = red[t + 32];
        float4 s = make_float4(a.x + b.x, a.y + b.y, a.z + b.z, a.w + b.w);
        *(float4*)(g + t * 4) = s;
    }
}

// ----------------- vuln head: sigmoid(relu(h@wv1+bv1)@wv2+bv2), tiled -----------------
__global__ __launch_bounds__(256) void vuln_fused_kernel(
        const float* __restrict__ h, const float* __restrict__ wv1, const float* __restrict__ bv1,
        const float* __restrict__ wv2, const float* __restrict__ bv2,
        float* __restrict__ out, int n)
{
    __shared__ float As[32][132];
    __shared__ float Bs[32][64];
    int t = threadIdx.x;
    int m0 = blockIdx.x * 128;
    int tm = t >> 4, tn = t & 15;

    float acc[8][4];
    #pragma unroll
    for (int i = 0; i < 8; ++i)
        #pragma unroll
        for (int j = 0; j < 4; ++j) acc[i][j] = 0.f;

    for (int kc = 0; kc < 4; ++kc){
        int k0 = kc * 32;
        #pragma unroll
        for (int i = 0; i < 4; ++i){
            int f = i * 256 + t;
            int row = f >> 3, kq = f & 7;
            int gr = m0 + row; if (gr > n - 1) gr = n - 1;
            float4 v = *(const float4*)(h + (size_t)gr * HC + k0 + kq * 4);
            As[kq*4+0][row] = v.x; As[kq*4+1][row] = v.y; As[kq*4+2][row] = v.z; As[kq*4+3][row] = v.w;
        }
        #pragma unroll
        for (int i = 0; i < 2; ++i){
            int f = i * 256 + t;
            int kk = f >> 4, nq = f & 15;
            *(float4*)&Bs[kk][nq*4] = *(const float4*)(wv1 + (size_t)(k0 + kk) * 64 + nq * 4);
        }
        __syncthreads();
        #pragma unroll 4
        for (int k = 0; k < 32; ++k){
            float a[8], b[4];
            *(float4*)&a[0] = *(float4*)&As[k][tm*8];
            *(float4*)&a[4] = *(float4*)&As[k][tm*8+4];
            *(float4*)&b[0] = *(float4*)&Bs[k][tn*4];
            #pragma unroll
            for (int i = 0; i < 8; ++i)
                #pragma unroll
                for (int j = 0; j < 4; ++j) acc[i][j] = fmaf(a[i], b[j], acc[i][j]);
        }
        __syncthreads();
    }

    float bb[4], wv[4];
    *(float4*)&bb[0] = *(const float4*)(bv1 + tn*4);
    *(float4*)&wv[0] = *(const float4*)(wv2 + tn*4);
    float bv2v = bv2[0];
    #pragma unroll
    for (int i = 0; i < 8; ++i){
        float v = 0.f;
        #pragma unroll
        for (int j = 0; j < 4; ++j) v = fmaf(fmaxf(acc[i][j] + bb[j], 0.f), wv[j], v);
        v += __shfl_xor(v, 1); v += __shfl_xor(v, 2);
        v += __shfl_xor(v, 4); v += __shfl_xor(v, 8);
        int node = m0 + tm*8 + i;
        if (tn == 0 && node < n)
            out[1 + node] = 1.0f / (1.0f + __expf(-(v + bv2v)));
    }
}

// ----------------- path head (1 block) -----------------
__global__ __launch_bounds__(128) void path_kernel(
        const float* __restrict__ h, const float* __restrict__ g,
        const float* __restrict__ wp1, const float* __restrict__ bp1,
        const float* __restrict__ wp2, const float* __restrict__ bp2,
        const float* __restrict__ wp3, const float* __restrict__ bp3,
        float* __restrict__ out, int n)
{
    __shared__ float pc[256];
    __shared__ float p1[HC];
    __shared__ float p2[64];
    int t = threadIdx.x;              // 128
    pc[t]       = h[t];               // h[0,:]
    pc[128 + t] = g[t] * (1.0f / (float)n);
    __syncthreads();
    float a = bp1[t];
    for (int k = 0; k < 256; ++k) a = fmaf(pc[k], wp1[k * HC + t], a);
    p1[t] = fmaxf(a, 0.f);
    __syncthreads();
    if (t < 64){
        float a2 = bp2[t];
        for (int k = 0; k < HC; ++k) a2 = fmaf(p1[k], wp2[k * 64 + t], a2);
        p2[t] = fmaxf(a2, 0.f);
    }
    __syncthreads();
    if (t == 0){
        float a3 = bp3[0];
        for (int k = 0; k < 64; ++k) a3 = fmaf(p2[k], wp3[k], a3);
        out[0] = 1.0f / (1.0f + __expf(-a3));
        out[1 + n] = 0.f;             // esc = 0
    }
}

extern "C" void kernel_launch(void* const* d_in, const int* in_sizes, int n_in,
                              void* d_out, int out_size, void* d_ws, size_t ws_size,
                              hipStream_t stream)
{
    const float* x    = (const float*)d_in[0];
    const int*   ei   = (const int*)d_in[1];
    const float* w_n1 = (const float*)d_in[3];
    const float* b_n1 = (const float*)d_in[4];
    const float* w_n2 = (const float*)d_in[5];
    const float* b_n2 = (const float*)d_in[6];
    const float* conv_w = (const float*)d_in[9];
    const float* att_s  = (const float*)d_in[10];
    const float* att_d  = (const float*)d_in[11];
    const float* conv_b = (const float*)d_in[12];
    const float* wp1 = (const float*)d_in[13];
    const float* bp1 = (const float*)d_in[14];
    const float* wp2 = (const float*)d_in[15];
    const float* bp2 = (const float*)d_in[16];
    const float* wp3 = (const float*)d_in[17];
    const float* bp3 = (const float*)d_in[18];
    const float* wv1 = (const float*)d_in[19];
    const float* bv1 = (const float*)d_in[20];
    const float* wv2 = (const float*)d_in[21];
    const float* bv2 = (const float*)d_in[22];

    const int N = in_sizes[0] / 32;
    const int E = in_sizes[1] / 2;
    float* out = (float*)d_out;

    char* ws = (char*)d_ws;
    size_t off = 0;
    auto take = [&](size_t bytes) -> char* {
        char* p = ws + off;
        off += (bytes + 255) & ~(size_t)255;
        return p;
    };
    float* hA    = (float*)take((size_t)N * HC * 4);
    float* hB    = (float*)take((size_t)N * HC * 4);   // f32 hid OR bf16 h' (reused)
    float* asrc  = (float*)take((size_t)N * 2 * 4);
    float* adst  = (float*)take((size_t)N * 2 * 4);
    int*   rowptr= (int*)take((size_t)(N + 1) * 4);
    int*   cursor= (int*)take((size_t)N * 4);
    int*   colsrc= (int*)take((size_t)E * 4);
    float* g     = (float*)take(HC * 4);
    const int MB = 64;                                  // mean partial blocks
    float* mpart = (float*)take((size_t)MB * HC * 4);
    int nb = (N + 1023) / 1024;
    int*   bsum  = (int*)take((size_t)((nb + 63) & ~63) * 4);
    int*   boff  = (int*)take((size_t)((nb + 63) & ~63) * 4);
    unsigned short* hBb = (unsigned short*)hB;

    // --- CSR build (dst-sorted; reused across the 3 layers) ---
    hipMemsetAsync(cursor, 0, (size_t)N * 4, stream);
    count_kernel<<<(E + 255) / 256, 256, 0, stream>>>(ei, cursor, E);
    scan_part_kernel<<<nb, 256, 0, stream>>>(cursor, bsum, N);
    scan_top_kernel<<<1, 64, 0, stream>>>(bsum, boff, rowptr, nb, N);
    scan_fin_kernel<<<nb, 256, 0, stream>>>(cursor, boff, rowptr, N);
    hipMemsetAsync(cursor, 0, (size_t)N * 4, stream);
    scatter_kernel<<<(E + 255) / 256, 256, 0, stream>>>(ei, rowptr, cursor, colsrc, E);

    int nblk = (N + 127) / 128;
    // node encoder: hid (hB f32) = relu(x@w1+b1); hA = hid@w2 + b2
    enc1_kernel<<<nblk, 256, 0, stream>>>(x, w_n1, b_n1, hB, N);
    gemm_main_kernel<false><<<nblk, 256, 0, stream>>>(
        hB, w_n2, b_n2, nullptr, nullptr, hA, nullptr, nullptr, nullptr, N);

    for (int l = 0; l < 3; ++l){
        gemm_main_kernel<true><<<nblk, 256, 0, stream>>>(
            hA, conv_w + (size_t)l * HC * HC, nullptr,
            att_s + (size_t)l * HC, att_d + (size_t)l * HC,
            nullptr, hBb, asrc, adst, N);
        aggregate_kernel<<<N, 64, 0, stream>>>(
            hBb, asrc, adst, rowptr, colsrc, conv_b + (size_t)l * HC, hA, N);
    }

    mean_part_kernel<<<MB, 256, 0, stream>>>(hA, mpart, N);
    mean_fin_kernel<<<1, 256, 0, stream>>>(mpart, g, MB);
    vuln_fused_kernel<<<nblk, 256, 0, stream>>>(hA, wv1, bv1, wv2, bv2, out, N);
    path_kernel<<<1, 128, 0, stream>>>(hA, g, wp1, bp1, wp2, bp2, wp3, bp3, out, N);
}

// Round 8
// 416.477 us; speedup vs baseline: 1.1851x; 1.0113x over previous
//
#include <hip/hip_runtime.h>
#include <math.h>

#define HC 128
#define NSLOPE 0.2f

__device__ __forceinline__ float lrelu(float v){ return v > 0.f ? v : NSLOPE * v; }

// bf16 round-to-nearest-even pack / unpack
__device__ __forceinline__ unsigned short f2bf(float f){
    unsigned int b = __float_as_uint(f);
    b += 0x7FFFu + ((b >> 16) & 1u);
    return (unsigned short)(b >> 16);
}
__device__ __forceinline__ float bf_lo(unsigned int v){ return __uint_as_float(v << 16); }
__device__ __forceinline__ float bf_hi(unsigned int v){ return __uint_as_float(v & 0xFFFF0000u); }

// ----------------- CSR build (dst-sorted) -----------------
__global__ void count_kernel(const int* __restrict__ ei, int* __restrict__ cnt, int E){
    int e = blockIdx.x * blockDim.x + threadIdx.x;
    if (e < E) atomicAdd(&cnt[ei[E + e]], 1);
}

// S1: per-block (1024 nodes) partial sums
__global__ __launch_bounds__(256) void scan_part_kernel(
        const int* __restrict__ deg, int* __restrict__ bsum, int n)
{
    int t = threadIdx.x, lane = t & 63, wid = t >> 6;
    int base = blockIdx.x * 1024 + t * 4;
    int s = 0;
    #pragma unroll
    for (int j = 0; j < 4; ++j){ int i = base + j; if (i < n) s += deg[i]; }
    #pragma unroll
    for (int o = 1; o < 64; o <<= 1) s += __shfl_xor(s, o);
    __shared__ int red[4];
    if (lane == 0) red[wid] = s;
    __syncthreads();
    if (t == 0) bsum[blockIdx.x] = red[0] + red[1] + red[2] + red[3];
}

// S2: 1 wave scans the (<=64) block sums; writes exclusive offsets + rowptr[n]=total
__global__ __launch_bounds__(64) void scan_top_kernel(
        const int* __restrict__ bsum, int* __restrict__ boff, int* __restrict__ rowptr,
        int nb, int n)
{
    int t = threadIdx.x;
    int v = (t < nb) ? bsum[t] : 0;
    int incl = v;
    #pragma unroll
    for (int o = 1; o < 64; o <<= 1){ int u = __shfl_up(incl, o); if (t >= o) incl += u; }
    if (t < nb) boff[t] = incl - v;
    if (t == 63) rowptr[n] = incl;
}

// S3: per-block exclusive scan with global offset -> rowptr[0..n-1]
__global__ __launch_bounds__(256) void scan_fin_kernel(
        const int* __restrict__ deg, const int* __restrict__ boff,
        int* __restrict__ rowptr, int n)
{
    int t = threadIdx.x, lane = t & 63, wid = t >> 6;
    int base = blockIdx.x * 1024 + t * 4;
    int d[4]; int s = 0;
    #pragma unroll
    for (int j = 0; j < 4; ++j){ int i = base + j; d[j] = (i < n) ? deg[i] : 0; s += d[j]; }
    int incl = s;
    #pragma unroll
    for (int o = 1; o < 64; o <<= 1){ int u = __shfl_up(incl, o); if (lane >= o) incl += u; }
    __shared__ int wsum[4];
    if (lane == 63) wsum[wid] = incl;
    __syncthreads();
    int off = boff[blockIdx.x] + (incl - s);
    for (int w = 0; w < wid; ++w) off += wsum[w];
    #pragma unroll
    for (int j = 0; j < 4; ++j){
        int i = base + j;
        if (i < n) rowptr[i] = off;
        off += d[j];
    }
}

// ILP=4: 4 independent atomic->store chains in flight per thread
__global__ __launch_bounds__(256) void scatter_kernel(
        const int* __restrict__ ei, const int* __restrict__ rowptr,
        int* __restrict__ cursor, int* __restrict__ colsrc, int E)
{
    int b = blockIdx.x * 1024 + threadIdx.x;
    int e0 = b, e1 = b + 256, e2 = b + 512, e3 = b + 768;
    bool v0 = e0 < E, v1 = e1 < E, v2 = e2 < E, v3 = e3 < E;
    int d0=0,d1=0,d2=0,d3=0, s0=0,s1=0,s2=0,s3=0;
    if (v0){ d0 = ei[E + e0]; s0 = ei[e0]; }
    if (v1){ d1 = ei[E + e1]; s1 = ei[e1]; }
    if (v2){ d2 = ei[E + e2]; s2 = ei[e2]; }
    if (v3){ d3 = ei[E + e3]; s3 = ei[e3]; }
    int p0=0,p1=0,p2=0,p3=0;
    if (v0) p0 = rowptr[d0] + atomicAdd(&cursor[d0], 1);
    if (v1) p1 = rowptr[d1] + atomicAdd(&cursor[d1], 1);
    if (v2) p2 = rowptr[d2] + atomicAdd(&cursor[d2], 1);
    if (v3) p3 = rowptr[d3] + atomicAdd(&cursor[d3], 1);
    if (v0) colsrc[p0] = s0;
    if (v1) colsrc[p1] = s1;
    if (v2) colsrc[p2] = s2;
    if (v3) colsrc[p3] = s3;
}

// ----------------- node encoder stage 1: hid = relu(x@w1+b1), K=32, 64-row tiles -----------------
__global__ __launch_bounds__(256) void enc1_kernel(
        const float* __restrict__ x, const float* __restrict__ w1, const float* __restrict__ b1,
        float* __restrict__ hid, int n)
{
    __shared__ float As[32][68];
    __shared__ float Bs[32][128];
    int t = threadIdx.x;
    int m0 = blockIdx.x * 64;
    int tm = t >> 4, tn = t & 15;      // 16x16 threads; 4 rows x 8 cols each

    #pragma unroll
    for (int i = 0; i < 2; ++i){       // A: 64 rows x 32 k
        int f = i * 256 + t;
        int row = f >> 3, kq = f & 7;
        int gr = m0 + row; if (gr > n - 1) gr = n - 1;
        float4 v = *(const float4*)(x + (size_t)gr * 32 + kq * 4);
        As[kq*4+0][row] = v.x; As[kq*4+1][row] = v.y; As[kq*4+2][row] = v.z; As[kq*4+3][row] = v.w;
    }
    #pragma unroll
    for (int i = 0; i < 4; ++i){       // B: 32x128
        int f = i * 256 + t;
        int kk = f >> 5, nq = f & 31;
        *(float4*)&Bs[kk][nq*4] = *(const float4*)(w1 + (size_t)kk * 128 + nq * 4);
    }
    __syncthreads();

    float acc[4][8];
    #pragma unroll
    for (int i = 0; i < 4; ++i)
        #pragma unroll
        for (int j = 0; j < 8; ++j) acc[i][j] = 0.f;

    #pragma unroll 4
    for (int k = 0; k < 32; ++k){
        float a[4], b[8];
        *(float4*)&a[0] = *(float4*)&As[k][tm*4];
        *(float4*)&b[0] = *(float4*)&Bs[k][tn*8];
        *(float4*)&b[4] = *(float4*)&Bs[k][tn*8+4];
        #pragma unroll
        for (int i = 0; i < 4; ++i)
            #pragma unroll
            for (int j = 0; j < 8; ++j) acc[i][j] = fmaf(a[i], b[j], acc[i][j]);
    }

    float bb[8];
    *(float4*)&bb[0] = *(const float4*)(b1 + tn*8);
    *(float4*)&bb[4] = *(const float4*)(b1 + tn*8 + 4);
    #pragma unroll
    for (int i = 0; i < 4; ++i){
        int node = m0 + tm*4 + i;
        if (node < n){
            float o[8];
            #pragma unroll
            for (int j = 0; j < 8; ++j) o[j] = fmaxf(acc[i][j] + bb[j], 0.f);
            *(float4*)(hid + (size_t)node*HC + tn*8)     = *(float4*)&o[0];
            *(float4*)(hid + (size_t)node*HC + tn*8 + 4) = *(float4*)&o[4];
        }
    }
}

// ----------------- main GEMM (64-row tiles): C = A@W (+bias); ATT: bf16 C + att dots -----------------
template<bool ATT>
__global__ __launch_bounds__(256) void gemm_main_kernel(
        const float* __restrict__ A, const float* __restrict__ W, const float* __restrict__ bias,
        const float* __restrict__ att_s, const float* __restrict__ att_d,
        float* __restrict__ C, unsigned short* __restrict__ Cb,
        float* __restrict__ asrc, float* __restrict__ adst, int n)
{
    __shared__ float As[32][68];
    __shared__ float Bs[32][128];
    int t = threadIdx.x;
    int m0 = blockIdx.x * 64;
    int tm = t >> 4, tn = t & 15;

    float acc[4][8];
    #pragma unroll
    for (int i = 0; i < 4; ++i)
        #pragma unroll
        for (int j = 0; j < 8; ++j) acc[i][j] = 0.f;

    for (int kc = 0; kc < 4; ++kc){
        int k0 = kc * 32;
        #pragma unroll
        for (int i = 0; i < 2; ++i){        // A chunk 64x32, transposed into LDS
            int f = i * 256 + t;
            int row = f >> 3, kq = f & 7;
            int gr = m0 + row; if (gr > n - 1) gr = n - 1;
            float4 v = *(const float4*)(A + (size_t)gr * HC + k0 + kq * 4);
            As[kq*4+0][row] = v.x; As[kq*4+1][row] = v.y; As[kq*4+2][row] = v.z; As[kq*4+3][row] = v.w;
        }
        #pragma unroll
        for (int i = 0; i < 4; ++i){        // B chunk 32x128
            int f = i * 256 + t;
            int kk = f >> 5, nq = f & 31;
            *(float4*)&Bs[kk][nq*4] = *(const float4*)(W + (size_t)(k0 + kk) * 128 + nq * 4);
        }
        __syncthreads();
        #pragma unroll 4
        for (int k = 0; k < 32; ++k){
            float a[4], b[8];
            *(float4*)&a[0] = *(float4*)&As[k][tm*4];
            *(float4*)&b[0] = *(float4*)&Bs[k][tn*8];
            *(float4*)&b[4] = *(float4*)&Bs[k][tn*8+4];
            #pragma unroll
            for (int i = 0; i < 4; ++i)
                #pragma unroll
                for (int j = 0; j < 8; ++j) acc[i][j] = fmaf(a[i], b[j], acc[i][j]);
        }
        __syncthreads();
    }

    if (!ATT){
        float bb[8];
        *(float4*)&bb[0] = *(const float4*)(bias + tn*8);
        *(float4*)&bb[4] = *(const float4*)(bias + tn*8 + 4);
        #pragma unroll
        for (int i = 0; i < 4; ++i){
            int node = m0 + tm*4 + i;
            if (node < n){
                float o[8];
                #pragma unroll
                for (int j = 0; j < 8; ++j) o[j] = acc[i][j] + bb[j];
                *(float4*)(C + (size_t)node*HC + tn*8)     = *(float4*)&o[0];
                *(float4*)(C + (size_t)node*HC + tn*8 + 4) = *(float4*)&o[4];
            }
        }
    } else {
        #pragma unroll
        for (int i = 0; i < 4; ++i){
            int node = m0 + tm*4 + i;
            if (node < n){
                uint4 pk;
                pk.x = (unsigned int)f2bf(acc[i][0]) | ((unsigned int)f2bf(acc[i][1]) << 16);
                pk.y = (unsigned int)f2bf(acc[i][2]) | ((unsigned int)f2bf(acc[i][3]) << 16);
                pk.z = (unsigned int)f2bf(acc[i][4]) | ((unsigned int)f2bf(acc[i][5]) << 16);
                pk.w = (unsigned int)f2bf(acc[i][6]) | ((unsigned int)f2bf(acc[i][7]) << 16);
                *(uint4*)(Cb + (size_t)node*HC + tn*8) = pk;
            }
        }
        float ats[8], atd[8];
        *(float4*)&ats[0] = *(const float4*)(att_s + tn*8);
        *(float4*)&ats[4] = *(const float4*)(att_s + tn*8 + 4);
        *(float4*)&atd[0] = *(const float4*)(att_d + tn*8);
        *(float4*)&atd[4] = *(const float4*)(att_d + tn*8 + 4);
        #pragma unroll
        for (int i = 0; i < 4; ++i){
            float sa = 0.f, sd = 0.f;
            #pragma unroll
            for (int j = 0; j < 8; ++j){
                sa = fmaf(acc[i][j], ats[j], sa);
                sd = fmaf(acc[i][j], atd[j], sd);
            }
            sa += __shfl_xor(sa, 1); sa += __shfl_xor(sa, 2); sa += __shfl_xor(sa, 4);
            sd += __shfl_xor(sd, 1); sd += __shfl_xor(sd, 2); sd += __shfl_xor(sd, 4);
            int node = m0 + tm*4 + i;
            if ((tn == 0 || tn == 8) && node < n){
                int head = tn >> 3;
                asrc[(size_t)node*2 + head] = sa;
                adst[(size_t)node*2 + head] = sd;
            }
        }
    }
}

// ----------------- aggregation: 1 wave/node; exp computed once/edge in-wave -----------------
__global__ __launch_bounds__(64) void aggregate_kernel(
        const unsigned short* __restrict__ h1b, const float* __restrict__ asrc, const float* __restrict__ adst,
        const int* __restrict__ rowptr, const int* __restrict__ colsrc,
        const float* __restrict__ bias, float* __restrict__ hout, int n)
{
    int i = blockIdx.x;
    if (i >= n) return;
    int t = threadIdx.x;              // 64 lanes, 2 channels each (one uint of 2 bf16)
    int head = t >> 5;
    float2 adv = *(const float2*)(adst + (size_t)i * 2);
    float2 asv = *(const float2*)(asrc + (size_t)i * 2);
    float ads = head ? adv.y : adv.x;
    // self loop (GATConv add_self_loops=True)
    float exs = __expf(lrelu((head ? asv.y : asv.x) + ads));
    unsigned int hv = ((const unsigned int*)(h1b + (size_t)i * HC))[t];
    float acc0 = exs * bf_lo(hv), acc1 = exs * bf_hi(hv), D = exs;

    int e  = rowptr[i];
    int e1 = rowptr[i + 1];
    while (e < e1){
        int m = e1 - e; if (m > 64) m = 64;
        int   sl  = 0;
        float ex0 = 0.f, ex1 = 0.f;
        if (t < m){
            sl = colsrc[e + t];                       // coalesced
            float2 as = *(const float2*)(asrc + (size_t)sl * 2);
            ex0 = __expf(lrelu(as.x + adv.x));
            ex1 = __expf(lrelu(as.y + adv.y));
        }
        int j = 0;
        for (; j + 2 <= m; j += 2){
            int   sa  = __shfl(sl,  j),     sb  = __shfl(sl,  j + 1);
            float ea0 = __shfl(ex0, j),     eb0 = __shfl(ex0, j + 1);
            float ea1 = __shfl(ex1, j),     eb1 = __shfl(ex1, j + 1);
            unsigned int va = ((const unsigned int*)(h1b + (size_t)sa * HC))[t];
            unsigned int vb = ((const unsigned int*)(h1b + (size_t)sb * HC))[t];
            float ea = head ? ea1 : ea0;
            float eb = head ? eb1 : eb0;
            acc0 = fmaf(ea, bf_lo(va), acc0);
            acc1 = fmaf(ea, bf_hi(va), acc1);
            acc0 = fmaf(eb, bf_lo(vb), acc0);
            acc1 = fmaf(eb, bf_hi(vb), acc1);
            D += ea + eb;
        }
        if (j < m){
            int   sa  = __shfl(sl,  j);
            float ea0 = __shfl(ex0, j);
            float ea1 = __shfl(ex1, j);
            unsigned int va = ((const unsigned int*)(h1b + (size_t)sa * HC))[t];
            float ea = head ? ea1 : ea0;
            acc0 = fmaf(ea, bf_lo(va), acc0);
            acc1 = fmaf(ea, bf_hi(va), acc1);
            D += ea;
        }
        e += m;
    }
    float rD = 1.0f / D;
    float o0 = fmaxf(acc0 * rD + bias[2*t],     0.f);
    float o1 = fmaxf(acc1 * rD + bias[2*t + 1], 0.f);
    ((float2*)(hout + (size_t)i * HC))[t] = make_float2(o0, o1);
}

// ----------------- graph mean: two-stage, NO global atomics -----------------
__global__ __launch_bounds__(256) void mean_part_kernel(
        const float* __restrict__ h, float* __restrict__ partial, int n)
{
    int t = threadIdx.x;
    int cq = t & 31;
    int rl = t >> 5;
    float4 acc = make_float4(0.f, 0.f, 0.f, 0.f);
    for (int i = blockIdx.x * 8 + rl; i < n; i += gridDim.x * 8){
        float4 v = *(const float4*)(h + (size_t)i * HC + cq * 4);
        acc.x += v.x; acc.y += v.y; acc.z += v.z; acc.w += v.w;
    }
    __shared__ float4 red[256];
    red[t] = acc;
    __syncthreads();
    if (t < 128){
        float4 o = red[t + 128];
        red[t].x += o.x; red[t].y += o.y; red[t].z += o.z; red[t].w += o.w;
    }
    __syncthreads();
    if (t < 64){
        float4 o = red[t + 64];
        red[t].x += o.x; red[t].y += o.y; red[t].z += o.z; red[t].w += o.w;
    }
    __syncthreads();
    if (t < 32){
        float4 a = red[t], b = red[t + 32];
        float4 s = make_float4(a.x + b.x, a.y + b.y, a.z + b.z, a.w + b.w);
        *(float4*)(partial + (size_t)blockIdx.x * HC + t * 4) = s;
    }
}

__global__ __launch_bounds__(256) void mean_fin_kernel(
        const float* __restrict__ partial, float* __restrict__ g, int nb)
{
    int t = threadIdx.x;
    int cq = t & 31, b0 = t >> 5;
    float4 acc = make_float4(0.f, 0.f, 0.f, 0.f);
    for (int b = b0; b < nb; b += 8){
        float4 v = *(const float4*)(partial + (size_t)b * HC + cq * 4);
        acc.x += v.x; acc.y += v.y; acc.z += v.z; acc.w += v.w;
    }
    __shared__ float4 red[256];
    red[t] = acc;
    __syncthreads();
    if (t < 128){
        float4 o = red[t + 128];
        red[t].x += o.x; red[t].y += o.y; red[t].z += o.z; red[t].w += o.w;
    }
    __syncthreads();
    if (t < 64){
        float4 o = red[t + 64];
        red[t].x += o.x; red[t].y += o.y; red[t].z += o.z; red[t].w += o.w;
    }
    __syncthreads();
    if (t < 32){
        float4 a = red[t], b = red[t + 32];
        float4 s = make_float4(a.x + b.x, a.y + b.y, a.z + b.z, a.w + b.w);
        *(float4*)(g + t * 4) = s;
    }
}

// ----------------- vuln head (64-row tiles): sigmoid(relu(h@wv1+bv1)@wv2+bv2) -----------------
__global__ __launch_bounds__(256) void vuln_fused_kernel(
        const float* __restrict__ h, const float* __restrict__ wv1, const float* __restrict__ bv1,
        const float* __restrict__ wv2, const float* __restrict__ bv2,
        float* __restrict__ out, int n)
{
    __shared__ float As[32][68];
    __shared__ float Bs[32][64];
    int t = threadIdx.x;
    int m0 = blockIdx.x * 64;
    int tm = t >> 4, tn = t & 15;

    float acc[4][4];
    #pragma unroll
    for (int i = 0; i < 4; ++i)
        #pragma unroll
        for (int j = 0; j < 4; ++j) acc[i][j] = 0.f;

    for (int kc = 0; kc < 4; ++kc){
        int k0 = kc * 32;
        #pragma unroll
        for (int i = 0; i < 2; ++i){
            int f = i * 256 + t;
            int row = f >> 3, kq = f & 7;
            int gr = m0 + row; if (gr > n - 1) gr = n - 1;
            float4 v = *(const float4*)(h + (size_t)gr * HC + k0 + kq * 4);
            As[kq*4+0][row] = v.x; As[kq*4+1][row] = v.y; As[kq*4+2][row] = v.z; As[kq*4+3][row] = v.w;
        }
        #pragma unroll
        for (int i = 0; i < 2; ++i){        // B chunk 32x64
            int f = i * 256 + t;
            int kk = f >> 4, nq = f & 15;
            *(float4*)&Bs[kk][nq*4] = *(const float4*)(wv1 + (size_t)(k0 + kk) * 64 + nq * 4);
        }
        __syncthreads();
        #pragma unroll 4
        for (int k = 0; k < 32; ++k){
            float a[4], b[4];
            *(float4*)&a[0] = *(float4*)&As[k][tm*4];
            *(float4*)&b[0] = *(float4*)&Bs[k][tn*4];
            #pragma unroll
            for (int i = 0; i < 4; ++i)
                #pragma unroll
                for (int j = 0; j < 4; ++j) acc[i][j] = fmaf(a[i], b[j], acc[i][j]);
        }
        __syncthreads();
    }

    float bb[4], wv[4];
    *(float4*)&bb[0] = *(const float4*)(bv1 + tn*4);
    *(float4*)&wv[0] = *(const float4*)(wv2 + tn*4);
    float bv2v = bv2[0];
    #pragma unroll
    for (int i = 0; i < 4; ++i){
        float v = 0.f;
        #pragma unroll
        for (int j = 0; j < 4; ++j) v = fmaf(fmaxf(acc[i][j] + bb[j], 0.f), wv[j], v);
        v += __shfl_xor(v, 1); v += __shfl_xor(v, 2);
        v += __shfl_xor(v, 4); v += __shfl_xor(v, 8);
        int node = m0 + tm*4 + i;
        if (tn == 0 && node < n)
            out[1 + node] = 1.0f / (1.0f + __expf(-(v + bv2v)));
    }
}

// ----------------- path head (1 block) -----------------
__global__ __launch_bounds__(128) void path_kernel(
        const float* __restrict__ h, const float* __restrict__ g,
        const float* __restrict__ wp1, const float* __restrict__ bp1,
        const float* __restrict__ wp2, const float* __restrict__ bp2,
        const float* __restrict__ wp3, const float* __restrict__ bp3,
        float* __restrict__ out, int n)
{
    __shared__ float pc[256];
    __shared__ float p1[HC];
    __shared__ float p2[64];
    int t = threadIdx.x;              // 128
    pc[t]       = h[t];               // h[0,:]
    pc[128 + t] = g[t] * (1.0f / (float)n);
    __syncthreads();
    float a = bp1[t];
    for (int k = 0; k < 256; ++k) a = fmaf(pc[k], wp1[k * HC + t], a);
    p1[t] = fmaxf(a, 0.f);
    __syncthreads();
    if (t < 64){
        float a2 = bp2[t];
        for (int k = 0; k < HC; ++k) a2 = fmaf(p1[k], wp2[k * 64 + t], a2);
        p2[t] = fmaxf(a2, 0.f);
    }
    __syncthreads();
    if (t == 0){
        float a3 = bp3[0];
        for (int k = 0; k < 64; ++k) a3 = fmaf(p2[k], wp3[k], a3);
        out[0] = 1.0f / (1.0f + __expf(-a3));
        out[1 + n] = 0.f;             // esc = 0
    }
}

extern "C" void kernel_launch(void* const* d_in, const int* in_sizes, int n_in,
                              void* d_out, int out_size, void* d_ws, size_t ws_size,
                              hipStream_t stream)
{
    const float* x    = (const float*)d_in[0];
    const int*   ei   = (const int*)d_in[1];
    const float* w_n1 = (const float*)d_in[3];
    const float* b_n1 = (const float*)d_in[4];
    const float* w_n2 = (const float*)d_in[5];
    const float* b_n2 = (const float*)d_in[6];
    const float* conv_w = (const float*)d_in[9];
    const float* att_s  = (const float*)d_in[10];
    const float* att_d  = (const float*)d_in[11];
    const float* conv_b = (const float*)d_in[12];
    const float* wp1 = (const float*)d_in[13];
    const float* bp1 = (const float*)d_in[14];
    const float* wp2 = (const float*)d_in[15];
    const float* bp2 = (const float*)d_in[16];
    const float* wp3 = (const float*)d_in[17];
    const float* bp3 = (const float*)d_in[18];
    const float* wv1 = (const float*)d_in[19];
    const float* bv1 = (const float*)d_in[20];
    const float* wv2 = (const float*)d_in[21];
    const float* bv2 = (const float*)d_in[22];

    const int N = in_sizes[0] / 32;
    const int E = in_sizes[1] / 2;
    float* out = (float*)d_out;

    char* ws = (char*)d_ws;
    size_t off = 0;
    auto take = [&](size_t bytes) -> char* {
        char* p = ws + off;
        off += (bytes + 255) & ~(size_t)255;
        return p;
    };
    float* hA    = (float*)take((size_t)N * HC * 4);
    float* hB    = (float*)take((size_t)N * HC * 4);   // f32 hid OR bf16 h' (reused)
    float* asrc  = (float*)take((size_t)N * 2 * 4);
    float* adst  = (float*)take((size_t)N * 2 * 4);
    int*   rowptr= (int*)take((size_t)(N + 1) * 4);
    int*   cursor= (int*)take((size_t)N * 4);
    int*   colsrc= (int*)take((size_t)E * 4);
    float* g     = (float*)take(HC * 4);
    const int MB = 64;                                  // mean partial blocks
    float* mpart = (float*)take((size_t)MB * HC * 4);
    int nb = (N + 1023) / 1024;
    int*   bsum  = (int*)take((size_t)((nb + 63) & ~63) * 4);
    int*   boff  = (int*)take((size_t)((nb + 63) & ~63) * 4);
    unsigned short* hBb = (unsigned short*)hB;

    // --- CSR build (dst-sorted; reused across the 3 layers) ---
    hipMemsetAsync(cursor, 0, (size_t)N * 4, stream);
    count_kernel<<<(E + 255) / 256, 256, 0, stream>>>(ei, cursor, E);
    scan_part_kernel<<<nb, 256, 0, stream>>>(cursor, bsum, N);
    scan_top_kernel<<<1, 64, 0, stream>>>(bsum, boff, rowptr, nb, N);
    scan_fin_kernel<<<nb, 256, 0, stream>>>(cursor, boff, rowptr, N);
    hipMemsetAsync(cursor, 0, (size_t)N * 4, stream);
    scatter_kernel<<<(E + 1023) / 1024, 256, 0, stream>>>(ei, rowptr, cursor, colsrc, E);

    int nblk64 = (N + 63) / 64;
    // node encoder: hid (hB f32) = relu(x@w1+b1); hA = hid@w2 + b2
    enc1_kernel<<<nblk64, 256, 0, stream>>>(x, w_n1, b_n1, hB, N);
    gemm_main_kernel<false><<<nblk64, 256, 0, stream>>>(
        hB, w_n2, b_n2, nullptr, nullptr, hA, nullptr, nullptr, nullptr, N);

    for (int l = 0; l < 3; ++l){
        gemm_main_kernel<true><<<nblk64, 256, 0, stream>>>(
            hA, conv_w + (size_t)l * HC * HC, nullptr,
            att_s + (size_t)l * HC, att_d + (size_t)l * HC,
            nullptr, hBb, asrc, adst, N);
        aggregate_kernel<<<N, 64, 0, stream>>>(
            hBb, asrc, adst, rowptr, colsrc, conv_b + (size_t)l * HC, hA, N);
    }

    mean_part_kernel<<<MB, 256, 0, stream>>>(hA, mpart, N);
    mean_fin_kernel<<<1, 256, 0, stream>>>(mpart, g, MB);
    vuln_fused_kernel<<<nblk64, 256, 0, stream>>>(hA, wv1, bv1, wv2, bv2, out, N);
    path_kernel<<<1, 128, 0, stream>>>(hA, g, wp1, bp1, wp2, bp2, wp3, bp3, out, N);
}

// Round 9
// 372.460 us; speedup vs baseline: 1.3252x; 1.1182x over previous
//
#include <hip/hip_runtime.h>
#include <math.h>

#define HC 128
#define NSLOPE 0.2f

__device__ __forceinline__ float lrelu(float v){ return v > 0.f ? v : NSLOPE * v; }

// bf16 round-to-nearest-even pack / unpack
__device__ __forceinline__ unsigned short f2bf(float f){
    unsigned int b = __float_as_uint(f);
    b += 0x7FFFu + ((b >> 16) & 1u);
    return (unsigned short)(b >> 16);
}
__device__ __forceinline__ float bf_lo(unsigned int v){ return __uint_as_float(v << 16); }
__device__ __forceinline__ float bf_hi(unsigned int v){ return __uint_as_float(v & 0xFFFF0000u); }
__device__ __forceinline__ float bf1(unsigned short v){ return __uint_as_float((unsigned int)v << 16); }

// ----------------- CSR build (dst-sorted) -----------------
// count + per-edge rank (the atomicAdd return IS the rank within the dst list)
__global__ void count_kernel(const int* __restrict__ ei, int* __restrict__ cnt,
                             int* __restrict__ rank, int E){
    int e = blockIdx.x * blockDim.x + threadIdx.x;
    if (e < E) rank[e] = atomicAdd(&cnt[ei[E + e]], 1);
}

// S1: per-block (1024 nodes) partial sums
__global__ __launch_bounds__(256) void scan_part_kernel(
        const int* __restrict__ deg, int* __restrict__ bsum, int n)
{
    int t = threadIdx.x, lane = t & 63, wid = t >> 6;
    int base = blockIdx.x * 1024 + t * 4;
    int s = 0;
    #pragma unroll
    for (int j = 0; j < 4; ++j){ int i = base + j; if (i < n) s += deg[i]; }
    #pragma unroll
    for (int o = 1; o < 64; o <<= 1) s += __shfl_xor(s, o);
    __shared__ int red[4];
    if (lane == 0) red[wid] = s;
    __syncthreads();
    if (t == 0) bsum[blockIdx.x] = red[0] + red[1] + red[2] + red[3];
}

// S2: 1 wave scans the (<=64) block sums; writes exclusive offsets + rowptr[n]=total
__global__ __launch_bounds__(64) void scan_top_kernel(
        const int* __restrict__ bsum, int* __restrict__ boff, int* __restrict__ rowptr,
        int nb, int n)
{
    int t = threadIdx.x;
    int v = (t < nb) ? bsum[t] : 0;
    int incl = v;
    #pragma unroll
    for (int o = 1; o < 64; o <<= 1){ int u = __shfl_up(incl, o); if (t >= o) incl += u; }
    if (t < nb) boff[t] = incl - v;
    if (t == 63) rowptr[n] = incl;
}

// S3: per-block exclusive scan with global offset -> rowptr[0..n-1]
__global__ __launch_bounds__(256) void scan_fin_kernel(
        const int* __restrict__ deg, const int* __restrict__ boff,
        int* __restrict__ rowptr, int n)
{
    int t = threadIdx.x, lane = t & 63, wid = t >> 6;
    int base = blockIdx.x * 1024 + t * 4;
    int d[4]; int s = 0;
    #pragma unroll
    for (int j = 0; j < 4; ++j){ int i = base + j; d[j] = (i < n) ? deg[i] : 0; s += d[j]; }
    int incl = s;
    #pragma unroll
    for (int o = 1; o < 64; o <<= 1){ int u = __shfl_up(incl, o); if (lane >= o) incl += u; }
    __shared__ int wsum[4];
    if (lane == 63) wsum[wid] = incl;
    __syncthreads();
    int off = boff[blockIdx.x] + (incl - s);
    for (int w = 0; w < wid; ++w) off += wsum[w];
    #pragma unroll
    for (int j = 0; j < 4; ++j){
        int i = base + j;
        if (i < n) rowptr[i] = off;
        off += d[j];
    }
}

// stateless scatter: pos = rowptr[d] + rank[e]; 4 independent chains per thread
__global__ __launch_bounds__(256) void scatter_kernel(
        const int* __restrict__ ei, const int* __restrict__ rowptr,
        const int* __restrict__ rank, int* __restrict__ colsrc, int E)
{
    int b = blockIdx.x * 1024 + threadIdx.x;
    int e0 = b, e1 = b + 256, e2 = b + 512, e3 = b + 768;
    bool v0 = e0 < E, v1 = e1 < E, v2 = e2 < E, v3 = e3 < E;
    int d0=0,d1=0,d2=0,d3=0, s0=0,s1=0,s2=0,s3=0, r0=0,r1=0,r2=0,r3=0;
    if (v0){ d0 = ei[E + e0]; s0 = ei[e0]; r0 = rank[e0]; }
    if (v1){ d1 = ei[E + e1]; s1 = ei[e1]; r1 = rank[e1]; }
    if (v2){ d2 = ei[E + e2]; s2 = ei[e2]; r2 = rank[e2]; }
    if (v3){ d3 = ei[E + e3]; s3 = ei[e3]; r3 = rank[e3]; }
    if (v0) colsrc[rowptr[d0] + r0] = s0;
    if (v1) colsrc[rowptr[d1] + r1] = s1;
    if (v2) colsrc[rowptr[d2] + r2] = s2;
    if (v3) colsrc[rowptr[d3] + r3] = s3;
}

// ----------------- node encoder stage 1: hid(bf16) = relu(x@w1+b1), K=32 -----------------
__global__ __launch_bounds__(256) void enc1_kernel(
        const float* __restrict__ x, const float* __restrict__ w1, const float* __restrict__ b1,
        unsigned short* __restrict__ hid, int n)
{
    __shared__ float As[32][68];
    __shared__ float Bs[32][128];
    int t = threadIdx.x;
    int m0 = blockIdx.x * 64;
    int tm = t >> 4, tn = t & 15;      // 16x16 threads; 4 rows x 8 cols each

    #pragma unroll
    for (int i = 0; i < 2; ++i){       // A: 64 rows x 32 k (f32 input)
        int f = i * 256 + t;
        int row = f >> 3, kq = f & 7;
        int gr = m0 + row; if (gr > n - 1) gr = n - 1;
        float4 v = *(const float4*)(x + (size_t)gr * 32 + kq * 4);
        As[kq*4+0][row] = v.x; As[kq*4+1][row] = v.y; As[kq*4+2][row] = v.z; As[kq*4+3][row] = v.w;
    }
    #pragma unroll
    for (int i = 0; i < 4; ++i){       // B: 32x128
        int f = i * 256 + t;
        int kk = f >> 5, nq = f & 31;
        *(float4*)&Bs[kk][nq*4] = *(const float4*)(w1 + (size_t)kk * 128 + nq * 4);
    }
    __syncthreads();

    float acc[4][8];
    #pragma unroll
    for (int i = 0; i < 4; ++i)
        #pragma unroll
        for (int j = 0; j < 8; ++j) acc[i][j] = 0.f;

    #pragma unroll 4
    for (int k = 0; k < 32; ++k){
        float a[4], b[8];
        *(float4*)&a[0] = *(float4*)&As[k][tm*4];
        *(float4*)&b[0] = *(float4*)&Bs[k][tn*8];
        *(float4*)&b[4] = *(float4*)&Bs[k][tn*8+4];
        #pragma unroll
        for (int i = 0; i < 4; ++i)
            #pragma unroll
            for (int j = 0; j < 8; ++j) acc[i][j] = fmaf(a[i], b[j], acc[i][j]);
    }

    float bb[8];
    *(float4*)&bb[0] = *(const float4*)(b1 + tn*8);
    *(float4*)&bb[4] = *(const float4*)(b1 + tn*8 + 4);
    #pragma unroll
    for (int i = 0; i < 4; ++i){
        int node = m0 + tm*4 + i;
        if (node < n){
            float o[8];
            #pragma unroll
            for (int j = 0; j < 8; ++j) o[j] = fmaxf(acc[i][j] + bb[j], 0.f);
            uint4 pk;
            pk.x = (unsigned int)f2bf(o[0]) | ((unsigned int)f2bf(o[1]) << 16);
            pk.y = (unsigned int)f2bf(o[2]) | ((unsigned int)f2bf(o[3]) << 16);
            pk.z = (unsigned int)f2bf(o[4]) | ((unsigned int)f2bf(o[5]) << 16);
            pk.w = (unsigned int)f2bf(o[6]) | ((unsigned int)f2bf(o[7]) << 16);
            *(uint4*)(hid + (size_t)node*HC + tn*8) = pk;
        }
    }
}

// ----------------- main GEMM: C(bf16) = A(bf16)@W (+bias); ATT adds att dots -----------------
template<bool ATT>
__global__ __launch_bounds__(256) void gemm_main_kernel(
        const unsigned short* __restrict__ A, const float* __restrict__ W, const float* __restrict__ bias,
        const float* __restrict__ att_s, const float* __restrict__ att_d,
        unsigned short* __restrict__ Cb,
        float* __restrict__ asrc, float* __restrict__ adst, int n)
{
    __shared__ float As[32][68];
    __shared__ float Bs[32][128];
    int t = threadIdx.x;
    int m0 = blockIdx.x * 64;
    int tm = t >> 4, tn = t & 15;

    float acc[4][8];
    #pragma unroll
    for (int i = 0; i < 4; ++i)
        #pragma unroll
        for (int j = 0; j < 8; ++j) acc[i][j] = 0.f;

    for (int kc = 0; kc < 4; ++kc){
        int k0 = kc * 32;
        {   // A chunk 64x32 bf16 (4KB): one pass, 8 bf16 per thread
            int row = t >> 2, kq = t & 3;
            int gr = m0 + row; if (gr > n - 1) gr = n - 1;
            uint4 v = *(const uint4*)(A + (size_t)gr * HC + k0 + kq * 8);
            As[kq*8+0][row] = bf_lo(v.x); As[kq*8+1][row] = bf_hi(v.x);
            As[kq*8+2][row] = bf_lo(v.y); As[kq*8+3][row] = bf_hi(v.y);
            As[kq*8+4][row] = bf_lo(v.z); As[kq*8+5][row] = bf_hi(v.z);
            As[kq*8+6][row] = bf_lo(v.w); As[kq*8+7][row] = bf_hi(v.w);
        }
        #pragma unroll
        for (int i = 0; i < 4; ++i){        // B chunk 32x128 f32
            int f = i * 256 + t;
            int kk = f >> 5, nq = f & 31;
            *(float4*)&Bs[kk][nq*4] = *(const float4*)(W + (size_t)(k0 + kk) * 128 + nq * 4);
        }
        __syncthreads();
        #pragma unroll 4
        for (int k = 0; k < 32; ++k){
            float a[4], b[8];
            *(float4*)&a[0] = *(float4*)&As[k][tm*4];
            *(float4*)&b[0] = *(float4*)&Bs[k][tn*8];
            *(float4*)&b[4] = *(float4*)&Bs[k][tn*8+4];
            #pragma unroll
            for (int i = 0; i < 4; ++i)
                #pragma unroll
                for (int j = 0; j < 8; ++j) acc[i][j] = fmaf(a[i], b[j], acc[i][j]);
        }
        __syncthreads();
    }

    float bb[8];
    if (!ATT){
        *(float4*)&bb[0] = *(const float4*)(bias + tn*8);
        *(float4*)&bb[4] = *(const float4*)(bias + tn*8 + 4);
    } else {
        #pragma unroll
        for (int j = 0; j < 8; ++j) bb[j] = 0.f;
    }
    #pragma unroll
    for (int i = 0; i < 4; ++i){
        int node = m0 + tm*4 + i;
        if (node < n){
            float o[8];
            #pragma unroll
            for (int j = 0; j < 8; ++j) o[j] = acc[i][j] + bb[j];
            uint4 pk;
            pk.x = (unsigned int)f2bf(o[0]) | ((unsigned int)f2bf(o[1]) << 16);
            pk.y = (unsigned int)f2bf(o[2]) | ((unsigned int)f2bf(o[3]) << 16);
            pk.z = (unsigned int)f2bf(o[4]) | ((unsigned int)f2bf(o[5]) << 16);
            pk.w = (unsigned int)f2bf(o[6]) | ((unsigned int)f2bf(o[7]) << 16);
            *(uint4*)(Cb + (size_t)node*HC + tn*8) = pk;
        }
    }

    if (ATT){
        float ats[8], atd[8];
        *(float4*)&ats[0] = *(const float4*)(att_s + tn*8);
        *(float4*)&ats[4] = *(const float4*)(att_s + tn*8 + 4);
        *(float4*)&atd[0] = *(const float4*)(att_d + tn*8);
        *(float4*)&atd[4] = *(const float4*)(att_d + tn*8 + 4);
        #pragma unroll
        for (int i = 0; i < 4; ++i){
            float sa = 0.f, sd = 0.f;
            #pragma unroll
            for (int j = 0; j < 8; ++j){
                sa = fmaf(acc[i][j], ats[j], sa);
                sd = fmaf(acc[i][j], atd[j], sd);
            }
            sa += __shfl_xor(sa, 1); sa += __shfl_xor(sa, 2); sa += __shfl_xor(sa, 4);
            sd += __shfl_xor(sd, 1); sd += __shfl_xor(sd, 2); sd += __shfl_xor(sd, 4);
            int node = m0 + tm*4 + i;
            if ((tn == 0 || tn == 8) && node < n){
                int head = tn >> 3;
                asrc[(size_t)node*2 + head] = sa;
                adst[(size_t)node*2 + head] = sd;
            }
        }
    }
}

// ----------------- aggregation: 1 wave/node; LDS coef table; 4-deep gather pipeline -----------------
__global__ __launch_bounds__(64) void aggregate_kernel(
        const unsigned short* __restrict__ h1b, const float* __restrict__ asrc, const float* __restrict__ adst,
        const int* __restrict__ rowptr, const int* __restrict__ colsrc,
        const float* __restrict__ bias, unsigned short* __restrict__ hout, int n)
{
    __shared__ float4 exl[64];
    int i = blockIdx.x;
    if (i >= n) return;
    int t = threadIdx.x;              // 64 lanes, 2 channels each (one uint of 2 bf16)
    int head = t >> 5;
    float2 adv = *(const float2*)(adst + (size_t)i * 2);
    float2 asv = *(const float2*)(asrc + (size_t)i * 2);
    float ads = head ? adv.y : adv.x;
    // self loop (GATConv add_self_loops=True)
    float exs = __expf(lrelu((head ? asv.y : asv.x) + ads));
    unsigned int hv = ((const unsigned int*)(h1b + (size_t)i * HC))[t];
    float acc0 = exs * bf_lo(hv), acc1 = exs * bf_hi(hv), D = exs;

    int e  = rowptr[i];
    int e1 = rowptr[i + 1];
    while (e < e1){
        int m = e1 - e; if (m > 64) m = 64;
        if (t < m){
            int s = colsrc[e + t];                       // coalesced
            float2 as = *(const float2*)(asrc + (size_t)s * 2);
            exl[t] = make_float4(__int_as_float(s),
                                 __expf(lrelu(as.x + adv.x)),
                                 __expf(lrelu(as.y + adv.y)), 0.f);
        }
        __syncthreads();
        int j = 0;
        for (; j + 4 <= m; j += 4){
            float4 q0 = exl[j], q1 = exl[j+1], q2 = exl[j+2], q3 = exl[j+3];
            const unsigned int* p0 = (const unsigned int*)(h1b + (size_t)__float_as_int(q0.x) * HC);
            const unsigned int* p1 = (const unsigned int*)(h1b + (size_t)__float_as_int(q1.x) * HC);
            const unsigned int* p2 = (const unsigned int*)(h1b + (size_t)__float_as_int(q2.x) * HC);
            const unsigned int* p3 = (const unsigned int*)(h1b + (size_t)__float_as_int(q3.x) * HC);
            unsigned int v0 = p0[t], v1 = p1[t], v2 = p2[t], v3 = p3[t];  // 4 gathers in flight
            float c0 = head ? q0.z : q0.y;
            float c1 = head ? q1.z : q1.y;
            float c2 = head ? q2.z : q2.y;
            float c3 = head ? q3.z : q3.y;
            acc0 = fmaf(c0, bf_lo(v0), acc0);  acc1 = fmaf(c0, bf_hi(v0), acc1);
            acc0 = fmaf(c1, bf_lo(v1), acc0);  acc1 = fmaf(c1, bf_hi(v1), acc1);
            acc0 = fmaf(c2, bf_lo(v2), acc0);  acc1 = fmaf(c2, bf_hi(v2), acc1);
            acc0 = fmaf(c3, bf_lo(v3), acc0);  acc1 = fmaf(c3, bf_hi(v3), acc1);
            D += (c0 + c1) + (c2 + c3);
        }
        for (; j < m; ++j){
            float4 q = exl[j];
            unsigned int v = ((const unsigned int*)(h1b + (size_t)__float_as_int(q.x) * HC))[t];
            float c = head ? q.z : q.y;
            acc0 = fmaf(c, bf_lo(v), acc0);
            acc1 = fmaf(c, bf_hi(v), acc1);
            D += c;
        }
        __syncthreads();
        e += m;
    }
    float rD = 1.0f / D;
    float o0 = fmaxf(acc0 * rD + bias[2*t],     0.f);
    float o1 = fmaxf(acc1 * rD + bias[2*t + 1], 0.f);
    ((unsigned int*)hout)[(size_t)i * 64 + t] =
        (unsigned int)f2bf(o0) | ((unsigned int)f2bf(o1) << 16);
}

// ----------------- graph mean: two-stage, bf16 input, NO global atomics -----------------
__global__ __launch_bounds__(256) void mean_part_kernel(
        const unsigned short* __restrict__ h, float* __restrict__ partial, int n)
{
    int t = threadIdx.x;
    int cq = t & 31;                   // channel quad: channels cq*4 .. cq*4+3
    int rl = t >> 5;                   // row lane 0..7
    float4 acc = make_float4(0.f, 0.f, 0.f, 0.f);
    for (int i = blockIdx.x * 8 + rl; i < n; i += gridDim.x * 8){
        uint2 v = *(const uint2*)(h + (size_t)i * HC + cq * 4);
        acc.x += bf_lo(v.x); acc.y += bf_hi(v.x);
        acc.z += bf_lo(v.y); acc.w += bf_hi(v.y);
    }
    __shared__ float4 red[256];
    red[t] = acc;
    __syncthreads();
    if (t < 128){
        float4 o = red[t + 128];
        red[t].x += o.x; red[t].y += o.y; red[t].z += o.z; red[t].w += o.w;
    }
    __syncthreads();
    if (t < 64){
        float4 o = red[t + 64];
        red[t].x += o.x; red[t].y += o.y; red[t].z += o.z; red[t].w += o.w;
    }
    __syncthreads();
    if (t < 32){
        float4 a = red[t], b = red[t + 32];
        float4 s = make_float4(a.x + b.x, a.y + b.y, a.z + b.z, a.w + b.w);
        *(float4*)(partial + (size_t)blockIdx.x * HC + t * 4) = s;
    }
}

__global__ __launch_bounds__(256) void mean_fin_kernel(
        const float* __restrict__ partial, float* __restrict__ g, int nb)
{
    int t = threadIdx.x;
    int cq = t & 31, b0 = t >> 5;
    float4 acc = make_float4(0.f, 0.f, 0.f, 0.f);
    for (int b = b0; b < nb; b += 8){
        float4 v = *(const float4*)(partial + (size_t)b * HC + cq * 4);
        acc.x += v.x; acc.y += v.y; acc.z += v.z; acc.w += v.w;
    }
    __shared__ float4 red[256];
    red[t] = acc;
    __syncthreads();
    if (t < 128){
        float4 o = red[t + 128];
        red[t].x += o.x; red[t].y += o.y; red[t].z += o.z; red[t].w += o.w;
    }
    __syncthreads();
    if (t < 64){
        float4 o = red[t + 64];
        red[t].x += o.x; red[t].y += o.y; red[t].z += o.z; red[t].w += o.w;
    }
    __syncthreads();
    if (t < 32){
        float4 a = red[t], b = red[t + 32];
        float4 s = make_float4(a.x + b.x, a.y + b.y, a.z + b.z, a.w + b.w);
        *(float4*)(g + t * 4) = s;
    }
}

// ----------------- vuln head (bf16 input): sigmoid(relu(h@wv1+bv1)@wv2+bv2) -----------------
__global__ __launch_bounds__(256) void vuln_fused_kernel(
        const unsigned short* __restrict__ h, const float* __restrict__ wv1, const float* __restrict__ bv1,
        const float* __restrict__ wv2, const float* __restrict__ bv2,
        float* __restrict__ out, int n)
{
    __shared__ float As[32][68];
    __shared__ float Bs[32][64];
    int t = threadIdx.x;
    int m0 = blockIdx.x * 64;
    int tm = t >> 4, tn = t & 15;

    float acc[4][4];
    #pragma unroll
    for (int i = 0; i < 4; ++i)
        #pragma unroll
        for (int j = 0; j < 4; ++j) acc[i][j] = 0.f;

    for (int kc = 0; kc < 4; ++kc){
        int k0 = kc * 32;
        {
            int row = t >> 2, kq = t & 3;
            int gr = m0 + row; if (gr > n - 1) gr = n - 1;
            uint4 v = *(const uint4*)(h + (size_t)gr * HC + k0 + kq * 8);
            As[kq*8+0][row] = bf_lo(v.x); As[kq*8+1][row] = bf_hi(v.x);
            As[kq*8+2][row] = bf_lo(v.y); As[kq*8+3][row] = bf_hi(v.y);
            As[kq*8+4][row] = bf_lo(v.z); As[kq*8+5][row] = bf_hi(v.z);
            As[kq*8+6][row] = bf_lo(v.w); As[kq*8+7][row] = bf_hi(v.w);
        }
        #pragma unroll
        for (int i = 0; i < 2; ++i){        // B chunk 32x64
            int f = i * 256 + t;
            int kk = f >> 4, nq = f & 15;
            *(float4*)&Bs[kk][nq*4] = *(const float4*)(wv1 + (size_t)(k0 + kk) * 64 + nq * 4);
        }
        __syncthreads();
        #pragma unroll 4
        for (int k = 0; k < 32; ++k){
            float a[4], b[4];
            *(float4*)&a[0] = *(float4*)&As[k][tm*4];
            *(float4*)&b[0] = *(float4*)&Bs[k][tn*4];
            #pragma unroll
            for (int i = 0; i < 4; ++i)
                #pragma unroll
                for (int j = 0; j < 4; ++j) acc[i][j] = fmaf(a[i], b[j], acc[i][j]);
        }
        __syncthreads();
    }

    float bb[4], wv[4];
    *(float4*)&bb[0] = *(const float4*)(bv1 + tn*4);
    *(float4*)&wv[0] = *(const float4*)(wv2 + tn*4);
    float bv2v = bv2[0];
    #pragma unroll
    for (int i = 0; i < 4; ++i){
        float v = 0.f;
        #pragma unroll
        for (int j = 0; j < 4; ++j) v = fmaf(fmaxf(acc[i][j] + bb[j], 0.f), wv[j], v);
        v += __shfl_xor(v, 1); v += __shfl_xor(v, 2);
        v += __shfl_xor(v, 4); v += __shfl_xor(v, 8);
        int node = m0 + tm*4 + i;
        if (tn == 0 && node < n)
            out[1 + node] = 1.0f / (1.0f + __expf(-(v + bv2v)));
    }
}

// ----------------- path head (1 block) -----------------
__global__ __launch_bounds__(128) void path_kernel(
        const unsigned short* __restrict__ h, const float* __restrict__ g,
        const float* __restrict__ wp1, const float* __restrict__ bp1,
        const float* __restrict__ wp2, const float* __restrict__ bp2,
        const float* __restrict__ wp3, const float* __restrict__ bp3,
        float* __restrict__ out, int n)
{
    __shared__ float pc[256];
    __shared__ float p1[HC];
    __shared__ float p2[64];
    int t = threadIdx.x;              // 128
    pc[t]       = bf1(h[t]);          // h[0,:]
    pc[128 + t] = g[t] * (1.0f / (float)n);
    __syncthreads();
    float a = bp1[t];
    for (int k = 0; k < 256; ++k) a = fmaf(pc[k], wp1[k * HC + t], a);
    p1[t] = fmaxf(a, 0.f);
    __syncthreads();
    if (t < 64){
        float a2 = bp2[t];
        for (int k = 0; k < HC; ++k) a2 = fmaf(p1[k], wp2[k * 64 + t], a2);
        p2[t] = fmaxf(a2, 0.f);
    }
    __syncthreads();
    if (t == 0){
        float a3 = bp3[0];
        for (int k = 0; k < 64; ++k) a3 = fmaf(p2[k], wp3[k], a3);
        out[0] = 1.0f / (1.0f + __expf(-a3));
        out[1 + n] = 0.f;             // esc = 0
    }
}

extern "C" void kernel_launch(void* const* d_in, const int* in_sizes, int n_in,
                              void* d_out, int out_size, void* d_ws, size_t ws_size,
                              hipStream_t stream)
{
    const float* x    = (const float*)d_in[0];
    const int*   ei   = (const int*)d_in[1];
    const float* w_n1 = (const float*)d_in[3];
    const float* b_n1 = (const float*)d_in[4];
    const float* w_n2 = (const float*)d_in[5];
    const float* b_n2 = (const float*)d_in[6];
    const float* conv_w = (const float*)d_in[9];
    const float* att_s  = (const float*)d_in[10];
    const float* att_d  = (const float*)d_in[11];
    const float* conv_b = (const float*)d_in[12];
    const float* wp1 = (const float*)d_in[13];
    const float* bp1 = (const float*)d_in[14];
    const float* wp2 = (const float*)d_in[15];
    const float* bp2 = (const float*)d_in[16];
    const float* wp3 = (const float*)d_in[17];
    const float* bp3 = (const float*)d_in[18];
    const float* wv1 = (const float*)d_in[19];
    const float* bv1 = (const float*)d_in[20];
    const float* wv2 = (const float*)d_in[21];
    const float* bv2 = (const float*)d_in[22];

    const int N = in_sizes[0] / 32;
    const int E = in_sizes[1] / 2;
    float* out = (float*)d_out;

    char* ws = (char*)d_ws;
    size_t off = 0;
    auto take = [&](size_t bytes) -> char* {
        char* p = ws + off;
        off += (bytes + 255) & ~(size_t)255;
        return p;
    };
    unsigned short* hA = (unsigned short*)take((size_t)N * HC * 2);  // bf16 node features
    unsigned short* hB = (unsigned short*)take((size_t)N * HC * 2);  // bf16 hid / h'
    float* asrc  = (float*)take((size_t)N * 2 * 4);
    float* adst  = (float*)take((size_t)N * 2 * 4);
    int*   rowptr= (int*)take((size_t)(N + 1) * 4);
    int*   cnt   = (int*)take((size_t)N * 4);
    int*   rank  = (int*)take((size_t)E * 4);
    int*   colsrc= (int*)take((size_t)E * 4);
    float* g     = (float*)take(HC * 4);
    const int MB = 64;                                  // mean partial blocks
    float* mpart = (float*)take((size_t)MB * HC * 4);
    int nb = (N + 1023) / 1024;
    int*   bsum  = (int*)take((size_t)((nb + 63) & ~63) * 4);
    int*   boff  = (int*)take((size_t)((nb + 63) & ~63) * 4);

    // --- CSR build (dst-sorted; reused across the 3 layers) ---
    hipMemsetAsync(cnt, 0, (size_t)N * 4, stream);
    count_kernel<<<(E + 255) / 256, 256, 0, stream>>>(ei, cnt, rank, E);
    scan_part_kernel<<<nb, 256, 0, stream>>>(cnt, bsum, N);
    scan_top_kernel<<<1, 64, 0, stream>>>(bsum, boff, rowptr, nb, N);
    scan_fin_kernel<<<nb, 256, 0, stream>>>(cnt, boff, rowptr, N);
    scatter_kernel<<<(E + 1023) / 1024, 256, 0, stream>>>(ei, rowptr, rank, colsrc, E);

    int nblk64 = (N + 63) / 64;
    // node encoder: hid (hB bf16) = relu(x@w1+b1); hA = hid@w2 + b2 (bf16)
    enc1_kernel<<<nblk64, 256, 0, stream>>>(x, w_n1, b_n1, hB, N);
    gemm_main_kernel<false><<<nblk64, 256, 0, stream>>>(
        hB, w_n2, b_n2, nullptr, nullptr, hA, nullptr, nullptr, N);

    for (int l = 0; l < 3; ++l){
        gemm_main_kernel<true><<<nblk64, 256, 0, stream>>>(
            hA, conv_w + (size_t)l * HC * HC, nullptr,
            att_s + (size_t)l * HC, att_d + (size_t)l * HC,
            hB, asrc, adst, N);
        aggregate_kernel<<<N, 64, 0, stream>>>(
            hB, asrc, adst, rowptr, colsrc, conv_b + (size_t)l * HC, hA, N);
    }

    mean_part_kernel<<<MB, 256, 0, stream>>>(hA, mpart, N);
    mean_fin_kernel<<<1, 256, 0, stream>>>(mpart, g, MB);
    vuln_fused_kernel<<<nblk64, 256, 0, stream>>>(hA, wv1, bv1, wv2, bv2, out, N);
    path_kernel<<<1, 128, 0, stream>>>(hA, g, wp1, bp1, wp2, bp2, wp3, bp3, out, N);
}

// Round 10
// 365.997 us; speedup vs baseline: 1.3486x; 1.0177x over previous
//
#include <hip/hip_runtime.h>
#include <math.h>

#define HC 128
#define NSLOPE 0.2f

__device__ __forceinline__ float lrelu(float v){ return v > 0.f ? v : NSLOPE * v; }

// bf16 round-to-nearest-even pack / unpack
__device__ __forceinline__ unsigned short f2bf(float f){
    unsigned int b = __float_as_uint(f);
    b += 0x7FFFu + ((b >> 16) & 1u);
    return (unsigned short)(b >> 16);
}
__device__ __forceinline__ float bf_lo(unsigned int v){ return __uint_as_float(v << 16); }
__device__ __forceinline__ float bf_hi(unsigned int v){ return __uint_as_float(v & 0xFFFF0000u); }
__device__ __forceinline__ float bf1(unsigned short v){ return __uint_as_float((unsigned int)v << 16); }

// ----------------- CSR build (dst-sorted) -----------------
__global__ void count_kernel(const int* __restrict__ ei, int* __restrict__ cnt,
                             int* __restrict__ rank, int E){
    int e = blockIdx.x * blockDim.x + threadIdx.x;
    if (e < E) rank[e] = atomicAdd(&cnt[ei[E + e]], 1);
}

__global__ __launch_bounds__(256) void scan_part_kernel(
        const int* __restrict__ deg, int* __restrict__ bsum, int n)
{
    int t = threadIdx.x, lane = t & 63, wid = t >> 6;
    int base = blockIdx.x * 1024 + t * 4;
    int s = 0;
    #pragma unroll
    for (int j = 0; j < 4; ++j){ int i = base + j; if (i < n) s += deg[i]; }
    #pragma unroll
    for (int o = 1; o < 64; o <<= 1) s += __shfl_xor(s, o);
    __shared__ int red[4];
    if (lane == 0) red[wid] = s;
    __syncthreads();
    if (t == 0) bsum[blockIdx.x] = red[0] + red[1] + red[2] + red[3];
}

__global__ __launch_bounds__(64) void scan_top_kernel(
        const int* __restrict__ bsum, int* __restrict__ boff, int* __restrict__ rowptr,
        int nb, int n)
{
    int t = threadIdx.x;
    int v = (t < nb) ? bsum[t] : 0;
    int incl = v;
    #pragma unroll
    for (int o = 1; o < 64; o <<= 1){ int u = __shfl_up(incl, o); if (t >= o) incl += u; }
    if (t < nb) boff[t] = incl - v;
    if (t == 63) rowptr[n] = incl;
}

__global__ __launch_bounds__(256) void scan_fin_kernel(
        const int* __restrict__ deg, const int* __restrict__ boff,
        int* __restrict__ rowptr, int n)
{
    int t = threadIdx.x, lane = t & 63, wid = t >> 6;
    int base = blockIdx.x * 1024 + t * 4;
    int d[4]; int s = 0;
    #pragma unroll
    for (int j = 0; j < 4; ++j){ int i = base + j; d[j] = (i < n) ? deg[i] : 0; s += d[j]; }
    int incl = s;
    #pragma unroll
    for (int o = 1; o < 64; o <<= 1){ int u = __shfl_up(incl, o); if (lane >= o) incl += u; }
    __shared__ int wsum[4];
    if (lane == 63) wsum[wid] = incl;
    __syncthreads();
    int off = boff[blockIdx.x] + (incl - s);
    for (int w = 0; w < wid; ++w) off += wsum[w];
    #pragma unroll
    for (int j = 0; j < 4; ++j){
        int i = base + j;
        if (i < n) rowptr[i] = off;
        off += d[j];
    }
}

__global__ __launch_bounds__(256) void scatter_kernel(
        const int* __restrict__ ei, const int* __restrict__ rowptr,
        const int* __restrict__ rank, int* __restrict__ colsrc, int E)
{
    int b = blockIdx.x * 1024 + threadIdx.x;
    int e0 = b, e1 = b + 256, e2 = b + 512, e3 = b + 768;
    bool v0 = e0 < E, v1 = e1 < E, v2 = e2 < E, v3 = e3 < E;
    int d0=0,d1=0,d2=0,d3=0, s0=0,s1=0,s2=0,s3=0, r0=0,r1=0,r2=0,r3=0;
    if (v0){ d0 = ei[E + e0]; s0 = ei[e0]; r0 = rank[e0]; }
    if (v1){ d1 = ei[E + e1]; s1 = ei[e1]; r1 = rank[e1]; }
    if (v2){ d2 = ei[E + e2]; s2 = ei[e2]; r2 = rank[e2]; }
    if (v3){ d3 = ei[E + e3]; s3 = ei[e3]; r3 = rank[e3]; }
    if (v0) colsrc[rowptr[d0] + r0] = s0;
    if (v1) colsrc[rowptr[d1] + r1] = s1;
    if (v2) colsrc[rowptr[d2] + r2] = s2;
    if (v3) colsrc[rowptr[d3] + r3] = s3;
}

// ----------------- node encoder stage 1: hid(bf16) = relu(x@w1+b1), K=32 -----------------
__global__ __launch_bounds__(256) void enc1_kernel(
        const float* __restrict__ x, const float* __restrict__ w1, const float* __restrict__ b1,
        unsigned short* __restrict__ hid, int n)
{
    __shared__ float As[32][68];
    __shared__ float Bs[32][128];
    int t = threadIdx.x;
    int m0 = blockIdx.x * 64;
    int tm = t >> 4, tn = t & 15;

    #pragma unroll
    for (int i = 0; i < 2; ++i){       // A: 64 rows x 32 k (f32 input)
        int f = i * 256 + t;
        int row = f >> 3, kq = f & 7;
        int gr = m0 + row; if (gr > n - 1) gr = n - 1;
        float4 v = *(const float4*)(x + (size_t)gr * 32 + kq * 4);
        As[kq*4+0][row] = v.x; As[kq*4+1][row] = v.y; As[kq*4+2][row] = v.z; As[kq*4+3][row] = v.w;
    }
    #pragma unroll
    for (int i = 0; i < 4; ++i){       // B: 32x128
        int f = i * 256 + t;
        int kk = f >> 5, nq = f & 31;
        *(float4*)&Bs[kk][nq*4] = *(const float4*)(w1 + (size_t)kk * 128 + nq * 4);
    }
    __syncthreads();

    float acc[4][8];
    #pragma unroll
    for (int i = 0; i < 4; ++i)
        #pragma unroll
        for (int j = 0; j < 8; ++j) acc[i][j] = 0.f;

    #pragma unroll 4
    for (int k = 0; k < 32; ++k){
        float a[4], b[8];
        *(float4*)&a[0] = *(float4*)&As[k][tm*4];
        *(float4*)&b[0] = *(float4*)&Bs[k][tn*8];
        *(float4*)&b[4] = *(float4*)&Bs[k][tn*8+4];
        #pragma unroll
        for (int i = 0; i < 4; ++i)
            #pragma unroll
            for (int j = 0; j < 8; ++j) acc[i][j] = fmaf(a[i], b[j], acc[i][j]);
    }

    float bb[8];
    *(float4*)&bb[0] = *(const float4*)(b1 + tn*8);
    *(float4*)&bb[4] = *(const float4*)(b1 + tn*8 + 4);
    #pragma unroll
    for (int i = 0; i < 4; ++i){
        int node = m0 + tm*4 + i;
        if (node < n){
            float o[8];
            #pragma unroll
            for (int j = 0; j < 8; ++j) o[j] = fmaxf(acc[i][j] + bb[j], 0.f);
            uint4 pk;
            pk.x = (unsigned int)f2bf(o[0]) | ((unsigned int)f2bf(o[1]) << 16);
            pk.y = (unsigned int)f2bf(o[2]) | ((unsigned int)f2bf(o[3]) << 16);
            pk.z = (unsigned int)f2bf(o[4]) | ((unsigned int)f2bf(o[5]) << 16);
            pk.w = (unsigned int)f2bf(o[6]) | ((unsigned int)f2bf(o[7]) << 16);
            *(uint4*)(hid + (size_t)node*HC + tn*8) = pk;
        }
    }
}

// ----------------- main GEMM, 64x64 tiles: C(bf16) = A(bf16)@W (+bias) -----------------
// grid = mblks*2; even/odd block = col half. Conflict-free A staging (kq = wave id).
__global__ __launch_bounds__(256) void gemm_main_kernel(
        const unsigned short* __restrict__ A, const float* __restrict__ W,
        const float* __restrict__ bias, unsigned short* __restrict__ Cb, int n)
{
    __shared__ float As[32][68];
    __shared__ float Bs[32][68];
    int t = threadIdx.x;
    int m0 = (blockIdx.x >> 1) * 64;
    int c0 = (blockIdx.x & 1) * 64;
    int tm = t >> 4, tn = t & 15;
    int kq = t >> 6, arow = t & 63;     // staging roles: wave-uniform k-group

    float acc[4][4];
    #pragma unroll
    for (int i = 0; i < 4; ++i)
        #pragma unroll
        for (int j = 0; j < 4; ++j) acc[i][j] = 0.f;

    for (int kc = 0; kc < 4; ++kc){
        int k0 = kc * 32;
        {   // A chunk 64x32 bf16: lane reads 8 bf16 (16B); writes hit 64 distinct rows -> conflict-free
            int gr = m0 + arow; if (gr > n - 1) gr = n - 1;
            uint4 v = *(const uint4*)(A + (size_t)gr * HC + k0 + kq * 8);
            As[kq*8+0][arow] = bf_lo(v.x); As[kq*8+1][arow] = bf_hi(v.x);
            As[kq*8+2][arow] = bf_lo(v.y); As[kq*8+3][arow] = bf_hi(v.y);
            As[kq*8+4][arow] = bf_lo(v.z); As[kq*8+5][arow] = bf_hi(v.z);
            As[kq*8+6][arow] = bf_lo(v.w); As[kq*8+7][arow] = bf_hi(v.w);
        }
        #pragma unroll
        for (int i = 0; i < 2; ++i){    // B chunk 32x64 f32
            int f = i * 256 + t;
            int kk = f >> 4, nq = f & 15;
            *(float4*)&Bs[kk][nq*4] = *(const float4*)(W + (size_t)(k0 + kk) * 128 + c0 + nq * 4);
        }
        __syncthreads();
        #pragma unroll 4
        for (int k = 0; k < 32; ++k){
            float a[4], b[4];
            *(float4*)&a[0] = *(float4*)&As[k][tm*4];
            *(float4*)&b[0] = *(float4*)&Bs[k][tn*4];
            #pragma unroll
            for (int i = 0; i < 4; ++i)
                #pragma unroll
                for (int j = 0; j < 4; ++j) acc[i][j] = fmaf(a[i], b[j], acc[i][j]);
        }
        __syncthreads();
    }

    float bb[4];
    if (bias){
        *(float4*)&bb[0] = *(const float4*)(bias + c0 + tn*4);
    } else {
        #pragma unroll
        for (int j = 0; j < 4; ++j) bb[j] = 0.f;
    }
    #pragma unroll
    for (int i = 0; i < 4; ++i){
        int node = m0 + tm*4 + i;
        if (node < n){
            float o[4];
            #pragma unroll
            for (int j = 0; j < 4; ++j) o[j] = acc[i][j] + bb[j];
            uint2 pk;
            pk.x = (unsigned int)f2bf(o[0]) | ((unsigned int)f2bf(o[1]) << 16);
            pk.y = (unsigned int)f2bf(o[2]) | ((unsigned int)f2bf(o[3]) << 16);
            *(uint2*)(Cb + (size_t)node*HC + c0 + tn*4) = pk;
        }
    }
}

// ----------------- att dots from bf16 h1: asrc/adst[node][head] -----------------
// 8 lanes per node; head0 = cols 0..63 (lanes 0..3), head1 = cols 64..127 (lanes 4..7)
__global__ __launch_bounds__(256) void att_kernel(
        const unsigned short* __restrict__ h1, const float* __restrict__ att_s,
        const float* __restrict__ att_d, float* __restrict__ asrc, float* __restrict__ adst, int n)
{
    int t = threadIdx.x;
    int node = blockIdx.x * 32 + (t >> 3);
    int l8 = t & 7;
    if (node >= n) return;
    uint4 v0 = *(const uint4*)(h1 + (size_t)node * HC + l8 * 16);
    uint4 v1 = *(const uint4*)(h1 + (size_t)node * HC + l8 * 16 + 8);
    float sa = 0.f, sd = 0.f;
    unsigned int w[8] = {v0.x, v0.y, v0.z, v0.w, v1.x, v1.y, v1.z, v1.w};
    #pragma unroll
    for (int q = 0; q < 8; ++q){
        float lo = bf_lo(w[q]), hi = bf_hi(w[q]);
        int c = l8 * 16 + q * 2;
        sa = fmaf(lo, att_s[c], sa);     sa = fmaf(hi, att_s[c + 1], sa);
        sd = fmaf(lo, att_d[c], sd);     sd = fmaf(hi, att_d[c + 1], sd);
    }
    sa += __shfl_xor(sa, 1); sa += __shfl_xor(sa, 2);   // reduce within 4-lane quad (one head)
    sd += __shfl_xor(sd, 1); sd += __shfl_xor(sd, 2);
    if ((l8 & 3) == 0){
        int head = l8 >> 2;
        asrc[(size_t)node * 2 + head] = sa;
        adst[(size_t)node * 2 + head] = sd;
    }
}

// ----------------- aggregation: 1 wave/node; LDS coef table; 4-deep gather pipeline -----------------
__global__ __launch_bounds__(64) void aggregate_kernel(
        const unsigned short* __restrict__ h1b, const float* __restrict__ asrc, const float* __restrict__ adst,
        const int* __restrict__ rowptr, const int* __restrict__ colsrc,
        const float* __restrict__ bias, unsigned short* __restrict__ hout, int n)
{
    __shared__ float4 exl[64];
    int i = blockIdx.x;
    if (i >= n) return;
    int t = threadIdx.x;
    int head = t >> 5;
    float2 adv = *(const float2*)(adst + (size_t)i * 2);
    float2 asv = *(const float2*)(asrc + (size_t)i * 2);
    float ads = head ? adv.y : adv.x;
    float exs = __expf(lrelu((head ? asv.y : asv.x) + ads));   // self loop
    unsigned int hv = ((const unsigned int*)(h1b + (size_t)i * HC))[t];
    float acc0 = exs * bf_lo(hv), acc1 = exs * bf_hi(hv), D = exs;

    int e  = rowptr[i];
    int e1 = rowptr[i + 1];
    while (e < e1){
        int m = e1 - e; if (m > 64) m = 64;
        if (t < m){
            int s = colsrc[e + t];
            float2 as = *(const float2*)(asrc + (size_t)s * 2);
            exl[t] = make_float4(__int_as_float(s),
                                 __expf(lrelu(as.x + adv.x)),
                                 __expf(lrelu(as.y + adv.y)), 0.f);
        }
        __syncthreads();
        int j = 0;
        for (; j + 4 <= m; j += 4){
            float4 q0 = exl[j], q1 = exl[j+1], q2 = exl[j+2], q3 = exl[j+3];
            const unsigned int* p0 = (const unsigned int*)(h1b + (size_t)__float_as_int(q0.x) * HC);
            const unsigned int* p1 = (const unsigned int*)(h1b + (size_t)__float_as_int(q1.x) * HC);
            const unsigned int* p2 = (const unsigned int*)(h1b + (size_t)__float_as_int(q2.x) * HC);
            const unsigned int* p3 = (const unsigned int*)(h1b + (size_t)__float_as_int(q3.x) * HC);
            unsigned int v0 = p0[t], v1 = p1[t], v2 = p2[t], v3 = p3[t];
            float c0 = head ? q0.z : q0.y;
            float c1 = head ? q1.z : q1.y;
            float c2 = head ? q2.z : q2.y;
            float c3 = head ? q3.z : q3.y;
            acc0 = fmaf(c0, bf_lo(v0), acc0);  acc1 = fmaf(c0, bf_hi(v0), acc1);
            acc0 = fmaf(c1, bf_lo(v1), acc0);  acc1 = fmaf(c1, bf_hi(v1), acc1);
            acc0 = fmaf(c2, bf_lo(v2), acc0);  acc1 = fmaf(c2, bf_hi(v2), acc1);
            acc0 = fmaf(c3, bf_lo(v3), acc0);  acc1 = fmaf(c3, bf_hi(v3), acc1);
            D += (c0 + c1) + (c2 + c3);
        }
        for (; j < m; ++j){
            float4 q = exl[j];
            unsigned int v = ((const unsigned int*)(h1b + (size_t)__float_as_int(q.x) * HC))[t];
            float c = head ? q.z : q.y;
            acc0 = fmaf(c, bf_lo(v), acc0);
            acc1 = fmaf(c, bf_hi(v), acc1);
            D += c;
        }
        __syncthreads();
        e += m;
    }
    float rD = 1.0f / D;
    float o0 = fmaxf(acc0 * rD + bias[2*t],     0.f);
    float o1 = fmaxf(acc1 * rD + bias[2*t + 1], 0.f);
    ((unsigned int*)hout)[(size_t)i * 64 + t] =
        (unsigned int)f2bf(o0) | ((unsigned int)f2bf(o1) << 16);
}

// ----------------- graph mean: two-stage, bf16 input, NO global atomics -----------------
__global__ __launch_bounds__(256) void mean_part_kernel(
        const unsigned short* __restrict__ h, float* __restrict__ partial, int n)
{
    int t = threadIdx.x;
    int cq = t & 31;
    int rl = t >> 5;
    float4 acc = make_float4(0.f, 0.f, 0.f, 0.f);
    for (int i = blockIdx.x * 8 + rl; i < n; i += gridDim.x * 8){
        uint2 v = *(const uint2*)(h + (size_t)i * HC + cq * 4);
        acc.x += bf_lo(v.x); acc.y += bf_hi(v.x);
        acc.z += bf_lo(v.y); acc.w += bf_hi(v.y);
    }
    __shared__ float4 red[256];
    red[t] = acc;
    __syncthreads();
    if (t < 128){
        float4 o = red[t + 128];
        red[t].x += o.x; red[t].y += o.y; red[t].z += o.z; red[t].w += o.w;
    }
    __syncthreads();
    if (t < 64){
        float4 o = red[t + 64];
        red[t].x += o.x; red[t].y += o.y; red[t].z += o.z; red[t].w += o.w;
    }
    __syncthreads();
    if (t < 32){
        float4 a = red[t], b = red[t + 32];
        float4 s = make_float4(a.x + b.x, a.y + b.y, a.z + b.z, a.w + b.w);
        *(float4*)(partial + (size_t)blockIdx.x * HC + t * 4) = s;
    }
}

__global__ __launch_bounds__(256) void mean_fin_kernel(
        const float* __restrict__ partial, float* __restrict__ g, int nb)
{
    int t = threadIdx.x;
    int cq = t & 31, b0 = t >> 5;
    float4 acc = make_float4(0.f, 0.f, 0.f, 0.f);
    for (int b = b0; b < nb; b += 8){
        float4 v = *(const float4*)(partial + (size_t)b * HC + cq * 4);
        acc.x += v.x; acc.y += v.y; acc.z += v.z; acc.w += v.w;
    }
    __shared__ float4 red[256];
    red[t] = acc;
    __syncthreads();
    if (t < 128){
        float4 o = red[t + 128];
        red[t].x += o.x; red[t].y += o.y; red[t].z += o.z; red[t].w += o.w;
    }
    __syncthreads();
    if (t < 64){
        float4 o = red[t + 64];
        red[t].x += o.x; red[t].y += o.y; red[t].z += o.z; red[t].w += o.w;
    }
    __syncthreads();
    if (t < 32){
        float4 a = red[t], b = red[t + 32];
        float4 s = make_float4(a.x + b.x, a.y + b.y, a.z + b.z, a.w + b.w);
        *(float4*)(g + t * 4) = s;
    }
}

// ----------------- vuln head (bf16 input): sigmoid(relu(h@wv1+bv1)@wv2+bv2) -----------------
__global__ __launch_bounds__(256) void vuln_fused_kernel(
        const unsigned short* __restrict__ h, const float* __restrict__ wv1, const float* __restrict__ bv1,
        const float* __restrict__ wv2, const float* __restrict__ bv2,
        float* __restrict__ out, int n)
{
    __shared__ float As[32][68];
    __shared__ float Bs[32][64];
    int t = threadIdx.x;
    int m0 = blockIdx.x * 64;
    int tm = t >> 4, tn = t & 15;
    int kq = t >> 6, arow = t & 63;

    float acc[4][4];
    #pragma unroll
    for (int i = 0; i < 4; ++i)
        #pragma unroll
        for (int j = 0; j < 4; ++j) acc[i][j] = 0.f;

    for (int kc = 0; kc < 4; ++kc){
        int k0 = kc * 32;
        {
            int gr = m0 + arow; if (gr > n - 1) gr = n - 1;
            uint4 v = *(const uint4*)(h + (size_t)gr * HC + k0 + kq * 8);
            As[kq*8+0][arow] = bf_lo(v.x); As[kq*8+1][arow] = bf_hi(v.x);
            As[kq*8+2][arow] = bf_lo(v.y); As[kq*8+3][arow] = bf_hi(v.y);
            As[kq*8+4][arow] = bf_lo(v.z); As[kq*8+5][arow] = bf_hi(v.z);
            As[kq*8+6][arow] = bf_lo(v.w); As[kq*8+7][arow] = bf_hi(v.w);
        }
        #pragma unroll
        for (int i = 0; i < 2; ++i){        // B chunk 32x64
            int f = i * 256 + t;
            int kk = f >> 4, nq = f & 15;
            *(float4*)&Bs[kk][nq*4] = *(const float4*)(wv1 + (size_t)(k0 + kk) * 64 + nq * 4);
        }
        __syncthreads();
        #pragma unroll 4
        for (int k = 0; k < 32; ++k){
            float a[4], b[4];
            *(float4*)&a[0] = *(float4*)&As[k][tm*4];
            *(float4*)&b[0] = *(float4*)&Bs[k][tn*4];
            #pragma unroll
            for (int i = 0; i < 4; ++i)
                #pragma unroll
                for (int j = 0; j < 4; ++j) acc[i][j] = fmaf(a[i], b[j], acc[i][j]);
        }
        __syncthreads();
    }

    float bb[4], wv[4];
    *(float4*)&bb[0] = *(const float4*)(bv1 + tn*4);
    *(float4*)&wv[0] = *(const float4*)(wv2 + tn*4);
    float bv2v = bv2[0];
    #pragma unroll
    for (int i = 0; i < 4; ++i){
        float v = 0.f;
        #pragma unroll
        for (int j = 0; j < 4; ++j) v = fmaf(fmaxf(acc[i][j] + bb[j], 0.f), wv[j], v);
        v += __shfl_xor(v, 1); v += __shfl_xor(v, 2);
        v += __shfl_xor(v, 4); v += __shfl_xor(v, 8);
        int node = m0 + tm*4 + i;
        if (tn == 0 && node < n)
            out[1 + node] = 1.0f / (1.0f + __expf(-(v + bv2v)));
    }
}

// ----------------- path head (1 block) -----------------
__global__ __launch_bounds__(128) void path_kernel(
        const unsigned short* __restrict__ h, const float* __restrict__ g,
        const float* __restrict__ wp1, const float* __restrict__ bp1,
        const float* __restrict__ wp2, const float* __restrict__ bp2,
        const float* __restrict__ wp3, const float* __restrict__ bp3,
        float* __restrict__ out, int n)
{
    __shared__ float pc[256];
    __shared__ float p1[HC];
    __shared__ float p2[64];
    int t = threadIdx.x;              // 128
    pc[t]       = bf1(h[t]);          // h[0,:]
    pc[128 + t] = g[t] * (1.0f / (float)n);
    __syncthreads();
    float a = bp1[t];
    for (int k = 0; k < 256; ++k) a = fmaf(pc[k], wp1[k * HC + t], a);
    p1[t] = fmaxf(a, 0.f);
    __syncthreads();
    if (t < 64){
        float a2 = bp2[t];
        for (int k = 0; k < HC; ++k) a2 = fmaf(p1[k], wp2[k * 64 + t], a2);
        p2[t] = fmaxf(a2, 0.f);
    }
    __syncthreads();
    if (t == 0){
        float a3 = bp3[0];
        for (int k = 0; k < 64; ++k) a3 = fmaf(p2[k], wp3[k], a3);
        out[0] = 1.0f / (1.0f + __expf(-a3));
        out[1 + n] = 0.f;             // esc = 0
    }
}

extern "C" void kernel_launch(void* const* d_in, const int* in_sizes, int n_in,
                              void* d_out, int out_size, void* d_ws, size_t ws_size,
                              hipStream_t stream)
{
    const float* x    = (const float*)d_in[0];
    const int*   ei   = (const int*)d_in[1];
    const float* w_n1 = (const float*)d_in[3];
    const float* b_n1 = (const float*)d_in[4];
    const float* w_n2 = (const float*)d_in[5];
    const float* b_n2 = (const float*)d_in[6];
    const float* conv_w = (const float*)d_in[9];
    const float* att_s  = (const float*)d_in[10];
    const float* att_d  = (const float*)d_in[11];
    const float* conv_b = (const float*)d_in[12];
    const float* wp1 = (const float*)d_in[13];
    const float* bp1 = (const float*)d_in[14];
    const float* wp2 = (const float*)d_in[15];
    const float* bp2 = (const float*)d_in[16];
    const float* wp3 = (const float*)d_in[17];
    const float* bp3 = (const float*)d_in[18];
    const float* wv1 = (const float*)d_in[19];
    const float* bv1 = (const float*)d_in[20];
    const float* wv2 = (const float*)d_in[21];
    const float* bv2 = (const float*)d_in[22];

    const int N = in_sizes[0] / 32;
    const int E = in_sizes[1] / 2;
    float* out = (float*)d_out;

    char* ws = (char*)d_ws;
    size_t off = 0;
    auto take = [&](size_t bytes) -> char* {
        char* p = ws + off;
        off += (bytes + 255) & ~(size_t)255;
        return p;
    };
    unsigned short* hA = (unsigned short*)take((size_t)N * HC * 2);  // bf16 node features
    unsigned short* hB = (unsigned short*)take((size_t)N * HC * 2);  // bf16 hid / h'
    float* asrc  = (float*)take((size_t)N * 2 * 4);
    float* adst  = (float*)take((size_t)N * 2 * 4);
    int*   rowptr= (int*)take((size_t)(N + 1) * 4);
    int*   cnt   = (int*)take((size_t)N * 4);
    int*   rank  = (int*)take((size_t)E * 4);
    int*   colsrc= (int*)take((size_t)E * 4);
    float* g     = (float*)take(HC * 4);
    const int MB = 64;                                  // mean partial blocks
    float* mpart = (float*)take((size_t)MB * HC * 4);
    int nb = (N + 1023) / 1024;
    int*   bsum  = (int*)take((size_t)((nb + 63) & ~63) * 4);
    int*   boff  = (int*)take((size_t)((nb + 63) & ~63) * 4);

    // --- CSR build (dst-sorted; reused across the 3 layers) ---
    hipMemsetAsync(cnt, 0, (size_t)N * 4, stream);
    count_kernel<<<(E + 255) / 256, 256, 0, stream>>>(ei, cnt, rank, E);
    scan_part_kernel<<<nb, 256, 0, stream>>>(cnt, bsum, N);
    scan_top_kernel<<<1, 64, 0, stream>>>(bsum, boff, rowptr, nb, N);
    scan_fin_kernel<<<nb, 256, 0, stream>>>(cnt, boff, rowptr, N);
    scatter_kernel<<<(E + 1023) / 1024, 256, 0, stream>>>(ei, rowptr, rank, colsrc, E);

    int nblk64 = (N + 63) / 64;
    int gemm_grid = nblk64 * 2;
    // node encoder: hid (hB bf16) = relu(x@w1+b1); hA = hid@w2 + b2 (bf16)
    enc1_kernel<<<nblk64, 256, 0, stream>>>(x, w_n1, b_n1, hB, N);
    gemm_main_kernel<<<gemm_grid, 256, 0, stream>>>(hB, w_n2, b_n2, hA, N);

    for (int l = 0; l < 3; ++l){
        gemm_main_kernel<<<gemm_grid, 256, 0, stream>>>(
            hA, conv_w + (size_t)l * HC * HC, nullptr, hB, N);
        att_kernel<<<(N + 31) / 32, 256, 0, stream>>>(
            hB, att_s + (size_t)l * HC, att_d + (size_t)l * HC, asrc, adst, N);
        aggregate_kernel<<<N, 64, 0, stream>>>(
            hB, asrc, adst, rowptr, colsrc, conv_b + (size_t)l * HC, hA, N);
    }

    mean_part_kernel<<<MB, 256, 0, stream>>>(hA, mpart, N);
    mean_fin_kernel<<<1, 256, 0, stream>>>(mpart, g, MB);
    vuln_fused_kernel<<<nblk64, 256, 0, stream>>>(hA, wv1, bv1, wv2, bv2, out, N);
    path_kernel<<<1, 128, 0, stream>>>(hA, g, wp1, bp1, wp2, bp2, wp3, bp3, out, N);
}

// Round 11
// 336.791 us; speedup vs baseline: 1.4655x; 1.0867x over previous
//
#include <hip/hip_runtime.h>
#include <math.h>

#define HC 128
#define NSLOPE 0.2f

using bf16x8 = __attribute__((ext_vector_type(8))) short;
using f32x4  = __attribute__((ext_vector_type(4))) float;

__device__ __forceinline__ float lrelu(float v){ return v > 0.f ? v : NSLOPE * v; }

// bf16 round-to-nearest-even pack / unpack
__device__ __forceinline__ unsigned short f2bf(float f){
    unsigned int b = __float_as_uint(f);
    b += 0x7FFFu + ((b >> 16) & 1u);
    return (unsigned short)(b >> 16);
}
__device__ __forceinline__ float bf_lo(unsigned int v){ return __uint_as_float(v << 16); }
__device__ __forceinline__ float bf_hi(unsigned int v){ return __uint_as_float(v & 0xFFFF0000u); }
__device__ __forceinline__ float bf1(unsigned short v){ return __uint_as_float((unsigned int)v << 16); }

// ----------------- CSR build (dst-sorted) -----------------
__global__ void count_kernel(const int* __restrict__ ei, int* __restrict__ cnt,
                             int* __restrict__ rank, int E){
    int e = blockIdx.x * blockDim.x + threadIdx.x;
    if (e < E) rank[e] = atomicAdd(&cnt[ei[E + e]], 1);
}

__global__ __launch_bounds__(256) void scan_part_kernel(
        const int* __restrict__ deg, int* __restrict__ bsum, int n)
{
    int t = threadIdx.x, lane = t & 63, wid = t >> 6;
    int base = blockIdx.x * 1024 + t * 4;
    int s = 0;
    #pragma unroll
    for (int j = 0; j < 4; ++j){ int i = base + j; if (i < n) s += deg[i]; }
    #pragma unroll
    for (int o = 1; o < 64; o <<= 1) s += __shfl_xor(s, o);
    __shared__ int red[4];
    if (lane == 0) red[wid] = s;
    __syncthreads();
    if (t == 0) bsum[blockIdx.x] = red[0] + red[1] + red[2] + red[3];
}

__global__ __launch_bounds__(64) void scan_top_kernel(
        const int* __restrict__ bsum, int* __restrict__ boff, int* __restrict__ rowptr,
        int nb, int n)
{
    int t = threadIdx.x;
    int v = (t < nb) ? bsum[t] : 0;
    int incl = v;
    #pragma unroll
    for (int o = 1; o < 64; o <<= 1){ int u = __shfl_up(incl, o); if (t >= o) incl += u; }
    if (t < nb) boff[t] = incl - v;
    if (t == 63) rowptr[n] = incl;
}

__global__ __launch_bounds__(256) void scan_fin_kernel(
        const int* __restrict__ deg, const int* __restrict__ boff,
        int* __restrict__ rowptr, int n)
{
    int t = threadIdx.x, lane = t & 63, wid = t >> 6;
    int base = blockIdx.x * 1024 + t * 4;
    int d[4]; int s = 0;
    #pragma unroll
    for (int j = 0; j < 4; ++j){ int i = base + j; d[j] = (i < n) ? deg[i] : 0; s += d[j]; }
    int incl = s;
    #pragma unroll
    for (int o = 1; o < 64; o <<= 1){ int u = __shfl_up(incl, o); if (lane >= o) incl += u; }
    __shared__ int wsum[4];
    if (lane == 63) wsum[wid] = incl;
    __syncthreads();
    int off = boff[blockIdx.x] + (incl - s);
    for (int w = 0; w < wid; ++w) off += wsum[w];
    #pragma unroll
    for (int j = 0; j < 4; ++j){
        int i = base + j;
        if (i < n) rowptr[i] = off;
        off += d[j];
    }
}

__global__ __launch_bounds__(256) void scatter_kernel(
        const int* __restrict__ ei, const int* __restrict__ rowptr,
        const int* __restrict__ rank, int* __restrict__ colsrc, int E)
{
    int b = blockIdx.x * 1024 + threadIdx.x;
    int e0 = b, e1 = b + 256, e2 = b + 512, e3 = b + 768;
    bool v0 = e0 < E, v1 = e1 < E, v2 = e2 < E, v3 = e3 < E;
    int d0=0,d1=0,d2=0,d3=0, s0=0,s1=0,s2=0,s3=0, r0=0,r1=0,r2=0,r3=0;
    if (v0){ d0 = ei[E + e0]; s0 = ei[e0]; r0 = rank[e0]; }
    if (v1){ d1 = ei[E + e1]; s1 = ei[e1]; r1 = rank[e1]; }
    if (v2){ d2 = ei[E + e2]; s2 = ei[e2]; r2 = rank[e2]; }
    if (v3){ d3 = ei[E + e3]; s3 = ei[e3]; r3 = rank[e3]; }
    if (v0) colsrc[rowptr[d0] + r0] = s0;
    if (v1) colsrc[rowptr[d1] + r1] = s1;
    if (v2) colsrc[rowptr[d2] + r2] = s2;
    if (v3) colsrc[rowptr[d3] + r3] = s3;
}

// ----------------- weight transpose->bf16: Wt[c][k] = W[k][c] -----------------
__global__ __launch_bounds__(256) void wtrans_kernel(
        const float* __restrict__ W, unsigned short* __restrict__ Wt, int nmat)
{
    int idx = blockIdx.x * 256 + threadIdx.x;      // mat*2048 + c*16 + kg
    if (idx >= nmat * 2048) return;
    int mat = idx >> 11;
    int rem = idx & 2047;
    int c = rem >> 4, kg = rem & 15;
    const float* Wm = W + (size_t)mat * 16384;
    unsigned short* Wo = Wt + (size_t)mat * 16384;
    unsigned int pk[4];
    #pragma unroll
    for (int j = 0; j < 4; ++j){
        float a = Wm[(size_t)(kg*8 + j*2    ) * 128 + c];
        float b = Wm[(size_t)(kg*8 + j*2 + 1) * 128 + c];
        pk[j] = (unsigned int)f2bf(a) | ((unsigned int)f2bf(b) << 16);
    }
    *(uint4*)(Wo + (size_t)c * 128 + kg * 8) = make_uint4(pk[0], pk[1], pk[2], pk[3]);
}

// ----------------- node encoder stage 1: hid(bf16) = relu(x@w1+b1), K=32 -----------------
__global__ __launch_bounds__(256) void enc1_kernel(
        const float* __restrict__ x, const float* __restrict__ w1, const float* __restrict__ b1,
        unsigned short* __restrict__ hid, int n)
{
    __shared__ float As[32][68];
    __shared__ float Bs[32][128];
    int t = threadIdx.x;
    int m0 = blockIdx.x * 64;
    int tm = t >> 4, tn = t & 15;

    #pragma unroll
    for (int i = 0; i < 2; ++i){
        int f = i * 256 + t;
        int row = f >> 3, kq = f & 7;
        int gr = m0 + row; if (gr > n - 1) gr = n - 1;
        float4 v = *(const float4*)(x + (size_t)gr * 32 + kq * 4);
        As[kq*4+0][row] = v.x; As[kq*4+1][row] = v.y; As[kq*4+2][row] = v.z; As[kq*4+3][row] = v.w;
    }
    #pragma unroll
    for (int i = 0; i < 4; ++i){
        int f = i * 256 + t;
        int kk = f >> 5, nq = f & 31;
        *(float4*)&Bs[kk][nq*4] = *(const float4*)(w1 + (size_t)kk * 128 + nq * 4);
    }
    __syncthreads();

    float acc[4][8];
    #pragma unroll
    for (int i = 0; i < 4; ++i)
        #pragma unroll
        for (int j = 0; j < 8; ++j) acc[i][j] = 0.f;

    #pragma unroll 4
    for (int k = 0; k < 32; ++k){
        float a[4], b[8];
        *(float4*)&a[0] = *(float4*)&As[k][tm*4];
        *(float4*)&b[0] = *(float4*)&Bs[k][tn*8];
        *(float4*)&b[4] = *(float4*)&Bs[k][tn*8+4];
        #pragma unroll
        for (int i = 0; i < 4; ++i)
            #pragma unroll
            for (int j = 0; j < 8; ++j) acc[i][j] = fmaf(a[i], b[j], acc[i][j]);
    }

    float bb[8];
    *(float4*)&bb[0] = *(const float4*)(b1 + tn*8);
    *(float4*)&bb[4] = *(const float4*)(b1 + tn*8 + 4);
    #pragma unroll
    for (int i = 0; i < 4; ++i){
        int node = m0 + tm*4 + i;
        if (node < n){
            float o[8];
            #pragma unroll
            for (int j = 0; j < 8; ++j) o[j] = fmaxf(acc[i][j] + bb[j], 0.f);
            uint4 pk;
            pk.x = (unsigned int)f2bf(o[0]) | ((unsigned int)f2bf(o[1]) << 16);
            pk.y = (unsigned int)f2bf(o[2]) | ((unsigned int)f2bf(o[3]) << 16);
            pk.z = (unsigned int)f2bf(o[4]) | ((unsigned int)f2bf(o[5]) << 16);
            pk.w = (unsigned int)f2bf(o[6]) | ((unsigned int)f2bf(o[7]) << 16);
            *(uint4*)(hid + (size_t)node*HC + tn*8) = pk;
        }
    }
}

// ----------------- MFMA GEMM: C(bf16)[n][128] = A(bf16)[n][128] @ W + bias -----------------
// 4 waves/block, wave w owns rows m0+w*16..+15, all 128 cols (8 col-tiles), K = 4x32.
// A frag: lane row=l&15, k=(l>>4)*8+j (one bf16x8 global load).
// B frag from Wt[c][k]: lane col=l&15, k=(l>>4)*8+j. C/D: col=l&15, row=(l>>4)*4+reg.
template<bool ATT>
__global__ __launch_bounds__(256) void gemm_mfma_kernel(
        const unsigned short* __restrict__ A, const unsigned short* __restrict__ Wt,
        const float* __restrict__ bias,
        const float* __restrict__ att_s, const float* __restrict__ att_d,
        unsigned short* __restrict__ Cb,
        float* __restrict__ asrc, float* __restrict__ adst, int n)
{
    __shared__ float lds[4][16][132];
    int t = threadIdx.x;
    int w = t >> 6, l = t & 63;
    int lane15 = l & 15, lanehi = l >> 4;
    int m0 = blockIdx.x * 64 + w * 16;

    f32x4 acc[8];
    #pragma unroll
    for (int ct = 0; ct < 8; ++ct) acc[ct] = (f32x4){0.f, 0.f, 0.f, 0.f};

    int ar = m0 + lane15; if (ar > n - 1) ar = n - 1;
    const unsigned short* Arow = A + (size_t)ar * HC;

    #pragma unroll
    for (int kc = 0; kc < 4; ++kc){
        bf16x8 af = *reinterpret_cast<const bf16x8*>(Arow + kc * 32 + lanehi * 8);
        #pragma unroll
        for (int ct = 0; ct < 8; ++ct){
            bf16x8 bf = *reinterpret_cast<const bf16x8*>(
                Wt + (size_t)(ct * 16 + lane15) * HC + kc * 32 + lanehi * 8);
            acc[ct] = __builtin_amdgcn_mfma_f32_16x16x32_bf16(af, bf, acc[ct], 0, 0, 0);
        }
    }

    // fused att dots (per row, per head) via 16-lane xor reduce
    if (ATT){
        float ats[8], atd[8];
        #pragma unroll
        for (int ct = 0; ct < 8; ++ct){
            ats[ct] = att_s[ct * 16 + lane15];
            atd[ct] = att_d[ct * 16 + lane15];
        }
        #pragma unroll
        for (int r = 0; r < 4; ++r){
            float sa0 = 0.f, sd0 = 0.f, sa1 = 0.f, sd1 = 0.f;
            #pragma unroll
            for (int ct = 0; ct < 4; ++ct){
                sa0 = fmaf(acc[ct][r], ats[ct], sa0);
                sd0 = fmaf(acc[ct][r], atd[ct], sd0);
            }
            #pragma unroll
            for (int ct = 4; ct < 8; ++ct){
                sa1 = fmaf(acc[ct][r], ats[ct], sa1);
                sd1 = fmaf(acc[ct][r], atd[ct], sd1);
            }
            #pragma unroll
            for (int o = 1; o < 16; o <<= 1){
                sa0 += __shfl_xor(sa0, o); sd0 += __shfl_xor(sd0, o);
                sa1 += __shfl_xor(sa1, o); sd1 += __shfl_xor(sd1, o);
            }
            int node = m0 + lanehi * 4 + r;
            if (lane15 == 0 && node < n){
                asrc[(size_t)node * 2]     = sa0;
                adst[(size_t)node * 2]     = sd0;
                asrc[(size_t)node * 2 + 1] = sa1;
                adst[(size_t)node * 2 + 1] = sd1;
            }
        }
    }

    // stage acc (+bias) to LDS, then pack rows to bf16
    float bb[8];
    #pragma unroll
    for (int ct = 0; ct < 8; ++ct) bb[ct] = ATT ? 0.f : bias[ct * 16 + lane15];
    #pragma unroll
    for (int ct = 0; ct < 8; ++ct)
        #pragma unroll
        for (int r = 0; r < 4; ++r)
            lds[w][lanehi * 4 + r][ct * 16 + lane15] = acc[ct][r] + bb[ct];
    __syncthreads();

    int row = lane15, cb = lanehi;         // this lane packs cols cb*32..+31 of its row
    int node = m0 + row;
    if (node < n){
        #pragma unroll
        for (int q = 0; q < 4; ++q){
            float o[8];
            *(float4*)&o[0] = *(float4*)&lds[w][row][cb * 32 + q * 8];
            *(float4*)&o[4] = *(float4*)&lds[w][row][cb * 32 + q * 8 + 4];
            uint4 pk;
            pk.x = (unsigned int)f2bf(o[0]) | ((unsigned int)f2bf(o[1]) << 16);
            pk.y = (unsigned int)f2bf(o[2]) | ((unsigned int)f2bf(o[3]) << 16);
            pk.z = (unsigned int)f2bf(o[4]) | ((unsigned int)f2bf(o[5]) << 16);
            pk.w = (unsigned int)f2bf(o[6]) | ((unsigned int)f2bf(o[7]) << 16);
            *(uint4*)(Cb + (size_t)node * HC + cb * 32 + q * 8) = pk;
        }
    }
}

// ----------------- aggregation: 1 wave/node; LDS coef table; 4-deep gather pipeline -----------------
__global__ __launch_bounds__(64) void aggregate_kernel(
        const unsigned short* __restrict__ h1b, const float* __restrict__ asrc, const float* __restrict__ adst,
        const int* __restrict__ rowptr, const int* __restrict__ colsrc,
        const float* __restrict__ bias, unsigned short* __restrict__ hout, int n)
{
    __shared__ float4 exl[64];
    int i = blockIdx.x;
    if (i >= n) return;
    int t = threadIdx.x;
    int head = t >> 5;
    float2 adv = *(const float2*)(adst + (size_t)i * 2);
    float2 asv = *(const float2*)(asrc + (size_t)i * 2);
    float ads = head ? adv.y : adv.x;
    float exs = __expf(lrelu((head ? asv.y : asv.x) + ads));   // self loop
    unsigned int hv = ((const unsigned int*)(h1b + (size_t)i * HC))[t];
    float acc0 = exs * bf_lo(hv), acc1 = exs * bf_hi(hv), D = exs;

    int e  = rowptr[i];
    int e1 = rowptr[i + 1];
    while (e < e1){
        int m = e1 - e; if (m > 64) m = 64;
        if (t < m){
            int s = colsrc[e + t];
            float2 as = *(const float2*)(asrc + (size_t)s * 2);
            exl[t] = make_float4(__int_as_float(s),
                                 __expf(lrelu(as.x + adv.x)),
                                 __expf(lrelu(as.y + adv.y)), 0.f);
        }
        __syncthreads();
        int j = 0;
        for (; j + 4 <= m; j += 4){
            float4 q0 = exl[j], q1 = exl[j+1], q2 = exl[j+2], q3 = exl[j+3];
            const unsigned int* p0 = (const unsigned int*)(h1b + (size_t)__float_as_int(q0.x) * HC);
            const unsigned int* p1 = (const unsigned int*)(h1b + (size_t)__float_as_int(q1.x) * HC);
            const unsigned int* p2 = (const unsigned int*)(h1b + (size_t)__float_as_int(q2.x) * HC);
            const unsigned int* p3 = (const unsigned int*)(h1b + (size_t)__float_as_int(q3.x) * HC);
            unsigned int v0 = p0[t], v1 = p1[t], v2 = p2[t], v3 = p3[t];
            float c0 = head ? q0.z : q0.y;
            float c1 = head ? q1.z : q1.y;
            float c2 = head ? q2.z : q2.y;
            float c3 = head ? q3.z : q3.y;
            acc0 = fmaf(c0, bf_lo(v0), acc0);  acc1 = fmaf(c0, bf_hi(v0), acc1);
            acc0 = fmaf(c1, bf_lo(v1), acc0);  acc1 = fmaf(c1, bf_hi(v1), acc1);
            acc0 = fmaf(c2, bf_lo(v2), acc0);  acc1 = fmaf(c2, bf_hi(v2), acc1);
            acc0 = fmaf(c3, bf_lo(v3), acc0);  acc1 = fmaf(c3, bf_hi(v3), acc1);
            D += (c0 + c1) + (c2 + c3);
        }
        for (; j < m; ++j){
            float4 q = exl[j];
            unsigned int v = ((const unsigned int*)(h1b + (size_t)__float_as_int(q.x) * HC))[t];
            float c = head ? q.z : q.y;
            acc0 = fmaf(c, bf_lo(v), acc0);
            acc1 = fmaf(c, bf_hi(v), acc1);
            D += c;
        }
        __syncthreads();
        e += m;
    }
    float rD = 1.0f / D;
    float o0 = fmaxf(acc0 * rD + bias[2*t],     0.f);
    float o1 = fmaxf(acc1 * rD + bias[2*t + 1], 0.f);
    ((unsigned int*)hout)[(size_t)i * 64 + t] =
        (unsigned int)f2bf(o0) | ((unsigned int)f2bf(o1) << 16);
}

// ----------------- graph mean: two-stage, bf16 input, NO global atomics -----------------
__global__ __launch_bounds__(256) void mean_part_kernel(
        const unsigned short* __restrict__ h, float* __restrict__ partial, int n)
{
    int t = threadIdx.x;
    int cq = t & 31;
    int rl = t >> 5;
    float4 acc = make_float4(0.f, 0.f, 0.f, 0.f);
    for (int i = blockIdx.x * 8 + rl; i < n; i += gridDim.x * 8){
        uint2 v = *(const uint2*)(h + (size_t)i * HC + cq * 4);
        acc.x += bf_lo(v.x); acc.y += bf_hi(v.x);
        acc.z += bf_lo(v.y); acc.w += bf_hi(v.y);
    }
    __shared__ float4 red[256];
    red[t] = acc;
    __syncthreads();
    if (t < 128){
        float4 o = red[t + 128];
        red[t].x += o.x; red[t].y += o.y; red[t].z += o.z; red[t].w += o.w;
    }
    __syncthreads();
    if (t < 64){
        float4 o = red[t + 64];
        red[t].x += o.x; red[t].y += o.y; red[t].z += o.z; red[t].w += o.w;
    }
    __syncthreads();
    if (t < 32){
        float4 a = red[t], b = red[t + 32];
        float4 s = make_float4(a.x + b.x, a.y + b.y, a.z + b.z, a.w + b.w);
        *(float4*)(partial + (size_t)blockIdx.x * HC + t * 4) = s;
    }
}

__global__ __launch_bounds__(256) void mean_fin_kernel(
        const float* __restrict__ partial, float* __restrict__ g, int nb)
{
    int t = threadIdx.x;
    int cq = t & 31, b0 = t >> 5;
    float4 acc = make_float4(0.f, 0.f, 0.f, 0.f);
    for (int b = b0; b < nb; b += 8){
        float4 v = *(const float4*)(partial + (size_t)b * HC + cq * 4);
        acc.x += v.x; acc.y += v.y; acc.z += v.z; acc.w += v.w;
    }
    __shared__ float4 red[256];
    red[t] = acc;
    __syncthreads();
    if (t < 128){
        float4 o = red[t + 128];
        red[t].x += o.x; red[t].y += o.y; red[t].z += o.z; red[t].w += o.w;
    }
    __syncthreads();
    if (t < 64){
        float4 o = red[t + 64];
        red[t].x += o.x; red[t].y += o.y; red[t].z += o.z; red[t].w += o.w;
    }
    __syncthreads();
    if (t < 32){
        float4 a = red[t], b = red[t + 32];
        float4 s = make_float4(a.x + b.x, a.y + b.y, a.z + b.z, a.w + b.w);
        *(float4*)(g + t * 4) = s;
    }
}

// ----------------- vuln head (bf16 input): sigmoid(relu(h@wv1+bv1)@wv2+bv2) -----------------
__global__ __launch_bounds__(256) void vuln_fused_kernel(
        const unsigned short* __restrict__ h, const float* __restrict__ wv1, const float* __restrict__ bv1,
        const float* __restrict__ wv2, const float* __restrict__ bv2,
        float* __restrict__ out, int n)
{
    __shared__ float As[32][68];
    __shared__ float Bs[32][64];
    int t = threadIdx.x;
    int m0 = blockIdx.x * 64;
    int tm = t >> 4, tn = t & 15;
    int kq = t >> 6, arow = t & 63;

    float acc[4][4];
    #pragma unroll
    for (int i = 0; i < 4; ++i)
        #pragma unroll
        for (int j = 0; j < 4; ++j) acc[i][j] = 0.f;

    for (int kc = 0; kc < 4; ++kc){
        int k0 = kc * 32;
        {
            int gr = m0 + arow; if (gr > n - 1) gr = n - 1;
            uint4 v = *(const uint4*)(h + (size_t)gr * HC + k0 + kq * 8);
            As[kq*8+0][arow] = bf_lo(v.x); As[kq*8+1][arow] = bf_hi(v.x);
            As[kq*8+2][arow] = bf_lo(v.y); As[kq*8+3][arow] = bf_hi(v.y);
            As[kq*8+4][arow] = bf_lo(v.z); As[kq*8+5][arow] = bf_hi(v.z);
            As[kq*8+6][arow] = bf_lo(v.w); As[kq*8+7][arow] = bf_hi(v.w);
        }
        #pragma unroll
        for (int i = 0; i < 2; ++i){        // B chunk 32x64
            int f = i * 256 + t;
            int kk = f >> 4, nq = f & 15;
            *(float4*)&Bs[kk][nq*4] = *(const float4*)(wv1 + (size_t)(k0 + kk) * 64 + nq * 4);
        }
        __syncthreads();
        #pragma unroll 4
        for (int k = 0; k < 32; ++k){
            float a[4], b[4];
            *(float4*)&a[0] = *(float4*)&As[k][tm*4];
            *(float4*)&b[0] = *(float4*)&Bs[k][tn*4];
            #pragma unroll
            for (int i = 0; i < 4; ++i)
                #pragma unroll
                for (int j = 0; j < 4; ++j) acc[i][j] = fmaf(a[i], b[j], acc[i][j]);
        }
        __syncthreads();
    }

    float bb[4], wv[4];
    *(float4*)&bb[0] = *(const float4*)(bv1 + tn*4);
    *(float4*)&wv[0] = *(const float4*)(wv2 + tn*4);
    float bv2v = bv2[0];
    #pragma unroll
    for (int i = 0; i < 4; ++i){
        float v = 0.f;
        #pragma unroll
        for (int j = 0; j < 4; ++j) v = fmaf(fmaxf(acc[i][j] + bb[j], 0.f), wv[j], v);
        v += __shfl_xor(v, 1); v += __shfl_xor(v, 2);
        v += __shfl_xor(v, 4); v += __shfl_xor(v, 8);
        int node = m0 + tm*4 + i;
        if (tn == 0 && node < n)
            out[1 + node] = 1.0f / (1.0f + __expf(-(v + bv2v)));
    }
}

// ----------------- path head (1 block) -----------------
__global__ __launch_bounds__(128) void path_kernel(
        const unsigned short* __restrict__ h, const float* __restrict__ g,
        const float* __restrict__ wp1, const float* __restrict__ bp1,
        const float* __restrict__ wp2, const float* __restrict__ bp2,
        const float* __restrict__ wp3, const float* __restrict__ bp3,
        float* __restrict__ out, int n)
{
    __shared__ float pc[256];
    __shared__ float p1[HC];
    __shared__ float p2[64];
    int t = threadIdx.x;              // 128
    pc[t]       = bf1(h[t]);          // h[0,:]
    pc[128 + t] = g[t] * (1.0f / (float)n);
    __syncthreads();
    float a = bp1[t];
    for (int k = 0; k < 256; ++k) a = fmaf(pc[k], wp1[k * HC + t], a);
    p1[t] = fmaxf(a, 0.f);
    __syncthreads();
    if (t < 64){
        float a2 = bp2[t];
        for (int k = 0; k < HC; ++k) a2 = fmaf(p1[k], wp2[k * 64 + t], a2);
        p2[t] = fmaxf(a2, 0.f);
    }
    __syncthreads();
    if (t == 0){
        float a3 = bp3[0];
        for (int k = 0; k < 64; ++k) a3 = fmaf(p2[k], wp3[k], a3);
        out[0] = 1.0f / (1.0f + __expf(-a3));
        out[1 + n] = 0.f;             // esc = 0
    }
}

extern "C" void kernel_launch(void* const* d_in, const int* in_sizes, int n_in,
                              void* d_out, int out_size, void* d_ws, size_t ws_size,
                              hipStream_t stream)
{
    const float* x    = (const float*)d_in[0];
    const int*   ei   = (const int*)d_in[1];
    const float* w_n1 = (const float*)d_in[3];
    const float* b_n1 = (const float*)d_in[4];
    const float* w_n2 = (const float*)d_in[5];
    const float* b_n2 = (const float*)d_in[6];
    const float* conv_w = (const float*)d_in[9];
    const float* att_s  = (const float*)d_in[10];
    const float* att_d  = (const float*)d_in[11];
    const float* conv_b = (const float*)d_in[12];
    const float* wp1 = (const float*)d_in[13];
    const float* bp1 = (const float*)d_in[14];
    const float* wp2 = (const float*)d_in[15];
    const float* bp2 = (const float*)d_in[16];
    const float* wp3 = (const float*)d_in[17];
    const float* bp3 = (const float*)d_in[18];
    const float* wv1 = (const float*)d_in[19];
    const float* bv1 = (const float*)d_in[20];
    const float* wv2 = (const float*)d_in[21];
    const float* bv2 = (const float*)d_in[22];

    const int N = in_sizes[0] / 32;
    const int E = in_sizes[1] / 2;
    float* out = (float*)d_out;

    char* ws = (char*)d_ws;
    size_t off = 0;
    auto take = [&](size_t bytes) -> char* {
        char* p = ws + off;
        off += (bytes + 255) & ~(size_t)255;
        return p;
    };
    unsigned short* hA = (unsigned short*)take((size_t)N * HC * 2);  // bf16 node features
    unsigned short* hB = (unsigned short*)take((size_t)N * HC * 2);  // bf16 hid / h'
    float* asrc  = (float*)take((size_t)N * 2 * 4);
    float* adst  = (float*)take((size_t)N * 2 * 4);
    int*   rowptr= (int*)take((size_t)(N + 1) * 4);
    int*   cnt   = (int*)take((size_t)N * 4);
    int*   rank  = (int*)take((size_t)E * 4);
    int*   colsrc= (int*)take((size_t)E * 4);
    float* g     = (float*)take(HC * 4);
    unsigned short* Wt0 = (unsigned short*)take(16384 * 2);          // w_n2 transposed bf16
    unsigned short* Wt1 = (unsigned short*)take((size_t)3 * 16384 * 2); // conv_w transposed bf16
    const int MB = 64;                                  // mean partial blocks
    float* mpart = (float*)take((size_t)MB * HC * 4);
    int nb = (N + 1023) / 1024;
    int*   bsum  = (int*)take((size_t)((nb + 63) & ~63) * 4);
    int*   boff  = (int*)take((size_t)((nb + 63) & ~63) * 4);

    // --- CSR build (dst-sorted; reused across the 3 layers) ---
    hipMemsetAsync(cnt, 0, (size_t)N * 4, stream);
    count_kernel<<<(E + 255) / 256, 256, 0, stream>>>(ei, cnt, rank, E);
    scan_part_kernel<<<nb, 256, 0, stream>>>(cnt, bsum, N);
    scan_top_kernel<<<1, 64, 0, stream>>>(bsum, boff, rowptr, nb, N);
    scan_fin_kernel<<<nb, 256, 0, stream>>>(cnt, boff, rowptr, N);
    scatter_kernel<<<(E + 1023) / 1024, 256, 0, stream>>>(ei, rowptr, rank, colsrc, E);

    // --- weights -> transposed bf16 for MFMA B fragments ---
    wtrans_kernel<<<8, 256, 0, stream>>>(w_n2, Wt0, 1);
    wtrans_kernel<<<24, 256, 0, stream>>>(conv_w, Wt1, 3);

    int nblk64 = (N + 63) / 64;
    // node encoder: hid (hB bf16) = relu(x@w1+b1); hA = hid@w2 + b2 (bf16, MFMA)
    enc1_kernel<<<nblk64, 256, 0, stream>>>(x, w_n1, b_n1, hB, N);
    gemm_mfma_kernel<false><<<nblk64, 256, 0, stream>>>(
        hB, Wt0, b_n2, nullptr, nullptr, hA, nullptr, nullptr, N);

    for (int l = 0; l < 3; ++l){
        gemm_mfma_kernel<true><<<nblk64, 256, 0, stream>>>(
            hA, Wt1 + (size_t)l * 16384, nullptr,
            att_s + (size_t)l * HC, att_d + (size_t)l * HC,
            hB, asrc, adst, N);
        aggregate_kernel<<<N, 64, 0, stream>>>(
            hB, asrc, adst, rowptr, colsrc, conv_b + (size_t)l * HC, hA, N);
    }

    mean_part_kernel<<<MB, 256, 0, stream>>>(hA, mpart, N);
    mean_fin_kernel<<<1, 256, 0, stream>>>(mpart, g, MB);
    vuln_fused_kernel<<<nblk64, 256, 0, stream>>>(hA, wv1, bv1, wv2, bv2, out, N);
    path_kernel<<<1, 128, 0, stream>>>(hA, g, wp1, bp1, wp2, bp2, wp3, bp3, out, N);
}

// Round 12
// 333.898 us; speedup vs baseline: 1.4782x; 1.0087x over previous
//
#include <hip/hip_runtime.h>
#include <math.h>

#define HC 128
#define NSLOPE 0.2f

using bf16x8 = __attribute__((ext_vector_type(8))) short;
using f32x4  = __attribute__((ext_vector_type(4))) float;

__device__ __forceinline__ float lrelu(float v){ return v > 0.f ? v : NSLOPE * v; }

// bf16 round-to-nearest-even pack / unpack
__device__ __forceinline__ unsigned short f2bf(float f){
    unsigned int b = __float_as_uint(f);
    b += 0x7FFFu + ((b >> 16) & 1u);
    return (unsigned short)(b >> 16);
}
__device__ __forceinline__ float bf_lo(unsigned int v){ return __uint_as_float(v << 16); }
__device__ __forceinline__ float bf_hi(unsigned int v){ return __uint_as_float(v & 0xFFFF0000u); }
__device__ __forceinline__ float bf1(unsigned short v){ return __uint_as_float((unsigned int)v << 16); }

// ----------------- CSR build (dst-sorted) -----------------
__global__ void count_kernel(const int* __restrict__ ei, int* __restrict__ cnt,
                             int* __restrict__ rank, int E){
    int e = blockIdx.x * blockDim.x + threadIdx.x;
    if (e < E) rank[e] = atomicAdd(&cnt[ei[E + e]], 1);
}

__global__ __launch_bounds__(256) void scan_part_kernel(
        const int* __restrict__ deg, int* __restrict__ bsum, int n)
{
    int t = threadIdx.x, lane = t & 63, wid = t >> 6;
    int base = blockIdx.x * 1024 + t * 4;
    int s = 0;
    #pragma unroll
    for (int j = 0; j < 4; ++j){ int i = base + j; if (i < n) s += deg[i]; }
    #pragma unroll
    for (int o = 1; o < 64; o <<= 1) s += __shfl_xor(s, o);
    __shared__ int red[4];
    if (lane == 0) red[wid] = s;
    __syncthreads();
    if (t == 0) bsum[blockIdx.x] = red[0] + red[1] + red[2] + red[3];
}

__global__ __launch_bounds__(64) void scan_top_kernel(
        const int* __restrict__ bsum, int* __restrict__ boff, int* __restrict__ rowptr,
        int nb, int n)
{
    int t = threadIdx.x;
    int v = (t < nb) ? bsum[t] : 0;
    int incl = v;
    #pragma unroll
    for (int o = 1; o < 64; o <<= 1){ int u = __shfl_up(incl, o); if (t >= o) incl += u; }
    if (t < nb) boff[t] = incl - v;
    if (t == 63) rowptr[n] = incl;
}

__global__ __launch_bounds__(256) void scan_fin_kernel(
        const int* __restrict__ deg, const int* __restrict__ boff,
        int* __restrict__ rowptr, int n)
{
    int t = threadIdx.x, lane = t & 63, wid = t >> 6;
    int base = blockIdx.x * 1024 + t * 4;
    int d[4]; int s = 0;
    #pragma unroll
    for (int j = 0; j < 4; ++j){ int i = base + j; d[j] = (i < n) ? deg[i] : 0; s += d[j]; }
    int incl = s;
    #pragma unroll
    for (int o = 1; o < 64; o <<= 1){ int u = __shfl_up(incl, o); if (lane >= o) incl += u; }
    __shared__ int wsum[4];
    if (lane == 63) wsum[wid] = incl;
    __syncthreads();
    int off = boff[blockIdx.x] + (incl - s);
    for (int w = 0; w < wid; ++w) off += wsum[w];
    #pragma unroll
    for (int j = 0; j < 4; ++j){
        int i = base + j;
        if (i < n) rowptr[i] = off;
        off += d[j];
    }
}

// stateless scatter, ILP=8
__global__ __launch_bounds__(256) void scatter_kernel(
        const int* __restrict__ ei, const int* __restrict__ rowptr,
        const int* __restrict__ rank, int* __restrict__ colsrc, int E)
{
    int b = blockIdx.x * 2048 + threadIdx.x;
    int e[8]; bool v[8]; int d[8], s[8], r[8];
    #pragma unroll
    for (int i = 0; i < 8; ++i){ e[i] = b + i * 256; v[i] = e[i] < E; }
    #pragma unroll
    for (int i = 0; i < 8; ++i) if (v[i]){ d[i] = ei[E + e[i]]; s[i] = ei[e[i]]; r[i] = rank[e[i]]; }
    #pragma unroll
    for (int i = 0; i < 8; ++i) if (v[i]) colsrc[rowptr[d[i]] + r[i]] = s[i];
}

// ----------------- weight transpose->bf16 (K x C, row-major) -> Wt[c][k] -----------------
__global__ __launch_bounds__(256) void wtrans_kernel(
        const float* __restrict__ W, unsigned short* __restrict__ Wt,
        int K, int C, int nmat)
{
    int kg8 = K >> 3;
    int per = C * kg8;
    int idx = blockIdx.x * 256 + threadIdx.x;
    if (idx >= nmat * per) return;
    int mat = idx / per;
    int rem = idx - mat * per;
    int c = rem / kg8, kg = rem - c * kg8;
    const float* Wm = W + (size_t)mat * K * C;
    unsigned short* Wo = Wt + (size_t)mat * K * C;
    unsigned int pk[4];
    #pragma unroll
    for (int j = 0; j < 4; ++j){
        float a = Wm[(size_t)(kg*8 + j*2    ) * C + c];
        float b = Wm[(size_t)(kg*8 + j*2 + 1) * C + c];
        pk[j] = (unsigned int)f2bf(a) | ((unsigned int)f2bf(b) << 16);
    }
    *(uint4*)(Wo + (size_t)c * K + kg * 8) = make_uint4(pk[0], pk[1], pk[2], pk[3]);
}

// ----------------- node encoder stage 1: hid(bf16) = relu(x@w1+b1), K=32 -----------------
__global__ __launch_bounds__(256) void enc1_kernel(
        const float* __restrict__ x, const float* __restrict__ w1, const float* __restrict__ b1,
        unsigned short* __restrict__ hid, int n)
{
    __shared__ float As[32][68];
    __shared__ float Bs[32][128];
    int t = threadIdx.x;
    int m0 = blockIdx.x * 64;
    int tm = t >> 4, tn = t & 15;

    #pragma unroll
    for (int i = 0; i < 2; ++i){
        int f = i * 256 + t;
        int row = f >> 3, kq = f & 7;
        int gr = m0 + row; if (gr > n - 1) gr = n - 1;
        float4 v = *(const float4*)(x + (size_t)gr * 32 + kq * 4);
        As[kq*4+0][row] = v.x; As[kq*4+1][row] = v.y; As[kq*4+2][row] = v.z; As[kq*4+3][row] = v.w;
    }
    #pragma unroll
    for (int i = 0; i < 4; ++i){
        int f = i * 256 + t;
        int kk = f >> 5, nq = f & 31;
        *(float4*)&Bs[kk][nq*4] = *(const float4*)(w1 + (size_t)kk * 128 + nq * 4);
    }
    __syncthreads();

    float acc[4][8];
    #pragma unroll
    for (int i = 0; i < 4; ++i)
        #pragma unroll
        for (int j = 0; j < 8; ++j) acc[i][j] = 0.f;

    #pragma unroll 4
    for (int k = 0; k < 32; ++k){
        float a[4], b[8];
        *(float4*)&a[0] = *(float4*)&As[k][tm*4];
        *(float4*)&b[0] = *(float4*)&Bs[k][tn*8];
        *(float4*)&b[4] = *(float4*)&Bs[k][tn*8+4];
        #pragma unroll
        for (int i = 0; i < 4; ++i)
            #pragma unroll
            for (int j = 0; j < 8; ++j) acc[i][j] = fmaf(a[i], b[j], acc[i][j]);
    }

    float bb[8];
    *(float4*)&bb[0] = *(const float4*)(b1 + tn*8);
    *(float4*)&bb[4] = *(const float4*)(b1 + tn*8 + 4);
    #pragma unroll
    for (int i = 0; i < 4; ++i){
        int node = m0 + tm*4 + i;
        if (node < n){
            float o[8];
            #pragma unroll
            for (int j = 0; j < 8; ++j) o[j] = fmaxf(acc[i][j] + bb[j], 0.f);
            uint4 pk;
            pk.x = (unsigned int)f2bf(o[0]) | ((unsigned int)f2bf(o[1]) << 16);
            pk.y = (unsigned int)f2bf(o[2]) | ((unsigned int)f2bf(o[3]) << 16);
            pk.z = (unsigned int)f2bf(o[4]) | ((unsigned int)f2bf(o[5]) << 16);
            pk.w = (unsigned int)f2bf(o[6]) | ((unsigned int)f2bf(o[7]) << 16);
            *(uint4*)(hid + (size_t)node*HC + tn*8) = pk;
        }
    }
}

// ----------------- MFMA GEMM: C(bf16)[n][128] = A(bf16)[n][128] @ W + bias -----------------
template<bool ATT>
__global__ __launch_bounds__(256) void gemm_mfma_kernel(
        const unsigned short* __restrict__ A, const unsigned short* __restrict__ Wt,
        const float* __restrict__ bias,
        const float* __restrict__ att_s, const float* __restrict__ att_d,
        unsigned short* __restrict__ Cb,
        float* __restrict__ asrc, float* __restrict__ adst, int n)
{
    __shared__ float lds[4][16][132];
    int t = threadIdx.x;
    int w = t >> 6, l = t & 63;
    int lane15 = l & 15, lanehi = l >> 4;
    int m0 = blockIdx.x * 64 + w * 16;

    f32x4 acc[8];
    #pragma unroll
    for (int ct = 0; ct < 8; ++ct) acc[ct] = (f32x4){0.f, 0.f, 0.f, 0.f};

    int ar = m0 + lane15; if (ar > n - 1) ar = n - 1;
    const unsigned short* Arow = A + (size_t)ar * HC;

    #pragma unroll
    for (int kc = 0; kc < 4; ++kc){
        bf16x8 af = *reinterpret_cast<const bf16x8*>(Arow + kc * 32 + lanehi * 8);
        #pragma unroll
        for (int ct = 0; ct < 8; ++ct){
            bf16x8 bf = *reinterpret_cast<const bf16x8*>(
                Wt + (size_t)(ct * 16 + lane15) * HC + kc * 32 + lanehi * 8);
            acc[ct] = __builtin_amdgcn_mfma_f32_16x16x32_bf16(af, bf, acc[ct], 0, 0, 0);
        }
    }

    if (ATT){
        float ats[8], atd[8];
        #pragma unroll
        for (int ct = 0; ct < 8; ++ct){
            ats[ct] = att_s[ct * 16 + lane15];
            atd[ct] = att_d[ct * 16 + lane15];
        }
        #pragma unroll
        for (int r = 0; r < 4; ++r){
            float sa0 = 0.f, sd0 = 0.f, sa1 = 0.f, sd1 = 0.f;
            #pragma unroll
            for (int ct = 0; ct < 4; ++ct){
                sa0 = fmaf(acc[ct][r], ats[ct], sa0);
                sd0 = fmaf(acc[ct][r], atd[ct], sd0);
            }
            #pragma unroll
            for (int ct = 4; ct < 8; ++ct){
                sa1 = fmaf(acc[ct][r], ats[ct], sa1);
                sd1 = fmaf(acc[ct][r], atd[ct], sd1);
            }
            #pragma unroll
            for (int o = 1; o < 16; o <<= 1){
                sa0 += __shfl_xor(sa0, o); sd0 += __shfl_xor(sd0, o);
                sa1 += __shfl_xor(sa1, o); sd1 += __shfl_xor(sd1, o);
            }
            int node = m0 + lanehi * 4 + r;
            if (lane15 == 0 && node < n){
                asrc[(size_t)node * 2]     = sa0;
                adst[(size_t)node * 2]     = sd0;
                asrc[(size_t)node * 2 + 1] = sa1;
                adst[(size_t)node * 2 + 1] = sd1;
            }
        }
    }

    float bb[8];
    #pragma unroll
    for (int ct = 0; ct < 8; ++ct) bb[ct] = ATT ? 0.f : bias[ct * 16 + lane15];
    #pragma unroll
    for (int ct = 0; ct < 8; ++ct)
        #pragma unroll
        for (int r = 0; r < 4; ++r)
            lds[w][lanehi * 4 + r][ct * 16 + lane15] = acc[ct][r] + bb[ct];
    __syncthreads();

    int row = lane15, cb = lanehi;
    int node = m0 + row;
    if (node < n){
        #pragma unroll
        for (int q = 0; q < 4; ++q){
            float o[8];
            *(float4*)&o[0] = *(float4*)&lds[w][row][cb * 32 + q * 8];
            *(float4*)&o[4] = *(float4*)&lds[w][row][cb * 32 + q * 8 + 4];
            uint4 pk;
            pk.x = (unsigned int)f2bf(o[0]) | ((unsigned int)f2bf(o[1]) << 16);
            pk.y = (unsigned int)f2bf(o[2]) | ((unsigned int)f2bf(o[3]) << 16);
            pk.z = (unsigned int)f2bf(o[4]) | ((unsigned int)f2bf(o[5]) << 16);
            pk.w = (unsigned int)f2bf(o[6]) | ((unsigned int)f2bf(o[7]) << 16);
            *(uint4*)(Cb + (size_t)node * HC + cb * 32 + q * 8) = pk;
        }
    }
}

// ----------------- aggregation: 1 wave/node; LDS coef table; 8-deep gather pipeline -----------------
__global__ __launch_bounds__(64) void aggregate_kernel(
        const unsigned short* __restrict__ h1b, const float* __restrict__ asrc, const float* __restrict__ adst,
        const int* __restrict__ rowptr, const int* __restrict__ colsrc,
        const float* __restrict__ bias, unsigned short* __restrict__ hout, int n)
{
    __shared__ float4 exl[64];
    int i = blockIdx.x;
    if (i >= n) return;
    int t = threadIdx.x;
    int head = t >> 5;
    float2 adv = *(const float2*)(adst + (size_t)i * 2);
    float2 asv = *(const float2*)(asrc + (size_t)i * 2);
    float ads = head ? adv.y : adv.x;
    float exs = __expf(lrelu((head ? asv.y : asv.x) + ads));   // self loop
    unsigned int hv = ((const unsigned int*)(h1b + (size_t)i * HC))[t];
    float acc0 = exs * bf_lo(hv), acc1 = exs * bf_hi(hv), D = exs;

    int e  = rowptr[i];
    int e1 = rowptr[i + 1];
    while (e < e1){
        int m = e1 - e; if (m > 64) m = 64;
        if (t < m){
            int s = colsrc[e + t];
            float2 as = *(const float2*)(asrc + (size_t)s * 2);
            exl[t] = make_float4(__int_as_float(s),
                                 __expf(lrelu(as.x + adv.x)),
                                 __expf(lrelu(as.y + adv.y)), 0.f);
        }
        __syncthreads();
        int j = 0;
        for (; j + 8 <= m; j += 8){
            float4 q[8];
            #pragma unroll
            for (int u = 0; u < 8; ++u) q[u] = exl[j + u];
            unsigned int v[8];
            #pragma unroll
            for (int u = 0; u < 8; ++u)
                v[u] = ((const unsigned int*)(h1b + (size_t)__float_as_int(q[u].x) * HC))[t];
            #pragma unroll
            for (int u = 0; u < 8; ++u){
                float c = head ? q[u].z : q[u].y;
                acc0 = fmaf(c, bf_lo(v[u]), acc0);
                acc1 = fmaf(c, bf_hi(v[u]), acc1);
                D += c;
            }
        }
        for (; j < m; ++j){
            float4 q = exl[j];
            unsigned int v = ((const unsigned int*)(h1b + (size_t)__float_as_int(q.x) * HC))[t];
            float c = head ? q.z : q.y;
            acc0 = fmaf(c, bf_lo(v), acc0);
            acc1 = fmaf(c, bf_hi(v), acc1);
            D += c;
        }
        __syncthreads();
        e += m;
    }
    float rD = 1.0f / D;
    float o0 = fmaxf(acc0 * rD + bias[2*t],     0.f);
    float o1 = fmaxf(acc1 * rD + bias[2*t + 1], 0.f);
    ((unsigned int*)hout)[(size_t)i * 64 + t] =
        (unsigned int)f2bf(o0) | ((unsigned int)f2bf(o1) << 16);
}

// ----------------- graph mean: two-stage, bf16 input -----------------
__global__ __launch_bounds__(256) void mean_part_kernel(
        const unsigned short* __restrict__ h, float* __restrict__ partial, int n)
{
    int t = threadIdx.x;
    int cq = t & 31;
    int rl = t >> 5;
    float4 acc = make_float4(0.f, 0.f, 0.f, 0.f);
    for (int i = blockIdx.x * 8 + rl; i < n; i += gridDim.x * 8){
        uint2 v = *(const uint2*)(h + (size_t)i * HC + cq * 4);
        acc.x += bf_lo(v.x); acc.y += bf_hi(v.x);
        acc.z += bf_lo(v.y); acc.w += bf_hi(v.y);
    }
    __shared__ float4 red[256];
    red[t] = acc;
    __syncthreads();
    if (t < 128){
        float4 o = red[t + 128];
        red[t].x += o.x; red[t].y += o.y; red[t].z += o.z; red[t].w += o.w;
    }
    __syncthreads();
    if (t < 64){
        float4 o = red[t + 64];
        red[t].x += o.x; red[t].y += o.y; red[t].z += o.z; red[t].w += o.w;
    }
    __syncthreads();
    if (t < 32){
        float4 a = red[t], b = red[t + 32];
        float4 s = make_float4(a.x + b.x, a.y + b.y, a.z + b.z, a.w + b.w);
        *(float4*)(partial + (size_t)blockIdx.x * HC + t * 4) = s;
    }
}

__global__ __launch_bounds__(256) void mean_fin_kernel(
        const float* __restrict__ partial, float* __restrict__ g, int nb)
{
    int t = threadIdx.x;
    int cq = t & 31, b0 = t >> 5;
    float4 acc = make_float4(0.f, 0.f, 0.f, 0.f);
    for (int b = b0; b < nb; b += 8){
        float4 v = *(const float4*)(partial + (size_t)b * HC + cq * 4);
        acc.x += v.x; acc.y += v.y; acc.z += v.z; acc.w += v.w;
    }
    __shared__ float4 red[256];
    red[t] = acc;
    __syncthreads();
    if (t < 128){
        float4 o = red[t + 128];
        red[t].x += o.x; red[t].y += o.y; red[t].z += o.z; red[t].w += o.w;
    }
    __syncthreads();
    if (t < 64){
        float4 o = red[t + 64];
        red[t].x += o.x; red[t].y += o.y; red[t].z += o.z; red[t].w += o.w;
    }
    __syncthreads();
    if (t < 32){
        float4 a = red[t], b = red[t + 32];
        float4 s = make_float4(a.x + b.x, a.y + b.y, a.z + b.z, a.w + b.w);
        *(float4*)(g + t * 4) = s;
    }
}

// ----------------- vuln head, MFMA: sigmoid(relu(h@wv1+bv1)@wv2+bv2) -----------------
// 4 waves/block, wave w rows m0+w*16..+15; Wtv[c=64][k=128] bf16; 4 col-tiles x 4 K-chunks.
__global__ __launch_bounds__(256) void vuln_mfma_kernel(
        const unsigned short* __restrict__ h, const unsigned short* __restrict__ Wtv,
        const float* __restrict__ bv1, const float* __restrict__ wv2,
        const float* __restrict__ bv2, float* __restrict__ out, int n)
{
    int t = threadIdx.x;
    int w = t >> 6, l = t & 63;
    int lane15 = l & 15, lanehi = l >> 4;
    int m0 = blockIdx.x * 64 + w * 16;

    f32x4 acc[4];
    #pragma unroll
    for (int ct = 0; ct < 4; ++ct) acc[ct] = (f32x4){0.f, 0.f, 0.f, 0.f};

    int ar = m0 + lane15; if (ar > n - 1) ar = n - 1;
    const unsigned short* Arow = h + (size_t)ar * HC;

    #pragma unroll
    for (int kc = 0; kc < 4; ++kc){
        bf16x8 af = *reinterpret_cast<const bf16x8*>(Arow + kc * 32 + lanehi * 8);
        #pragma unroll
        for (int ct = 0; ct < 4; ++ct){
            bf16x8 bf = *reinterpret_cast<const bf16x8*>(
                Wtv + (size_t)(ct * 16 + lane15) * HC + kc * 32 + lanehi * 8);
            acc[ct] = __builtin_amdgcn_mfma_f32_16x16x32_bf16(af, bf, acc[ct], 0, 0, 0);
        }
    }

    float bb[4], wv[4];
    #pragma unroll
    for (int ct = 0; ct < 4; ++ct){
        bb[ct] = bv1[ct * 16 + lane15];
        wv[ct] = wv2[ct * 16 + lane15];
    }
    float bv2v = bv2[0];
    #pragma unroll
    for (int r = 0; r < 4; ++r){
        float s = 0.f;
        #pragma unroll
        for (int ct = 0; ct < 4; ++ct)
            s = fmaf(fmaxf(acc[ct][r] + bb[ct], 0.f), wv[ct], s);
        #pragma unroll
        for (int o = 1; o < 16; o <<= 1) s += __shfl_xor(s, o);
        int node = m0 + lanehi * 4 + r;
        if (lane15 == 0 && node < n)
            out[1 + node] = 1.0f / (1.0f + __expf(-(s + bv2v)));
    }
}

// ----------------- path head (1 block) -----------------
__global__ __launch_bounds__(128) void path_kernel(
        const unsigned short* __restrict__ h, const float* __restrict__ g,
        const float* __restrict__ wp1, const float* __restrict__ bp1,
        const float* __restrict__ wp2, const float* __restrict__ bp2,
        const float* __restrict__ wp3, const float* __restrict__ bp3,
        float* __restrict__ out, int n)
{
    __shared__ float pc[256];
    __shared__ float p1[HC];
    __shared__ float p2[64];
    int t = threadIdx.x;              // 128
    pc[t]       = bf1(h[t]);          // h[0,:]
    pc[128 + t] = g[t] * (1.0f / (float)n);
    __syncthreads();
    float a = bp1[t];
    for (int k = 0; k < 256; ++k) a = fmaf(pc[k], wp1[k * HC + t], a);
    p1[t] = fmaxf(a, 0.f);
    __syncthreads();
    if (t < 64){
        float a2 = bp2[t];
        for (int k = 0; k < HC; ++k) a2 = fmaf(p1[k], wp2[k * 64 + t], a2);
        p2[t] = fmaxf(a2, 0.f);
    }
    __syncthreads();
    if (t == 0){
        float a3 = bp3[0];
        for (int k = 0; k < 64; ++k) a3 = fmaf(p2[k], wp3[k], a3);
        out[0] = 1.0f / (1.0f + __expf(-a3));
        out[1 + n] = 0.f;             // esc = 0
    }
}

extern "C" void kernel_launch(void* const* d_in, const int* in_sizes, int n_in,
                              void* d_out, int out_size, void* d_ws, size_t ws_size,
                              hipStream_t stream)
{
    const float* x    = (const float*)d_in[0];
    const int*   ei   = (const int*)d_in[1];
    const float* w_n1 = (const float*)d_in[3];
    const float* b_n1 = (const float*)d_in[4];
    const float* w_n2 = (const float*)d_in[5];
    const float* b_n2 = (const float*)d_in[6];
    const float* conv_w = (const float*)d_in[9];
    const float* att_s  = (const float*)d_in[10];
    const float* att_d  = (const float*)d_in[11];
    const float* conv_b = (const float*)d_in[12];
    const float* wp1 = (const float*)d_in[13];
    const float* bp1 = (const float*)d_in[14];
    const float* wp2 = (const float*)d_in[15];
    const float* bp2 = (const float*)d_in[16];
    const float* wp3 = (const float*)d_in[17];
    const float* bp3 = (const float*)d_in[18];
    const float* wv1 = (const float*)d_in[19];
    const float* bv1 = (const float*)d_in[20];
    const float* wv2 = (const float*)d_in[21];
    const float* bv2 = (const float*)d_in[22];

    const int N = in_sizes[0] / 32;
    const int E = in_sizes[1] / 2;
    float* out = (float*)d_out;

    char* ws = (char*)d_ws;
    size_t off = 0;
    auto take = [&](size_t bytes) -> char* {
        char* p = ws + off;
        off += (bytes + 255) & ~(size_t)255;
        return p;
    };
    unsigned short* hA = (unsigned short*)take((size_t)N * HC * 2);  // bf16 node features
    unsigned short* hB = (unsigned short*)take((size_t)N * HC * 2);  // bf16 hid / h'
    float* asrc  = (float*)take((size_t)N * 2 * 4);
    float* adst  = (float*)take((size_t)N * 2 * 4);
    int*   rowptr= (int*)take((size_t)(N + 1) * 4);
    int*   cnt   = (int*)take((size_t)N * 4);
    int*   rank  = (int*)take((size_t)E * 4);
    int*   colsrc= (int*)take((size_t)E * 4);
    float* g     = (float*)take(HC * 4);
    unsigned short* Wt0 = (unsigned short*)take(16384 * 2);             // w_n2^T bf16
    unsigned short* Wt1 = (unsigned short*)take((size_t)3 * 16384 * 2); // conv_w^T bf16
    unsigned short* Wtv = (unsigned short*)take(8192 * 2);              // wv1^T bf16 (64x128)
    const int MB = 64;
    float* mpart = (float*)take((size_t)MB * HC * 4);
    int nb = (N + 1023) / 1024;
    int*   bsum  = (int*)take((size_t)((nb + 63) & ~63) * 4);
    int*   boff  = (int*)take((size_t)((nb + 63) & ~63) * 4);

    // --- CSR build (dst-sorted; reused across the 3 layers) ---
    hipMemsetAsync(cnt, 0, (size_t)N * 4, stream);
    count_kernel<<<(E + 255) / 256, 256, 0, stream>>>(ei, cnt, rank, E);
    scan_part_kernel<<<nb, 256, 0, stream>>>(cnt, bsum, N);
    scan_top_kernel<<<1, 64, 0, stream>>>(bsum, boff, rowptr, nb, N);
    scan_fin_kernel<<<nb, 256, 0, stream>>>(cnt, boff, rowptr, N);
    scatter_kernel<<<(E + 2047) / 2048, 256, 0, stream>>>(ei, rowptr, rank, colsrc, E);

    // --- weights -> transposed bf16 for MFMA B fragments ---
    wtrans_kernel<<<8, 256, 0, stream>>>(w_n2, Wt0, 128, 128, 1);
    wtrans_kernel<<<24, 256, 0, stream>>>(conv_w, Wt1, 128, 128, 3);
    wtrans_kernel<<<4, 256, 0, stream>>>(wv1, Wtv, 128, 64, 1);

    int nblk64 = (N + 63) / 64;
    // node encoder: hid (hB bf16) = relu(x@w1+b1); hA = hid@w2 + b2 (bf16, MFMA)
    enc1_kernel<<<nblk64, 256, 0, stream>>>(x, w_n1, b_n1, hB, N);
    gemm_mfma_kernel<false><<<nblk64, 256, 0, stream>>>(
        hB, Wt0, b_n2, nullptr, nullptr, hA, nullptr, nullptr, N);

    for (int l = 0; l < 3; ++l){
        gemm_mfma_kernel<true><<<nblk64, 256, 0, stream>>>(
            hA, Wt1 + (size_t)l * 16384, nullptr,
            att_s + (size_t)l * HC, att_d + (size_t)l * HC,
            hB, asrc, adst, N);
        aggregate_kernel<<<N, 64, 0, stream>>>(
            hB, asrc, adst, rowptr, colsrc, conv_b + (size_t)l * HC, hA, N);
    }

    mean_part_kernel<<<MB, 256, 0, stream>>>(hA, mpart, N);
    mean_fin_kernel<<<1, 256, 0, stream>>>(mpart, g, MB);
    vuln_mfma_kernel<<<nblk64, 256, 0, stream>>>(hA, Wtv, bv1, wv2, bv2, out, N);
    path_kernel<<<1, 128, 0, stream>>>(hA, g, wp1, bp1, wp2, bp2, wp3, bp3, out, N);
}

// Round 13
// 325.366 us; speedup vs baseline: 1.5170x; 1.0262x over previous
//
#include <hip/hip_runtime.h>
#include <math.h>

#define HC 128
#define NSLOPE 0.2f

using bf16x8 = __attribute__((ext_vector_type(8))) short;
using f32x4  = __attribute__((ext_vector_type(4))) float;

__device__ __forceinline__ float lrelu(float v){ return v > 0.f ? v : NSLOPE * v; }

// bf16 round-to-nearest-even pack / unpack
__device__ __forceinline__ unsigned short f2bf(float f){
    unsigned int b = __float_as_uint(f);
    b += 0x7FFFu + ((b >> 16) & 1u);
    return (unsigned short)(b >> 16);
}
__device__ __forceinline__ float bf_lo(unsigned int v){ return __uint_as_float(v << 16); }
__device__ __forceinline__ float bf_hi(unsigned int v){ return __uint_as_float(v & 0xFFFF0000u); }
__device__ __forceinline__ float bf1(unsigned short v){ return __uint_as_float((unsigned int)v << 16); }

// ----------------- CSR build (dst-sorted) -----------------
__global__ void count_kernel(const int* __restrict__ ei, int* __restrict__ cnt,
                             int* __restrict__ rank, int E){
    int e = blockIdx.x * blockDim.x + threadIdx.x;
    if (e < E) rank[e] = atomicAdd(&cnt[ei[E + e]], 1);
}

__global__ __launch_bounds__(256) void scan_part_kernel(
        const int* __restrict__ deg, int* __restrict__ bsum, int n)
{
    int t = threadIdx.x, lane = t & 63, wid = t >> 6;
    int base = blockIdx.x * 1024 + t * 4;
    int s = 0;
    #pragma unroll
    for (int j = 0; j < 4; ++j){ int i = base + j; if (i < n) s += deg[i]; }
    #pragma unroll
    for (int o = 1; o < 64; o <<= 1) s += __shfl_xor(s, o);
    __shared__ int red[4];
    if (lane == 0) red[wid] = s;
    __syncthreads();
    if (t == 0) bsum[blockIdx.x] = red[0] + red[1] + red[2] + red[3];
}

__global__ __launch_bounds__(64) void scan_top_kernel(
        const int* __restrict__ bsum, int* __restrict__ boff, int* __restrict__ rowptr,
        int nb, int n)
{
    int t = threadIdx.x;
    int v = (t < nb) ? bsum[t] : 0;
    int incl = v;
    #pragma unroll
    for (int o = 1; o < 64; o <<= 1){ int u = __shfl_up(incl, o); if (t >= o) incl += u; }
    if (t < nb) boff[t] = incl - v;
    if (t == 63) rowptr[n] = incl;
}

__global__ __launch_bounds__(256) void scan_fin_kernel(
        const int* __restrict__ deg, const int* __restrict__ boff,
        int* __restrict__ rowptr, int n)
{
    int t = threadIdx.x, lane = t & 63, wid = t >> 6;
    int base = blockIdx.x * 1024 + t * 4;
    int d[4]; int s = 0;
    #pragma unroll
    for (int j = 0; j < 4; ++j){ int i = base + j; d[j] = (i < n) ? deg[i] : 0; s += d[j]; }
    int incl = s;
    #pragma unroll
    for (int o = 1; o < 64; o <<= 1){ int u = __shfl_up(incl, o); if (lane >= o) incl += u; }
    __shared__ int wsum[4];
    if (lane == 63) wsum[wid] = incl;
    __syncthreads();
    int off = boff[blockIdx.x] + (incl - s);
    for (int w = 0; w < wid; ++w) off += wsum[w];
    #pragma unroll
    for (int j = 0; j < 4; ++j){
        int i = base + j;
        if (i < n) rowptr[i] = off;
        off += d[j];
    }
}

// stateless scatter, ILP=8
__global__ __launch_bounds__(256) void scatter_kernel(
        const int* __restrict__ ei, const int* __restrict__ rowptr,
        const int* __restrict__ rank, int* __restrict__ colsrc, int E)
{
    int b = blockIdx.x * 2048 + threadIdx.x;
    int e[8]; bool v[8]; int d[8], s[8], r[8];
    #pragma unroll
    for (int i = 0; i < 8; ++i){ e[i] = b + i * 256; v[i] = e[i] < E; }
    #pragma unroll
    for (int i = 0; i < 8; ++i) if (v[i]){ d[i] = ei[E + e[i]]; s[i] = ei[e[i]]; r[i] = rank[e[i]]; }
    #pragma unroll
    for (int i = 0; i < 8; ++i) if (v[i]) colsrc[rowptr[d[i]] + r[i]] = s[i];
}

// ----------------- all weight transposes -> bf16 Wt[c][K=128], one dispatch -----------------
__global__ __launch_bounds__(256) void wtrans_all_kernel(
        const float* __restrict__ w_n2, const float* __restrict__ conv_w,
        const float* __restrict__ wv1,
        unsigned short* __restrict__ Wt0, unsigned short* __restrict__ Wt1,
        unsigned short* __restrict__ Wtv)
{
    int idx = blockIdx.x * 256 + threadIdx.x;
    if (idx >= 9216) return;
    const float* Wm; unsigned short* Wo; int C; int rem;
    if (idx < 2048){ Wm = w_n2; Wo = Wt0; C = 128; rem = idx; }
    else if (idx < 8192){
        int m2 = (idx - 2048) >> 11; rem = (idx - 2048) & 2047;
        Wm = conv_w + (size_t)m2 * 16384; Wo = Wt1 + (size_t)m2 * 16384; C = 128;
    } else { rem = idx - 8192; Wm = wv1; Wo = Wtv; C = 64; }
    int c = rem >> 4, kg = rem & 15;
    unsigned int pk[4];
    #pragma unroll
    for (int j = 0; j < 4; ++j){
        float a = Wm[(size_t)(kg*8 + j*2    ) * C + c];
        float b = Wm[(size_t)(kg*8 + j*2 + 1) * C + c];
        pk[j] = (unsigned int)f2bf(a) | ((unsigned int)f2bf(b) << 16);
    }
    *(uint4*)(Wo + (size_t)c * 128 + kg * 8) = make_uint4(pk[0], pk[1], pk[2], pk[3]);
}

// ----------------- node encoder stage 1: hid(bf16) = relu(x@w1+b1), K=32 -----------------
__global__ __launch_bounds__(256) void enc1_kernel(
        const float* __restrict__ x, const float* __restrict__ w1, const float* __restrict__ b1,
        unsigned short* __restrict__ hid, int n)
{
    __shared__ float As[32][68];
    __shared__ float Bs[32][128];
    int t = threadIdx.x;
    int m0 = blockIdx.x * 64;
    int tm = t >> 4, tn = t & 15;

    #pragma unroll
    for (int i = 0; i < 2; ++i){
        int f = i * 256 + t;
        int row = f >> 3, kq = f & 7;
        int gr = m0 + row; if (gr > n - 1) gr = n - 1;
        float4 v = *(const float4*)(x + (size_t)gr * 32 + kq * 4);
        As[kq*4+0][row] = v.x; As[kq*4+1][row] = v.y; As[kq*4+2][row] = v.z; As[kq*4+3][row] = v.w;
    }
    #pragma unroll
    for (int i = 0; i < 4; ++i){
        int f = i * 256 + t;
        int kk = f >> 5, nq = f & 31;
        *(float4*)&Bs[kk][nq*4] = *(const float4*)(w1 + (size_t)kk * 128 + nq * 4);
    }
    __syncthreads();

    float acc[4][8];
    #pragma unroll
    for (int i = 0; i < 4; ++i)
        #pragma unroll
        for (int j = 0; j < 8; ++j) acc[i][j] = 0.f;

    #pragma unroll 4
    for (int k = 0; k < 32; ++k){
        float a[4], b[8];
        *(float4*)&a[0] = *(float4*)&As[k][tm*4];
        *(float4*)&b[0] = *(float4*)&Bs[k][tn*8];
        *(float4*)&b[4] = *(float4*)&Bs[k][tn*8+4];
        #pragma unroll
        for (int i = 0; i < 4; ++i)
            #pragma unroll
            for (int j = 0; j < 8; ++j) acc[i][j] = fmaf(a[i], b[j], acc[i][j]);
    }

    float bb[8];
    *(float4*)&bb[0] = *(const float4*)(b1 + tn*8);
    *(float4*)&bb[4] = *(const float4*)(b1 + tn*8 + 4);
    #pragma unroll
    for (int i = 0; i < 4; ++i){
        int node = m0 + tm*4 + i;
        if (node < n){
            float o[8];
            #pragma unroll
            for (int j = 0; j < 8; ++j) o[j] = fmaxf(acc[i][j] + bb[j], 0.f);
            uint4 pk;
            pk.x = (unsigned int)f2bf(o[0]) | ((unsigned int)f2bf(o[1]) << 16);
            pk.y = (unsigned int)f2bf(o[2]) | ((unsigned int)f2bf(o[3]) << 16);
            pk.z = (unsigned int)f2bf(o[4]) | ((unsigned int)f2bf(o[5]) << 16);
            pk.w = (unsigned int)f2bf(o[6]) | ((unsigned int)f2bf(o[7]) << 16);
            *(uint4*)(hid + (size_t)node*HC + tn*8) = pk;
        }
    }
}

// ----------------- MFMA GEMM -----------------
// ATT=false: C(bf16) = A@W + bias.  ATT=true: C8(fp8 e4m3) = A@W, + fused att dots.
template<bool ATT>
__global__ __launch_bounds__(256) void gemm_mfma_kernel(
        const unsigned short* __restrict__ A, const unsigned short* __restrict__ Wt,
        const float* __restrict__ bias,
        const float* __restrict__ att_s, const float* __restrict__ att_d,
        unsigned short* __restrict__ Cb, unsigned char* __restrict__ C8,
        float* __restrict__ asrc, float* __restrict__ adst, int n)
{
    __shared__ float lds[4][16][132];
    int t = threadIdx.x;
    int w = t >> 6, l = t & 63;
    int lane15 = l & 15, lanehi = l >> 4;
    int m0 = blockIdx.x * 64 + w * 16;

    f32x4 acc[8];
    #pragma unroll
    for (int ct = 0; ct < 8; ++ct) acc[ct] = (f32x4){0.f, 0.f, 0.f, 0.f};

    int ar = m0 + lane15; if (ar > n - 1) ar = n - 1;
    const unsigned short* Arow = A + (size_t)ar * HC;

    #pragma unroll
    for (int kc = 0; kc < 4; ++kc){
        bf16x8 af = *reinterpret_cast<const bf16x8*>(Arow + kc * 32 + lanehi * 8);
        #pragma unroll
        for (int ct = 0; ct < 8; ++ct){
            bf16x8 bf = *reinterpret_cast<const bf16x8*>(
                Wt + (size_t)(ct * 16 + lane15) * HC + kc * 32 + lanehi * 8);
            acc[ct] = __builtin_amdgcn_mfma_f32_16x16x32_bf16(af, bf, acc[ct], 0, 0, 0);
        }
    }

    if (ATT){
        float ats[8], atd[8];
        #pragma unroll
        for (int ct = 0; ct < 8; ++ct){
            ats[ct] = att_s[ct * 16 + lane15];
            atd[ct] = att_d[ct * 16 + lane15];
        }
        #pragma unroll
        for (int r = 0; r < 4; ++r){
            float sa0 = 0.f, sd0 = 0.f, sa1 = 0.f, sd1 = 0.f;
            #pragma unroll
            for (int ct = 0; ct < 4; ++ct){
                sa0 = fmaf(acc[ct][r], ats[ct], sa0);
                sd0 = fmaf(acc[ct][r], atd[ct], sd0);
            }
            #pragma unroll
            for (int ct = 4; ct < 8; ++ct){
                sa1 = fmaf(acc[ct][r], ats[ct], sa1);
                sd1 = fmaf(acc[ct][r], atd[ct], sd1);
            }
            #pragma unroll
            for (int o = 1; o < 16; o <<= 1){
                sa0 += __shfl_xor(sa0, o); sd0 += __shfl_xor(sd0, o);
                sa1 += __shfl_xor(sa1, o); sd1 += __shfl_xor(sd1, o);
            }
            int node = m0 + lanehi * 4 + r;
            if (lane15 == 0 && node < n){
                asrc[(size_t)node * 2]     = sa0;
                adst[(size_t)node * 2]     = sd0;
                asrc[(size_t)node * 2 + 1] = sa1;
                adst[(size_t)node * 2 + 1] = sd1;
            }
        }
    }

    float bb[8];
    #pragma unroll
    for (int ct = 0; ct < 8; ++ct) bb[ct] = ATT ? 0.f : bias[ct * 16 + lane15];
    #pragma unroll
    for (int ct = 0; ct < 8; ++ct)
        #pragma unroll
        for (int r = 0; r < 4; ++r)
            lds[w][lanehi * 4 + r][ct * 16 + lane15] = acc[ct][r] + bb[ct];
    __syncthreads();

    int row = lane15, cb = lanehi;
    int node = m0 + row;
    if (node < n){
        if (!ATT){
            #pragma unroll
            for (int q = 0; q < 4; ++q){
                float o[8];
                *(float4*)&o[0] = *(float4*)&lds[w][row][cb * 32 + q * 8];
                *(float4*)&o[4] = *(float4*)&lds[w][row][cb * 32 + q * 8 + 4];
                uint4 pk;
                pk.x = (unsigned int)f2bf(o[0]) | ((unsigned int)f2bf(o[1]) << 16);
                pk.y = (unsigned int)f2bf(o[2]) | ((unsigned int)f2bf(o[3]) << 16);
                pk.z = (unsigned int)f2bf(o[4]) | ((unsigned int)f2bf(o[5]) << 16);
                pk.w = (unsigned int)f2bf(o[6]) | ((unsigned int)f2bf(o[7]) << 16);
                *(uint4*)(Cb + (size_t)node * HC + cb * 32 + q * 8) = pk;
            }
        } else {
            unsigned int words[8];
            #pragma unroll
            for (int gq = 0; gq < 8; ++gq){
                float4 v = *(float4*)&lds[w][row][cb * 32 + gq * 4];
                unsigned int r = __builtin_amdgcn_cvt_pk_fp8_f32(v.x, v.y, 0, 0);
                r = __builtin_amdgcn_cvt_pk_fp8_f32(v.z, v.w, r, 1);
                words[gq] = r;
            }
            *(uint4*)(C8 + (size_t)node * HC + cb * 32)      = make_uint4(words[0], words[1], words[2], words[3]);
            *(uint4*)(C8 + (size_t)node * HC + cb * 32 + 16) = make_uint4(words[4], words[5], words[6], words[7]);
        }
    }
}

// ----------------- aggregation: 4 nodes/block (1 wave each, shfl-broadcast, no barriers) --------
// h' gathered as fp8 e4m3 (128 B/row); coef exp computed once/edge by owning lane.
__global__ __launch_bounds__(256) void aggregate_kernel(
        const unsigned char* __restrict__ h8, const float* __restrict__ asrc,
        const float* __restrict__ adst,
        const int* __restrict__ rowptr, const int* __restrict__ colsrc,
        const float* __restrict__ bias, unsigned short* __restrict__ hout, int n)
{
    int i = blockIdx.x * 4 + (threadIdx.x >> 6);
    if (i >= n) return;
    int t = threadIdx.x & 63;
    int head = t >> 5;
    float2 adv = *(const float2*)(adst + (size_t)i * 2);
    float2 asv = *(const float2*)(asrc + (size_t)i * 2);
    float ads = head ? adv.y : adv.x;
    float exs = __expf(lrelu((head ? asv.y : asv.x) + ads));   // self loop
    unsigned int hv = *(const unsigned short*)(h8 + (size_t)i * HC + t * 2);
    float acc0 = exs * __builtin_amdgcn_cvt_f32_fp8(hv, 0);
    float acc1 = exs * __builtin_amdgcn_cvt_f32_fp8(hv, 1);
    float D = exs;

    int e  = rowptr[i];
    int e1 = rowptr[i + 1];
    while (e < e1){
        int m = e1 - e; if (m > 64) m = 64;
        int sl = 0; float ex0 = 0.f, ex1 = 0.f;
        if (t < m){
            sl = colsrc[e + t];                       // coalesced
            float2 as = *(const float2*)(asrc + (size_t)sl * 2);
            ex0 = __expf(lrelu(as.x + adv.x));
            ex1 = __expf(lrelu(as.y + adv.y));
        }
        int j = 0;
        for (; j + 8 <= m; j += 8){
            int s[8]; float c[8];
            #pragma unroll
            for (int u = 0; u < 8; ++u){
                s[u] = __shfl(sl, j + u);
                float c0 = __shfl(ex0, j + u);
                float c1 = __shfl(ex1, j + u);
                c[u] = head ? c1 : c0;
            }
            unsigned int v[8];
            #pragma unroll
            for (int u = 0; u < 8; ++u)
                v[u] = *(const unsigned short*)(h8 + (size_t)s[u] * HC + t * 2);
            #pragma unroll
            for (int u = 0; u < 8; ++u){
                acc0 = fmaf(c[u], __builtin_amdgcn_cvt_f32_fp8(v[u], 0), acc0);
                acc1 = fmaf(c[u], __builtin_amdgcn_cvt_f32_fp8(v[u], 1), acc1);
                D += c[u];
            }
        }
        for (; j < m; ++j){
            int s = __shfl(sl, j);
            float c0 = __shfl(ex0, j), c1 = __shfl(ex1, j);
            float c = head ? c1 : c0;
            unsigned int v = *(const unsigned short*)(h8 + (size_t)s * HC + t * 2);
            acc0 = fmaf(c, __builtin_amdgcn_cvt_f32_fp8(v, 0), acc0);
            acc1 = fmaf(c, __builtin_amdgcn_cvt_f32_fp8(v, 1), acc1);
            D += c;
        }
        e += m;
    }
    float rD = 1.0f / D;
    float o0 = fmaxf(acc0 * rD + bias[2*t],     0.f);
    float o1 = fmaxf(acc1 * rD + bias[2*t + 1], 0.f);
    ((unsigned int*)hout)[(size_t)i * 64 + t] =
        (unsigned int)f2bf(o0) | ((unsigned int)f2bf(o1) << 16);
}

// ----------------- graph mean: two-stage, bf16 input -----------------
__global__ __launch_bounds__(256) void mean_part_kernel(
        const unsigned short* __restrict__ h, float* __restrict__ partial, int n)
{
    int t = threadIdx.x;
    int cq = t & 31;
    int rl = t >> 5;
    float4 acc = make_float4(0.f, 0.f, 0.f, 0.f);
    for (int i = blockIdx.x * 8 + rl; i < n; i += gridDim.x * 8){
        uint2 v = *(const uint2*)(h + (size_t)i * HC + cq * 4);
        acc.x += bf_lo(v.x); acc.y += bf_hi(v.x);
        acc.z += bf_lo(v.y); acc.w += bf_hi(v.y);
    }
    __shared__ float4 red[256];
    red[t] = acc;
    __syncthreads();
    if (t < 128){
        float4 o = red[t + 128];
        red[t].x += o.x; red[t].y += o.y; red[t].z += o.z; red[t].w += o.w;
    }
    __syncthreads();
    if (t < 64){
        float4 o = red[t + 64];
        red[t].x += o.x; red[t].y += o.y; red[t].z += o.z; red[t].w += o.w;
    }
    __syncthreads();
    if (t < 32){
        float4 a = red[t], b = red[t + 32];
        float4 s = make_float4(a.x + b.x, a.y + b.y, a.z + b.z, a.w + b.w);
        *(float4*)(partial + (size_t)blockIdx.x * HC + t * 4) = s;
    }
}

__global__ __launch_bounds__(256) void mean_fin_kernel(
        const float* __restrict__ partial, float* __restrict__ g, int nb)
{
    int t = threadIdx.x;
    int cq = t & 31, b0 = t >> 5;
    float4 acc = make_float4(0.f, 0.f, 0.f, 0.f);
    for (int b = b0; b < nb; b += 8){
        float4 v = *(const float4*)(partial + (size_t)b * HC + cq * 4);
        acc.x += v.x; acc.y += v.y; acc.z += v.z; acc.w += v.w;
    }
    __shared__ float4 red[256];
    red[t] = acc;
    __syncthreads();
    if (t < 128){
        float4 o = red[t + 128];
        red[t].x += o.x; red[t].y += o.y; red[t].z += o.z; red[t].w += o.w;
    }
    __syncthreads();
    if (t < 64){
        float4 o = red[t + 64];
        red[t].x += o.x; red[t].y += o.y; red[t].z += o.z; red[t].w += o.w;
    }
    __syncthreads();
    if (t < 32){
        float4 a = red[t], b = red[t + 32];
        float4 s = make_float4(a.x + b.x, a.y + b.y, a.z + b.z, a.w + b.w);
        *(float4*)(g + t * 4) = s;
    }
}

// ----------------- vuln head, MFMA -----------------
__global__ __launch_bounds__(256) void vuln_mfma_kernel(
        const unsigned short* __restrict__ h, const unsigned short* __restrict__ Wtv,
        const float* __restrict__ bv1, const float* __restrict__ wv2,
        const float* __restrict__ bv2, float* __restrict__ out, int n)
{
    int t = threadIdx.x;
    int w = t >> 6, l = t & 63;
    int lane15 = l & 15, lanehi = l >> 4;
    int m0 = blockIdx.x * 64 + w * 16;

    f32x4 acc[4];
    #pragma unroll
    for (int ct = 0; ct < 4; ++ct) acc[ct] = (f32x4){0.f, 0.f, 0.f, 0.f};

    int ar = m0 + lane15; if (ar > n - 1) ar = n - 1;
    const unsigned short* Arow = h + (size_t)ar * HC;

    #pragma unroll
    for (int kc = 0; kc < 4; ++kc){
        bf16x8 af = *reinterpret_cast<const bf16x8*>(Arow + kc * 32 + lanehi * 8);
        #pragma unroll
        for (int ct = 0; ct < 4; ++ct){
            bf16x8 bf = *reinterpret_cast<const bf16x8*>(
                Wtv + (size_t)(ct * 16 + lane15) * HC + kc * 32 + lanehi * 8);
            acc[ct] = __builtin_amdgcn_mfma_f32_16x16x32_bf16(af, bf, acc[ct], 0, 0, 0);
        }
    }

    float bb[4], wv[4];
    #pragma unroll
    for (int ct = 0; ct < 4; ++ct){
        bb[ct] = bv1[ct * 16 + lane15];
        wv[ct] = wv2[ct * 16 + lane15];
    }
    float bv2v = bv2[0];
    #pragma unroll
    for (int r = 0; r < 4; ++r){
        float s = 0.f;
        #pragma unroll
        for (int ct = 0; ct < 4; ++ct)
            s = fmaf(fmaxf(acc[ct][r] + bb[ct], 0.f), wv[ct], s);
        #pragma unroll
        for (int o = 1; o < 16; o <<= 1) s += __shfl_xor(s, o);
        int node = m0 + lanehi * 4 + r;
        if (lane15 == 0 && node < n)
            out[1 + node] = 1.0f / (1.0f + __expf(-(s + bv2v)));
    }
}

// ----------------- path head (1 block) -----------------
__global__ __launch_bounds__(128) void path_kernel(
        const unsigned short* __restrict__ h, const float* __restrict__ g,
        const float* __restrict__ wp1, const float* __restrict__ bp1,
        const float* __restrict__ wp2, const float* __restrict__ bp2,
        const float* __restrict__ wp3, const float* __restrict__ bp3,
        float* __restrict__ out, int n)
{
    __shared__ float pc[256];
    __shared__ float p1[HC];
    __shared__ float p2[64];
    int t = threadIdx.x;              // 128
    pc[t]       = bf1(h[t]);          // h[0,:]
    pc[128 + t] = g[t] * (1.0f / (float)n);
    __syncthreads();
    float a = bp1[t];
    for (int k = 0; k < 256; ++k) a = fmaf(pc[k], wp1[k * HC + t], a);
    p1[t] = fmaxf(a, 0.f);
    __syncthreads();
    if (t < 64){
        float a2 = bp2[t];
        for (int k = 0; k < HC; ++k) a2 = fmaf(p1[k], wp2[k * 64 + t], a2);
        p2[t] = fmaxf(a2, 0.f);
    }
    __syncthreads();
    if (t == 0){
        float a3 = bp3[0];
        for (int k = 0; k < 64; ++k) a3 = fmaf(p2[k], wp3[k], a3);
        out[0] = 1.0f / (1.0f + __expf(-a3));
        out[1 + n] = 0.f;             // esc = 0
    }
}

extern "C" void kernel_launch(void* const* d_in, const int* in_sizes, int n_in,
                              void* d_out, int out_size, void* d_ws, size_t ws_size,
                              hipStream_t stream)
{
    const float* x    = (const float*)d_in[0];
    const int*   ei   = (const int*)d_in[1];
    const float* w_n1 = (const float*)d_in[3];
    const float* b_n1 = (const float*)d_in[4];
    const float* w_n2 = (const float*)d_in[5];
    const float* b_n2 = (const float*)d_in[6];
    const float* conv_w = (const float*)d_in[9];
    const float* att_s  = (const float*)d_in[10];
    const float* att_d  = (const float*)d_in[11];
    const float* conv_b = (const float*)d_in[12];
    const float* wp1 = (const float*)d_in[13];
    const float* bp1 = (const float*)d_in[14];
    const float* wp2 = (const float*)d_in[15];
    const float* bp2 = (const float*)d_in[16];
    const float* wp3 = (const float*)d_in[17];
    const float* bp3 = (const float*)d_in[18];
    const float* wv1 = (const float*)d_in[19];
    const float* bv1 = (const float*)d_in[20];
    const float* wv2 = (const float*)d_in[21];
    const float* bv2 = (const float*)d_in[22];

    const int N = in_sizes[0] / 32;
    const int E = in_sizes[1] / 2;
    float* out = (float*)d_out;

    char* ws = (char*)d_ws;
    size_t off = 0;
    auto take = [&](size_t bytes) -> char* {
        char* p = ws + off;
        off += (bytes + 255) & ~(size_t)255;
        return p;
    };
    unsigned short* hA = (unsigned short*)take((size_t)N * HC * 2);  // bf16 node features
    unsigned short* hB = (unsigned short*)take((size_t)N * HC * 2);  // bf16 enc hidden
    unsigned char*  h8 = (unsigned char*)take((size_t)N * HC);      // fp8 h' for gathers
    float* asrc  = (float*)take((size_t)N * 2 * 4);
    float* adst  = (float*)take((size_t)N * 2 * 4);
    int*   rowptr= (int*)take((size_t)(N + 1) * 4);
    int*   cnt   = (int*)take((size_t)N * 4);
    int*   rank  = (int*)take((size_t)E * 4);
    int*   colsrc= (int*)take((size_t)E * 4);
    float* g     = (float*)take(HC * 4);
    unsigned short* Wt0 = (unsigned short*)take(16384 * 2);             // w_n2^T bf16
    unsigned short* Wt1 = (unsigned short*)take((size_t)3 * 16384 * 2); // conv_w^T bf16
    unsigned short* Wtv = (unsigned short*)take(8192 * 2);              // wv1^T bf16 (64x128)
    const int MB = 64;
    float* mpart = (float*)take((size_t)MB * HC * 4);
    int nb = (N + 1023) / 1024;
    int*   bsum  = (int*)take((size_t)((nb + 63) & ~63) * 4);
    int*   boff  = (int*)take((size_t)((nb + 63) & ~63) * 4);

    // --- CSR build (dst-sorted; reused across the 3 layers) ---
    hipMemsetAsync(cnt, 0, (size_t)N * 4, stream);
    count_kernel<<<(E + 255) / 256, 256, 0, stream>>>(ei, cnt, rank, E);
    scan_part_kernel<<<nb, 256, 0, stream>>>(cnt, bsum, N);
    scan_top_kernel<<<1, 64, 0, stream>>>(bsum, boff, rowptr, nb, N);
    scan_fin_kernel<<<nb, 256, 0, stream>>>(cnt, boff, rowptr, N);
    scatter_kernel<<<(E + 2047) / 2048, 256, 0, stream>>>(ei, rowptr, rank, colsrc, E);

    // --- weights -> transposed bf16 for MFMA B fragments (one dispatch) ---
    wtrans_all_kernel<<<36, 256, 0, stream>>>(w_n2, conv_w, wv1, Wt0, Wt1, Wtv);

    int nblk64 = (N + 63) / 64;
    // node encoder: hid (hB bf16) = relu(x@w1+b1); hA = hid@w2 + b2 (bf16, MFMA)
    enc1_kernel<<<nblk64, 256, 0, stream>>>(x, w_n1, b_n1, hB, N);
    gemm_mfma_kernel<false><<<nblk64, 256, 0, stream>>>(
        hB, Wt0, b_n2, nullptr, nullptr, hA, nullptr, nullptr, nullptr, N);

    for (int l = 0; l < 3; ++l){
        gemm_mfma_kernel<true><<<nblk64, 256, 0, stream>>>(
            hA, Wt1 + (size_t)l * 16384, nullptr,
            att_s + (size_t)l * HC, att_d + (size_t)l * HC,
            nullptr, h8, asrc, adst, N);
        aggregate_kernel<<<(N + 3) / 4, 256, 0, stream>>>(
            h8, asrc, adst, rowptr, colsrc, conv_b + (size_t)l * HC, hA, N);
    }

    mean_part_kernel<<<MB, 256, 0, stream>>>(hA, mpart, N);
    mean_fin_kernel<<<1, 256, 0, stream>>>(mpart, g, MB);
    vuln_mfma_kernel<<<nblk64, 256, 0, stream>>>(hA, Wtv, bv1, wv2, bv2, out, N);
    path_kernel<<<1, 128, 0, stream>>>(hA, g, wp1, bp1, wp2, bp2, wp3, bp3, out, N);
}

// Round 14
// 306.424 us; speedup vs baseline: 1.6108x; 1.0618x over previous
//
#include <hip/hip_runtime.h>
#include <math.h>

#define HC 128
#define NSLOPE 0.2f

using bf16x8 = __attribute__((ext_vector_type(8))) short;
using f32x4  = __attribute__((ext_vector_type(4))) float;

__device__ __forceinline__ float lrelu(float v){ return v > 0.f ? v : NSLOPE * v; }

// bf16 round-to-nearest-even pack / unpack
__device__ __forceinline__ unsigned short f2bf(float f){
    unsigned int b = __float_as_uint(f);
    b += 0x7FFFu + ((b >> 16) & 1u);
    return (unsigned short)(b >> 16);
}
__device__ __forceinline__ float bf_lo(unsigned int v){ return __uint_as_float(v << 16); }
__device__ __forceinline__ float bf_hi(unsigned int v){ return __uint_as_float(v & 0xFFFF0000u); }
__device__ __forceinline__ float bf1(unsigned short v){ return __uint_as_float((unsigned int)v << 16); }

// ----------------- CSR build (dst-sorted) -----------------
__global__ void count_kernel(const int* __restrict__ ei, int* __restrict__ cnt,
                             int* __restrict__ rank, int E){
    int e = blockIdx.x * blockDim.x + threadIdx.x;
    if (e < E) rank[e] = atomicAdd(&cnt[ei[E + e]], 1);
}

__global__ __launch_bounds__(256) void scan_part_kernel(
        const int* __restrict__ deg, int* __restrict__ bsum, int n)
{
    int t = threadIdx.x, lane = t & 63, wid = t >> 6;
    int base = blockIdx.x * 1024 + t * 4;
    int s = 0;
    #pragma unroll
    for (int j = 0; j < 4; ++j){ int i = base + j; if (i < n) s += deg[i]; }
    #pragma unroll
    for (int o = 1; o < 64; o <<= 1) s += __shfl_xor(s, o);
    __shared__ int red[4];
    if (lane == 0) red[wid] = s;
    __syncthreads();
    if (t == 0) bsum[blockIdx.x] = red[0] + red[1] + red[2] + red[3];
}

__global__ __launch_bounds__(64) void scan_top_kernel(
        const int* __restrict__ bsum, int* __restrict__ boff, int* __restrict__ rowptr,
        int nb, int n)
{
    int t = threadIdx.x;
    int v = (t < nb) ? bsum[t] : 0;
    int incl = v;
    #pragma unroll
    for (int o = 1; o < 64; o <<= 1){ int u = __shfl_up(incl, o); if (t >= o) incl += u; }
    if (t < nb) boff[t] = incl - v;
    if (t == 63) rowptr[n] = incl;
}

__global__ __launch_bounds__(256) void scan_fin_kernel(
        const int* __restrict__ deg, const int* __restrict__ boff,
        int* __restrict__ rowptr, int n)
{
    int t = threadIdx.x, lane = t & 63, wid = t >> 6;
    int base = blockIdx.x * 1024 + t * 4;
    int d[4]; int s = 0;
    #pragma unroll
    for (int j = 0; j < 4; ++j){ int i = base + j; d[j] = (i < n) ? deg[i] : 0; s += d[j]; }
    int incl = s;
    #pragma unroll
    for (int o = 1; o < 64; o <<= 1){ int u = __shfl_up(incl, o); if (lane >= o) incl += u; }
    __shared__ int wsum[4];
    if (lane == 63) wsum[wid] = incl;
    __syncthreads();
    int off = boff[blockIdx.x] + (incl - s);
    for (int w = 0; w < wid; ++w) off += wsum[w];
    #pragma unroll
    for (int j = 0; j < 4; ++j){
        int i = base + j;
        if (i < n) rowptr[i] = off;
        off += d[j];
    }
}

// stateless scatter, ILP=8
__global__ __launch_bounds__(256) void scatter_kernel(
        const int* __restrict__ ei, const int* __restrict__ rowptr,
        const int* __restrict__ rank, int* __restrict__ colsrc, int E)
{
    int b = blockIdx.x * 2048 + threadIdx.x;
    int e[8]; bool v[8]; int d[8], s[8], r[8];
    #pragma unroll
    for (int i = 0; i < 8; ++i){ e[i] = b + i * 256; v[i] = e[i] < E; }
    #pragma unroll
    for (int i = 0; i < 8; ++i) if (v[i]){ d[i] = ei[E + e[i]]; s[i] = ei[e[i]]; r[i] = rank[e[i]]; }
    #pragma unroll
    for (int i = 0; i < 8; ++i) if (v[i]) colsrc[rowptr[d[i]] + r[i]] = s[i];
}

// ----------------- all weight transposes -> bf16 Wt[c][K=128], one dispatch -----------------
__global__ __launch_bounds__(256) void wtrans_all_kernel(
        const float* __restrict__ w_n2, const float* __restrict__ conv_w,
        const float* __restrict__ wv1,
        unsigned short* __restrict__ Wt0, unsigned short* __restrict__ Wt1,
        unsigned short* __restrict__ Wtv)
{
    int idx = blockIdx.x * 256 + threadIdx.x;
    if (idx >= 9216) return;
    const float* Wm; unsigned short* Wo; int C; int rem;
    if (idx < 2048){ Wm = w_n2; Wo = Wt0; C = 128; rem = idx; }
    else if (idx < 8192){
        int m2 = (idx - 2048) >> 11; rem = (idx - 2048) & 2047;
        Wm = conv_w + (size_t)m2 * 16384; Wo = Wt1 + (size_t)m2 * 16384; C = 128;
    } else { rem = idx - 8192; Wm = wv1; Wo = Wtv; C = 64; }
    int c = rem >> 4, kg = rem & 15;
    unsigned int pk[4];
    #pragma unroll
    for (int j = 0; j < 4; ++j){
        float a = Wm[(size_t)(kg*8 + j*2    ) * C + c];
        float b = Wm[(size_t)(kg*8 + j*2 + 1) * C + c];
        pk[j] = (unsigned int)f2bf(a) | ((unsigned int)f2bf(b) << 16);
    }
    *(uint4*)(Wo + (size_t)c * 128 + kg * 8) = make_uint4(pk[0], pk[1], pk[2], pk[3]);
}

// ----------------- node encoder stage 1: hid(bf16) = relu(x@w1+b1), K=32 -----------------
__global__ __launch_bounds__(256) void enc1_kernel(
        const float* __restrict__ x, const float* __restrict__ w1, const float* __restrict__ b1,
        unsigned short* __restrict__ hid, int n)
{
    __shared__ float As[32][68];
    __shared__ float Bs[32][128];
    int t = threadIdx.x;
    int m0 = blockIdx.x * 64;
    int tm = t >> 4, tn = t & 15;

    #pragma unroll
    for (int i = 0; i < 2; ++i){
        int f = i * 256 + t;
        int row = f >> 3, kq = f & 7;
        int gr = m0 + row; if (gr > n - 1) gr = n - 1;
        float4 v = *(const float4*)(x + (size_t)gr * 32 + kq * 4);
        As[kq*4+0][row] = v.x; As[kq*4+1][row] = v.y; As[kq*4+2][row] = v.z; As[kq*4+3][row] = v.w;
    }
    #pragma unroll
    for (int i = 0; i < 4; ++i){
        int f = i * 256 + t;
        int kk = f >> 5, nq = f & 31;
        *(float4*)&Bs[kk][nq*4] = *(const float4*)(w1 + (size_t)kk * 128 + nq * 4);
    }
    __syncthreads();

    float acc[4][8];
    #pragma unroll
    for (int i = 0; i < 4; ++i)
        #pragma unroll
        for (int j = 0; j < 8; ++j) acc[i][j] = 0.f;

    #pragma unroll 4
    for (int k = 0; k < 32; ++k){
        float a[4], b[8];
        *(float4*)&a[0] = *(float4*)&As[k][tm*4];
        *(float4*)&b[0] = *(float4*)&Bs[k][tn*8];
        *(float4*)&b[4] = *(float4*)&Bs[k][tn*8+4];
        #pragma unroll
        for (int i = 0; i < 4; ++i)
            #pragma unroll
            for (int j = 0; j < 8; ++j) acc[i][j] = fmaf(a[i], b[j], acc[i][j]);
    }

    float bb[8];
    *(float4*)&bb[0] = *(const float4*)(b1 + tn*8);
    *(float4*)&bb[4] = *(const float4*)(b1 + tn*8 + 4);
    #pragma unroll
    for (int i = 0; i < 4; ++i){
        int node = m0 + tm*4 + i;
        if (node < n){
            float o[8];
            #pragma unroll
            for (int j = 0; j < 8; ++j) o[j] = fmaxf(acc[i][j] + bb[j], 0.f);
            uint4 pk;
            pk.x = (unsigned int)f2bf(o[0]) | ((unsigned int)f2bf(o[1]) << 16);
            pk.y = (unsigned int)f2bf(o[2]) | ((unsigned int)f2bf(o[3]) << 16);
            pk.z = (unsigned int)f2bf(o[4]) | ((unsigned int)f2bf(o[5]) << 16);
            pk.w = (unsigned int)f2bf(o[6]) | ((unsigned int)f2bf(o[7]) << 16);
            *(uint4*)(hid + (size_t)node*HC + tn*8) = pk;
        }
    }
}

// ----------------- MFMA GEMM -----------------
// ATT=false: C(bf16) = A@W + bias.  ATT=true: C8(fp8 e4m3) = A@W, + fused att dots.
template<bool ATT>
__global__ __launch_bounds__(256) void gemm_mfma_kernel(
        const unsigned short* __restrict__ A, const unsigned short* __restrict__ Wt,
        const float* __restrict__ bias,
        const float* __restrict__ att_s, const float* __restrict__ att_d,
        unsigned short* __restrict__ Cb, unsigned char* __restrict__ C8,
        float* __restrict__ asrc, float* __restrict__ adst, int n)
{
    __shared__ float lds[4][16][132];
    int t = threadIdx.x;
    int w = t >> 6, l = t & 63;
    int lane15 = l & 15, lanehi = l >> 4;
    int m0 = blockIdx.x * 64 + w * 16;

    f32x4 acc[8];
    #pragma unroll
    for (int ct = 0; ct < 8; ++ct) acc[ct] = (f32x4){0.f, 0.f, 0.f, 0.f};

    int ar = m0 + lane15; if (ar > n - 1) ar = n - 1;
    const unsigned short* Arow = A + (size_t)ar * HC;

    #pragma unroll
    for (int kc = 0; kc < 4; ++kc){
        bf16x8 af = *reinterpret_cast<const bf16x8*>(Arow + kc * 32 + lanehi * 8);
        #pragma unroll
        for (int ct = 0; ct < 8; ++ct){
            bf16x8 bf = *reinterpret_cast<const bf16x8*>(
                Wt + (size_t)(ct * 16 + lane15) * HC + kc * 32 + lanehi * 8);
            acc[ct] = __builtin_amdgcn_mfma_f32_16x16x32_bf16(af, bf, acc[ct], 0, 0, 0);
        }
    }

    if (ATT){
        float ats[8], atd[8];
        #pragma unroll
        for (int ct = 0; ct < 8; ++ct){
            ats[ct] = att_s[ct * 16 + lane15];
            atd[ct] = att_d[ct * 16 + lane15];
        }
        #pragma unroll
        for (int r = 0; r < 4; ++r){
            float sa0 = 0.f, sd0 = 0.f, sa1 = 0.f, sd1 = 0.f;
            #pragma unroll
            for (int ct = 0; ct < 4; ++ct){
                sa0 = fmaf(acc[ct][r], ats[ct], sa0);
                sd0 = fmaf(acc[ct][r], atd[ct], sd0);
            }
            #pragma unroll
            for (int ct = 4; ct < 8; ++ct){
                sa1 = fmaf(acc[ct][r], ats[ct], sa1);
                sd1 = fmaf(acc[ct][r], atd[ct], sd1);
            }
            #pragma unroll
            for (int o = 1; o < 16; o <<= 1){
                sa0 += __shfl_xor(sa0, o); sd0 += __shfl_xor(sd0, o);
                sa1 += __shfl_xor(sa1, o); sd1 += __shfl_xor(sd1, o);
            }
            int node = m0 + lanehi * 4 + r;
            if (lane15 == 0 && node < n){
                asrc[(size_t)node * 2]     = sa0;
                adst[(size_t)node * 2]     = sd0;
                asrc[(size_t)node * 2 + 1] = sa1;
                adst[(size_t)node * 2 + 1] = sd1;
            }
        }
    }

    float bb[8];
    #pragma unroll
    for (int ct = 0; ct < 8; ++ct) bb[ct] = ATT ? 0.f : bias[ct * 16 + lane15];
    #pragma unroll
    for (int ct = 0; ct < 8; ++ct)
        #pragma unroll
        for (int r = 0; r < 4; ++r)
            lds[w][lanehi * 4 + r][ct * 16 + lane15] = acc[ct][r] + bb[ct];
    __syncthreads();

    int row = lane15, cb = lanehi;
    int node = m0 + row;
    if (node < n){
        if (!ATT){
            #pragma unroll
            for (int q = 0; q < 4; ++q){
                float o[8];
                *(float4*)&o[0] = *(float4*)&lds[w][row][cb * 32 + q * 8];
                *(float4*)&o[4] = *(float4*)&lds[w][row][cb * 32 + q * 8 + 4];
                uint4 pk;
                pk.x = (unsigned int)f2bf(o[0]) | ((unsigned int)f2bf(o[1]) << 16);
                pk.y = (unsigned int)f2bf(o[2]) | ((unsigned int)f2bf(o[3]) << 16);
                pk.z = (unsigned int)f2bf(o[4]) | ((unsigned int)f2bf(o[5]) << 16);
                pk.w = (unsigned int)f2bf(o[6]) | ((unsigned int)f2bf(o[7]) << 16);
                *(uint4*)(Cb + (size_t)node * HC + cb * 32 + q * 8) = pk;
            }
        } else {
            unsigned int words[8];
            #pragma unroll
            for (int gq = 0; gq < 8; ++gq){
                float4 v = *(float4*)&lds[w][row][cb * 32 + gq * 4];
                unsigned int r = __builtin_amdgcn_cvt_pk_fp8_f32(v.x, v.y, 0, 0);
                r = __builtin_amdgcn_cvt_pk_fp8_f32(v.z, v.w, r, 1);
                words[gq] = r;
            }
            *(uint4*)(C8 + (size_t)node * HC + cb * 32)      = make_uint4(words[0], words[1], words[2], words[3]);
            *(uint4*)(C8 + (size_t)node * HC + cb * 32 + 16) = make_uint4(words[4], words[5], words[6], words[7]);
        }
    }
}

// ----------------- aggregation: 4 nodes/block, 2 edges/wave-iteration -----------------
// half-wave hw = t>>5 owns edge j+hw; lane covers 4 fp8 channels (uint load, 32 lanes = 128B row).
__global__ __launch_bounds__(256) void aggregate_kernel(
        const unsigned char* __restrict__ h8, const float* __restrict__ asrc,
        const float* __restrict__ adst,
        const int* __restrict__ rowptr, const int* __restrict__ colsrc,
        const float* __restrict__ bias, unsigned short* __restrict__ hout, int n)
{
    int i = blockIdx.x * 4 + (threadIdx.x >> 6);
    if (i >= n) return;
    int t = threadIdx.x & 63;
    int hw = t >> 5;              // which edge of the pair this half-wave processes
    int lc = t & 31;              // channels lc*4 .. lc*4+3
    int head = lc >> 4;           // lc*4 < 64 -> head0 else head1
    float2 adv = *(const float2*)(adst + (size_t)i * 2);
    float2 asv = *(const float2*)(asrc + (size_t)i * 2);
    // self loop: counted by half-wave 0 only
    float exs = __expf(lrelu((head ? asv.y : asv.x) + (head ? adv.y : adv.x)));
    float w0 = hw ? 0.f : exs;
    unsigned int hv = *(const unsigned int*)(h8 + (size_t)i * HC + lc * 4);
    float a0 = w0 * __builtin_amdgcn_cvt_f32_fp8(hv, 0);
    float a1 = w0 * __builtin_amdgcn_cvt_f32_fp8(hv, 1);
    float a2 = w0 * __builtin_amdgcn_cvt_f32_fp8(hv, 2);
    float a3 = w0 * __builtin_amdgcn_cvt_f32_fp8(hv, 3);
    float D = w0;

    int e  = rowptr[i];
    int e1 = rowptr[i + 1];
    while (e < e1){
        int m = e1 - e; if (m > 64) m = 64;
        int sl = 0; float ex0 = 0.f, ex1 = 0.f;
        if (t < m){
            sl = colsrc[e + t];                       // coalesced
            float2 as = *(const float2*)(asrc + (size_t)sl * 2);
            ex0 = __expf(lrelu(as.x + adv.x));
            ex1 = __expf(lrelu(as.y + adv.y));
        }
        int j = 0;
        for (; j + 8 <= m; j += 8){                   // 4 pairs -> 4 gathers in flight/half-wave
            int   s[4]; float c[4];
            #pragma unroll
            for (int u = 0; u < 4; ++u){
                int src = j + 2 * u + hw;
                s[u] = __shfl(sl, src);
                float c0 = __shfl(ex0, src);
                float c1 = __shfl(ex1, src);
                c[u] = head ? c1 : c0;
            }
            unsigned int v[4];
            #pragma unroll
            for (int u = 0; u < 4; ++u)
                v[u] = *(const unsigned int*)(h8 + (size_t)s[u] * HC + lc * 4);
            #pragma unroll
            for (int u = 0; u < 4; ++u){
                a0 = fmaf(c[u], __builtin_amdgcn_cvt_f32_fp8(v[u], 0), a0);
                a1 = fmaf(c[u], __builtin_amdgcn_cvt_f32_fp8(v[u], 1), a1);
                a2 = fmaf(c[u], __builtin_amdgcn_cvt_f32_fp8(v[u], 2), a2);
                a3 = fmaf(c[u], __builtin_amdgcn_cvt_f32_fp8(v[u], 3), a3);
                D += c[u];
            }
        }
        for (; j + 2 <= m; j += 2){
            int src = j + hw;
            int   s  = __shfl(sl, src);
            float c0 = __shfl(ex0, src);
            float c1 = __shfl(ex1, src);
            float c = head ? c1 : c0;
            unsigned int v = *(const unsigned int*)(h8 + (size_t)s * HC + lc * 4);
            a0 = fmaf(c, __builtin_amdgcn_cvt_f32_fp8(v, 0), a0);
            a1 = fmaf(c, __builtin_amdgcn_cvt_f32_fp8(v, 1), a1);
            a2 = fmaf(c, __builtin_amdgcn_cvt_f32_fp8(v, 2), a2);
            a3 = fmaf(c, __builtin_amdgcn_cvt_f32_fp8(v, 3), a3);
            D += c;
        }
        if (j < m){                                   // odd tail: half-wave 0 only
            int   s  = __shfl(sl, j);
            float c0 = __shfl(ex0, j);
            float c1 = __shfl(ex1, j);
            float c = head ? c1 : c0;
            if (hw == 0){
                unsigned int v = *(const unsigned int*)(h8 + (size_t)s * HC + lc * 4);
                a0 = fmaf(c, __builtin_amdgcn_cvt_f32_fp8(v, 0), a0);
                a1 = fmaf(c, __builtin_amdgcn_cvt_f32_fp8(v, 1), a1);
                a2 = fmaf(c, __builtin_amdgcn_cvt_f32_fp8(v, 2), a2);
                a3 = fmaf(c, __builtin_amdgcn_cvt_f32_fp8(v, 3), a3);
                D += c;
            }
        }
        e += m;
    }
    // combine the two half-waves
    a0 += __shfl_xor(a0, 32);
    a1 += __shfl_xor(a1, 32);
    a2 += __shfl_xor(a2, 32);
    a3 += __shfl_xor(a3, 32);
    D  += __shfl_xor(D, 32);
    if (hw == 0){
        float rD = 1.0f / D;
        float4 bb = *(const float4*)(bias + lc * 4);
        float o0 = fmaxf(a0 * rD + bb.x, 0.f);
        float o1 = fmaxf(a1 * rD + bb.y, 0.f);
        float o2 = fmaxf(a2 * rD + bb.z, 0.f);
        float o3 = fmaxf(a3 * rD + bb.w, 0.f);
        uint2 pk;
        pk.x = (unsigned int)f2bf(o0) | ((unsigned int)f2bf(o1) << 16);
        pk.y = (unsigned int)f2bf(o2) | ((unsigned int)f2bf(o3) << 16);
        *(uint2*)(hout + (size_t)i * HC + lc * 4) = pk;
    }
}

// ----------------- graph mean: two-stage, bf16 input -----------------
__global__ __launch_bounds__(256) void mean_part_kernel(
        const unsigned short* __restrict__ h, float* __restrict__ partial, int n)
{
    int t = threadIdx.x;
    int cq = t & 31;
    int rl = t >> 5;
    float4 acc = make_float4(0.f, 0.f, 0.f, 0.f);
    for (int i = blockIdx.x * 8 + rl; i < n; i += gridDim.x * 8){
        uint2 v = *(const uint2*)(h + (size_t)i * HC + cq * 4);
        acc.x += bf_lo(v.x); acc.y += bf_hi(v.x);
        acc.z += bf_lo(v.y); acc.w += bf_hi(v.y);
    }
    __shared__ float4 red[256];
    red[t] = acc;
    __syncthreads();
    if (t < 128){
        float4 o = red[t + 128];
        red[t].x += o.x; red[t].y += o.y; red[t].z += o.z; red[t].w += o.w;
    }
    __syncthreads();
    if (t < 64){
        float4 o = red[t + 64];
        red[t].x += o.x; red[t].y += o.y; red[t].z += o.z; red[t].w += o.w;
    }
    __syncthreads();
    if (t < 32){
        float4 a = red[t], b = red[t + 32];
        float4 s = make_float4(a.x + b.x, a.y + b.y, a.z + b.z, a.w + b.w);
        *(float4*)(partial + (size_t)blockIdx.x * HC + t * 4) = s;
    }
}

__global__ __launch_bounds__(256) void mean_fin_kernel(
        const float* __restrict__ partial, float* __restrict__ g, int nb)
{
    int t = threadIdx.x;
    int cq = t & 31, b0 = t >> 5;
    float4 acc = make_float4(0.f, 0.f, 0.f, 0.f);
    for (int b = b0; b < nb; b += 8){
        float4 v = *(const float4*)(partial + (size_t)b * HC + cq * 4);
        acc.x += v.x; acc.y += v.y; acc.z += v.z; acc.w += v.w;
    }
    __shared__ float4 red[256];
    red[t] = acc;
    __syncthreads();
    if (t < 128){
        float4 o = red[t + 128];
        red[t].x += o.x; red[t].y += o.y; red[t].z += o.z; red[t].w += o.w;
    }
    __syncthreads();
    if (t < 64){
        float4 o = red[t + 64];
        red[t].x += o.x; red[t].y += o.y; red[t].z += o.z; red[t].w += o.w;
    }
    __syncthreads();
    if (t < 32){
        float4 a = red[t], b = red[t + 32];
        float4 s = make_float4(a.x + b.x, a.y + b.y, a.z + b.z, a.w + b.w);
        *(float4*)(g + t * 4) = s;
    }
}

// ----------------- vuln head, MFMA -----------------
__global__ __launch_bounds__(256) void vuln_mfma_kernel(
        const unsigned short* __restrict__ h, const unsigned short* __restrict__ Wtv,
        const float* __restrict__ bv1, const float* __restrict__ wv2,
        const float* __restrict__ bv2, float* __restrict__ out, int n)
{
    int t = threadIdx.x;
    int w = t >> 6, l = t & 63;
    int lane15 = l & 15, lanehi = l >> 4;
    int m0 = blockIdx.x * 64 + w * 16;

    f32x4 acc[4];
    #pragma unroll
    for (int ct = 0; ct < 4; ++ct) acc[ct] = (f32x4){0.f, 0.f, 0.f, 0.f};

    int ar = m0 + lane15; if (ar > n - 1) ar = n - 1;
    const unsigned short* Arow = h + (size_t)ar * HC;

    #pragma unroll
    for (int kc = 0; kc < 4; ++kc){
        bf16x8 af = *reinterpret_cast<const bf16x8*>(Arow + kc * 32 + lanehi * 8);
        #pragma unroll
        for (int ct = 0; ct < 4; ++ct){
            bf16x8 bf = *reinterpret_cast<const bf16x8*>(
                Wtv + (size_t)(ct * 16 + lane15) * HC + kc * 32 + lanehi * 8);
            acc[ct] = __builtin_amdgcn_mfma_f32_16x16x32_bf16(af, bf, acc[ct], 0, 0, 0);
        }
    }

    float bb[4], wv[4];
    #pragma unroll
    for (int ct = 0; ct < 4; ++ct){
        bb[ct] = bv1[ct * 16 + lane15];
        wv[ct] = wv2[ct * 16 + lane15];
    }
    float bv2v = bv2[0];
    #pragma unroll
    for (int r = 0; r < 4; ++r){
        float s = 0.f;
        #pragma unroll
        for (int ct = 0; ct < 4; ++ct)
            s = fmaf(fmaxf(acc[ct][r] + bb[ct], 0.f), wv[ct], s);
        #pragma unroll
        for (int o = 1; o < 16; o <<= 1) s += __shfl_xor(s, o);
        int node = m0 + lanehi * 4 + r;
        if (lane15 == 0 && node < n)
            out[1 + node] = 1.0f / (1.0f + __expf(-(s + bv2v)));
    }
}

// ----------------- path head (1 block) -----------------
__global__ __launch_bounds__(128) void path_kernel(
        const unsigned short* __restrict__ h, const float* __restrict__ g,
        const float* __restrict__ wp1, const float* __restrict__ bp1,
        const float* __restrict__ wp2, const float* __restrict__ bp2,
        const float* __restrict__ wp3, const float* __restrict__ bp3,
        float* __restrict__ out, int n)
{
    __shared__ float pc[256];
    __shared__ float p1[HC];
    __shared__ float p2[64];
    int t = threadIdx.x;              // 128
    pc[t]       = bf1(h[t]);          // h[0,:]
    pc[128 + t] = g[t] * (1.0f / (float)n);
    __syncthreads();
    float a = bp1[t];
    for (int k = 0; k < 256; ++k) a = fmaf(pc[k], wp1[k * HC + t], a);
    p1[t] = fmaxf(a, 0.f);
    __syncthreads();
    if (t < 64){
        float a2 = bp2[t];
        for (int k = 0; k < HC; ++k) a2 = fmaf(p1[k], wp2[k * 64 + t], a2);
        p2[t] = fmaxf(a2, 0.f);
    }
    __syncthreads();
    if (t == 0){
        float a3 = bp3[0];
        for (int k = 0; k < 64; ++k) a3 = fmaf(p2[k], wp3[k], a3);
        out[0] = 1.0f / (1.0f + __expf(-a3));
        out[1 + n] = 0.f;             // esc = 0
    }
}

extern "C" void kernel_launch(void* const* d_in, const int* in_sizes, int n_in,
                              void* d_out, int out_size, void* d_ws, size_t ws_size,
                              hipStream_t stream)
{
    const float* x    = (const float*)d_in[0];
    const int*   ei   = (const int*)d_in[1];
    const float* w_n1 = (const float*)d_in[3];
    const float* b_n1 = (const float*)d_in[4];
    const float* w_n2 = (const float*)d_in[5];
    const float* b_n2 = (const float*)d_in[6];
    const float* conv_w = (const float*)d_in[9];
    const float* att_s  = (const float*)d_in[10];
    const float* att_d  = (const float*)d_in[11];
    const float* conv_b = (const float*)d_in[12];
    const float* wp1 = (const float*)d_in[13];
    const float* bp1 = (const float*)d_in[14];
    const float* wp2 = (const float*)d_in[15];
    const float* bp2 = (const float*)d_in[16];
    const float* wp3 = (const float*)d_in[17];
    const float* bp3 = (const float*)d_in[18];
    const float* wv1 = (const float*)d_in[19];
    const float* bv1 = (const float*)d_in[20];
    const float* wv2 = (const float*)d_in[21];
    const float* bv2 = (const float*)d_in[22];

    const int N = in_sizes[0] / 32;
    const int E = in_sizes[1] / 2;
    float* out = (float*)d_out;

    char* ws = (char*)d_ws;
    size_t off = 0;
    auto take = [&](size_t bytes) -> char* {
        char* p = ws + off;
        off += (bytes + 255) & ~(size_t)255;
        return p;
    };
    unsigned short* hA = (unsigned short*)take((size_t)N * HC * 2);  // bf16 node features
    unsigned short* hB = (unsigned short*)take((size_t)N * HC * 2);  // bf16 enc hidden
    unsigned char*  h8 = (unsigned char*)take((size_t)N * HC);      // fp8 h' for gathers
    float* asrc  = (float*)take((size_t)N * 2 * 4);
    float* adst  = (float*)take((size_t)N * 2 * 4);
    int*   rowptr= (int*)take((size_t)(N + 1) * 4);
    int*   cnt   = (int*)take((size_t)N * 4);
    int*   rank  = (int*)take((size_t)E * 4);
    int*   colsrc= (int*)take((size_t)E * 4);
    float* g     = (float*)take(HC * 4);
    unsigned short* Wt0 = (unsigned short*)take(16384 * 2);             // w_n2^T bf16
    unsigned short* Wt1 = (unsigned short*)take((size_t)3 * 16384 * 2); // conv_w^T bf16
    unsigned short* Wtv = (unsigned short*)take(8192 * 2);              // wv1^T bf16 (64x128)
    const int MB = 64;
    float* mpart = (float*)take((size_t)MB * HC * 4);
    int nb = (N + 1023) / 1024;
    int*   bsum  = (int*)take((size_t)((nb + 63) & ~63) * 4);
    int*   boff  = (int*)take((size_t)((nb + 63) & ~63) * 4);

    // --- CSR build (dst-sorted; reused across the 3 layers) ---
    hipMemsetAsync(cnt, 0, (size_t)N * 4, stream);
    count_kernel<<<(E + 255) / 256, 256, 0, stream>>>(ei, cnt, rank, E);
    scan_part_kernel<<<nb, 256, 0, stream>>>(cnt, bsum, N);
    scan_top_kernel<<<1, 64, 0, stream>>>(bsum, boff, rowptr, nb, N);
    scan_fin_kernel<<<nb, 256, 0, stream>>>(cnt, boff, rowptr, N);
    scatter_kernel<<<(E + 2047) / 2048, 256, 0, stream>>>(ei, rowptr, rank, colsrc, E);

    // --- weights -> transposed bf16 for MFMA B fragments (one dispatch) ---
    wtrans_all_kernel<<<36, 256, 0, stream>>>(w_n2, conv_w, wv1, Wt0, Wt1, Wtv);

    int nblk64 = (N + 63) / 64;
    // node encoder: hid (hB bf16) = relu(x@w1+b1); hA = hid@w2 + b2 (bf16, MFMA)
    enc1_kernel<<<nblk64, 256, 0, stream>>>(x, w_n1, b_n1, hB, N);
    gemm_mfma_kernel<false><<<nblk64, 256, 0, stream>>>(
        hB, Wt0, b_n2, nullptr, nullptr, hA, nullptr, nullptr, nullptr, N);

    for (int l = 0; l < 3; ++l){
        gemm_mfma_kernel<true><<<nblk64, 256, 0, stream>>>(
            hA, Wt1 + (size_t)l * 16384, nullptr,
            att_s + (size_t)l * HC, att_d + (size_t)l * HC,
            nullptr, h8, asrc, adst, N);
        aggregate_kernel<<<(N + 3) / 4, 256, 0, stream>>>(
            h8, asrc, adst, rowptr, colsrc, conv_b + (size_t)l * HC, hA, N);
    }

    mean_part_kernel<<<MB, 256, 0, stream>>>(hA, mpart, N);
    mean_fin_kernel<<<1, 256, 0, stream>>>(mpart, g, MB);
    vuln_mfma_kernel<<<nblk64, 256, 0, stream>>>(hA, Wtv, bv1, wv2, bv2, out, N);
    path_kernel<<<1, 128, 0, stream>>>(hA, g, wp1, bp1, wp2, bp2, wp3, bp3, out, N);
}